// Round 2
// baseline (917.040 us; speedup 1.0000x reference)
//
#include <hip/hip_runtime.h>

// Problem constants
#define B_    2
#define N_    2048
#define D_    1024
#define H_    16
#define FD_   16
#define HD_   64
#define ENC_  512
#define FP_   288              // feature dim 273 padded to 288
#define NV_   65               // 64 value cols + 1 ones-col (denominator)
#define CHK_  64               // chunk length
#define NC_   32               // N_/CHK_
#define SSZ_  (FP_*NV_)        // 18720 floats per state
#define C2C_  0.17677669529663687f   // 1/(4*sqrt(2))
#define EPS_  1e-12f

// ---------------------------------------------------------------------------
// Generic f32 GEMM: C = A @ W^T.  A is logically M x K with a row remap
// (a_row = (r/rpb)*rowjump + r%rpb) so encoder GEMMs can read x[:, :512].
// mode 0: C[r*O + c] plain row-major.
// mode 1: permuted store to [b][h][n][j] (j = c&63, h = c>>6), n-range = rpb.
// 64x64 tile, 256 threads, 4x4 per thread.
// ---------------------------------------------------------------------------
__global__ __launch_bounds__(256) void gemm_nt(
    const float* __restrict__ A, const float* __restrict__ W,
    float* __restrict__ C, int M, int K, int O,
    int rpb, int rowjump, int mode)
{
    __shared__ float As[16][68];
    __shared__ float Bs[16][68];
    int t = threadIdx.x;
    int tx = t & 15, ty = t >> 4;
    int row0 = blockIdx.y * 64, col0 = blockIdx.x * 64;
    float acc[4][4] = {{0.f}};

    int lr = (t * 4) >> 4;       // 0..63
    int lc = (t * 4) & 15;       // 0,4,8,12
    int gr_l = row0 + lr;
    const float* ap = A + (size_t)((gr_l / rpb) * rowjump + (gr_l % rpb)) * K + lc;
    const float* wp = W + (size_t)(col0 + lr) * K + lc;

    for (int k0 = 0; k0 < K; k0 += 16) {
        float4 av = *(const float4*)(ap + k0);
        float4 wv = *(const float4*)(wp + k0);
        As[lc+0][lr] = av.x; As[lc+1][lr] = av.y; As[lc+2][lr] = av.z; As[lc+3][lr] = av.w;
        Bs[lc+0][lr] = wv.x; Bs[lc+1][lr] = wv.y; Bs[lc+2][lr] = wv.z; Bs[lc+3][lr] = wv.w;
        __syncthreads();
        #pragma unroll
        for (int kk = 0; kk < 16; ++kk) {
            float a[4], b[4];
            #pragma unroll
            for (int i = 0; i < 4; ++i) a[i] = As[kk][ty*4+i];
            #pragma unroll
            for (int j = 0; j < 4; ++j) b[j] = Bs[kk][tx*4+j];
            #pragma unroll
            for (int i = 0; i < 4; ++i)
                #pragma unroll
                for (int j = 0; j < 4; ++j)
                    acc[i][j] = fmaf(a[i], b[j], acc[i][j]);
        }
        __syncthreads();
    }
    #pragma unroll
    for (int i = 0; i < 4; ++i) {
        int gr = row0 + ty*4 + i;
        #pragma unroll
        for (int j = 0; j < 4; ++j) {
            int gc = col0 + tx*4 + j;
            if (mode == 0) {
                C[(size_t)gr * O + gc] = acc[i][j];
            } else {
                int bb = gr / rpb, n = gr % rpb;
                int hh = gc >> 6, jj = gc & 63;
                C[(((size_t)(bb*H_ + hh)) * rpb + n) * HD_ + jj] = acc[i][j];
            }
        }
    }
}

// ---------------------------------------------------------------------------
// Per-chunk state GEMM with on-the-fly features:
//   S[bh][c][f][j] = sum_{m in chunk} feat_f(k_m) * Vext[m][j],  Vext=[V|1].
// feat_0=1; feat_{1..16}=k/2; feat_{17..272}=k_i*k_j/(4*sqrt2); rest 0.
// Kp layout: [b*Npb + n][256] (16-dim rows at col h*16). V: [bh][Npb][64].
// Grid = bh*nc*9 blocks (9 f-tiles of 32).
// ---------------------------------------------------------------------------
__global__ __launch_bounds__(256) void state_gemm(
    const float* __restrict__ Kp, const float* __restrict__ V,
    float* __restrict__ S, int mlen, int Npb, int nc)
{
    __shared__ float ks[8][17];
    __shared__ float vs[8][72];
    int bid = blockIdx.x;
    int ft = bid % 9; int rest = bid / 9;
    int c = rest % nc; int bh = rest / nc;
    int b = bh >> 4, h = bh & 15;
    int t = threadIdx.x;
    int fl = t & 31, jg = t >> 5;   // feature-in-tile, j-group
    int f = ft * 32 + fl;

    // per-thread feature decomposition (uniform over the m-loop)
    int ftype, fi = 0, fj = 0;
    if (f == 0)        ftype = 0;
    else if (f < 17)  { ftype = 1; fi = f - 1; }
    else if (f < 273) { ftype = 2; fi = (f-17) >> 4; fj = (f-17) & 15; }
    else               ftype = 3;

    size_t kbase = ((size_t)b * Npb + c * mlen) * 256 + h * 16;
    size_t vbase = ((size_t)bh * Npb + c * mlen) * HD_;
    float acc[9] = {0.f,0.f,0.f,0.f,0.f,0.f,0.f,0.f,0.f};

    for (int m0 = 0; m0 < mlen; m0 += 8) {
        if (t < 128) {
            int mm = t >> 4, i = t & 15;
            ks[mm][i] = Kp[kbase + (size_t)(m0 + mm) * 256 + i];
        }
        for (int i = t; i < 8*72; i += 256) {
            int mm = i / 72, j = i % 72;
            float val = 0.0f;
            if (j < 64)       val = V[vbase + (size_t)(m0 + mm) * HD_ + j];
            else if (j == 64) val = 1.0f;
            vs[mm][j] = val;
        }
        __syncthreads();
        #pragma unroll
        for (int mm = 0; mm < 8; ++mm) {
            float kv;
            if (ftype == 0)      kv = 1.0f;
            else if (ftype == 1) kv = ks[mm][fi] * 0.5f;
            else if (ftype == 2) kv = ks[mm][fi] * ks[mm][fj] * C2C_;
            else                 kv = 0.0f;
            #pragma unroll
            for (int s = 0; s < 9; ++s)
                acc[s] = fmaf(kv, vs[mm][jg + 8*s], acc[s]);
        }
        __syncthreads();
    }
    size_t sb = ((size_t)bh * nc + c) * SSZ_ + (size_t)f * NV_;
    #pragma unroll
    for (int s = 0; s < 9; ++s) {
        int j = jg + 8*s;
        if (j < NV_) S[sb + j] = acc[s];
    }
}

// ---------------------------------------------------------------------------
// In-place exclusive prefix over chunk states; run starts at encoder state.
// ---------------------------------------------------------------------------
__global__ void prefix_scan(float* __restrict__ Sloc, const float* __restrict__ Senc)
{
    int gid = blockIdx.x * blockDim.x + threadIdx.x;
    if (gid >= 32 * SSZ_) return;
    int bh = gid / SSZ_, e = gid % SSZ_;
    float run = Senc[(size_t)bh * SSZ_ + e];
    size_t base = (size_t)bh * NC_ * SSZ_ + e;
    for (int c = 0; c < NC_; ++c) {
        size_t idx = base + (size_t)c * SSZ_;
        float tv = Sloc[idx];
        Sloc[idx] = run;
        run += tv;
    }
}

// ---------------------------------------------------------------------------
// Fused per-chunk attention (features never materialized):
//   s = q·k (16-dim);  A = tril(1 + s/4 + s^2/32)
//   Y = A @ [V|1]  +  qf @ S_prefix   (qf features read on-the-fly from LDS)
//   out[...,j] = Y[:, j] / (Y[:, 64] + EPS)
// Grid = 32 bh * 32 chunks, 256 threads.
// ---------------------------------------------------------------------------
__global__ __launch_bounds__(256) void attn_chunk(
    const float* __restrict__ qp, const float* __restrict__ kp,
    const float* __restrict__ v, const float* __restrict__ Spre,
    float* __restrict__ out)
{
    __shared__ float A_s[64*65];
    __shared__ float qs[64][17];
    __shared__ float buf[4736];      // ks[64][17] -> Vext[64][68] -> S piece [72][65]
    __shared__ float den_s[64];
    int bid = blockIdx.x;
    int bh = bid >> 5, c = bid & 31;
    int b = bh >> 4, h = bh & 15;
    int t = threadIdx.x;

    // stage q,k 16-dim rows of this chunk
    float* ks = buf;                 // [64][17]
    for (int i = t; i < 64*16; i += 256) {
        int r = i >> 4, ii = i & 15;
        size_t row = (size_t)b * N_ + c * CHK_ + r;
        qs[r][ii]     = qp[row * 256 + h * 16 + ii];
        ks[r*17 + ii] = kp[row * 256 + h * 16 + ii];
    }
    __syncthreads();

    // ---- phase A: A = tril(1 + s/4 + s^2/32), s = q.k
    int tx = t & 15, ty = t >> 4;
    #pragma unroll
    for (int i2 = 0; i2 < 4; ++i2) {
        int r = ty*4 + i2;
        #pragma unroll
        for (int j2 = 0; j2 < 4; ++j2) {
            int m = tx*4 + j2;
            float s = 0.f;
            #pragma unroll
            for (int kk = 0; kk < 16; ++kk) s = fmaf(qs[r][kk], ks[m*17 + kk], s);
            float a = fmaf(s, 0.25f, 1.0f) + s * s * 0.03125f;
            A_s[r*65 + m] = (r >= m) ? a : 0.0f;
        }
    }
    __syncthreads();   // A_s ready; ks dead -> buf reusable

    // stage Vext = [V | 1 | pad] into buf[64][68]
    for (int i = t; i < 64*68; i += 256) {
        int r = i / 68, j = i % 68;
        float val = 0.0f;
        if (j < 64)       val = v[((size_t)bh * N_ + c*CHK_ + r) * HD_ + j];
        else if (j == 64) val = 1.0f;
        buf[i] = val;
    }
    __syncthreads();

    // ---- phase B: thread owns (row r, 17 j-columns)
    int r = t & 63, quad = t >> 6;
    int jbase = quad * 17;           // j=64 (denominator) owned by quad 3, jj=13
    float accy[17];
    #pragma unroll
    for (int jj = 0; jj < 17; ++jj) accy[jj] = 0.0f;

    // intra-chunk: Y += tril(A) @ Vext
    for (int m = 0; m < CHK_; ++m) {
        float a = A_s[r*65 + m];
        const float* vr = buf + m*68 + jbase;
        #pragma unroll
        for (int jj = 0; jj < 17; ++jj) accy[jj] = fmaf(a, vr[jj], accy[jj]);
    }
    __syncthreads();

    // inter-chunk: Y += qf @ S_prefix, S staged through LDS in 4 pieces of 72 f-rows
    const float* sp = Spre + ((size_t)bh * NC_ + c) * SSZ_;
    for (int p = 0; p < 4; ++p) {
        for (int i = t; i < 72*65; i += 256) buf[i] = sp[p*72*65 + i];
        __syncthreads();
        for (int fl = 0; fl < 72; ++fl) {
            int f = p*72 + fl;
            float qfv;
            if (f == 0)       qfv = 1.0f;
            else if (f < 17)  qfv = qs[r][f-1] * 0.5f;
            else if (f < 273) qfv = qs[r][(f-17) >> 4] * qs[r][(f-17) & 15] * C2C_;
            else              qfv = 0.0f;
            const float* srw = buf + fl*65 + jbase;
            #pragma unroll
            for (int jj = 0; jj < 17; ++jj) accy[jj] = fmaf(qfv, srw[jj], accy[jj]);
        }
        __syncthreads();
    }

    // divide by denominator column (j = 64) and store
    if (quad == 3) den_s[r] = accy[13];
    __syncthreads();
    float z = 1.0f / (den_s[r] + EPS_);
    float* orow = out + ((size_t)b * N_ + c*CHK_ + r) * (H_*HD_) + h * HD_;
    #pragma unroll
    for (int jj = 0; jj < 17; ++jj) {
        int j = jbase + jj;
        if (j < 64) orow[j] = accy[jj] * z;
    }
}

// ---------------------------------------------------------------------------
extern "C" void kernel_launch(void* const* d_in, const int* in_sizes, int n_in,
                              void* d_out, int out_size, void* d_ws, size_t ws_size,
                              hipStream_t stream)
{
    const float* x    = (const float*)d_in[0];
    const float* Wq   = (const float*)d_in[1];
    const float* Wk   = (const float*)d_in[2];
    const float* Wv   = (const float*)d_in[3];
    const float* Wke  = (const float*)d_in[4];
    const float* Wve  = (const float*)d_in[5];
    const float* Wout = (const float*)d_in[6];
    float* out = (float*)d_out;
    float* ws  = (float*)d_ws;

    // workspace layout (floats); total 31,564,800 floats ~= 120.4 MiB
    float* tmpq  = ws;                                 // [4096][256]
    float* tmpk  = tmpq  + (size_t)4096*256;           // [4096][256]
    float* tmpke = tmpk  + (size_t)4096*256;           // [1024][256]
    float* v     = tmpke + (size_t)1024*256;           // [32][2048][64]
    float* ve    = v     + (size_t)32*N_*HD_;          // [32][512][64]
    float* Sloc  = ve    + (size_t)32*ENC_*HD_;        // [32][32][18720] -> prefix
    float* Senc  = Sloc  + (size_t)32*NC_*SSZ_;        // [32][18720]
    float* attn  = Senc  + (size_t)32*SSZ_;            // [4096][1024]

    dim3 blk(256);

    // projections (x is (B*N, 1024); encoder GEMMs remap rows to x[b][:512])
    gemm_nt<<<dim3(4, 64),  blk, 0, stream>>>(x, Wq,  tmpq,  4096, 1024, 256,  4096, 0,    0);
    gemm_nt<<<dim3(4, 64),  blk, 0, stream>>>(x, Wk,  tmpk,  4096, 1024, 256,  4096, 0,    0);
    gemm_nt<<<dim3(16, 64), blk, 0, stream>>>(x, Wv,  v,     4096, 1024, 1024, 2048, 2048, 1);
    gemm_nt<<<dim3(4, 16),  blk, 0, stream>>>(x, Wke, tmpke, 1024, 1024, 256,  512,  2048, 0);
    gemm_nt<<<dim3(16, 16), blk, 0, stream>>>(x, Wve, ve,    1024, 1024, 1024, 512,  2048, 1);

    // states: encoder init + per-chunk locals + prefix scan
    state_gemm<<<32*9,     blk, 0, stream>>>(tmpke, ve, Senc, ENC_, ENC_, 1);
    state_gemm<<<32*NC_*9, blk, 0, stream>>>(tmpk,  v,  Sloc, CHK_, N_,   NC_);
    prefix_scan<<<(32*SSZ_ + 255)/256, blk, 0, stream>>>(Sloc, Senc);

    // fused chunked attention (numerator + denominator + divide)
    attn_chunk<<<32*NC_, blk, 0, stream>>>(tmpq, tmpk, v, Sloc, attn);

    // output projection -> d_out
    gemm_nt<<<dim3(16, 64), blk, 0, stream>>>(attn, Wout, out, 4096, 1024, 1024, 4096, 0, 0);
}

// Round 3
// 676.761 us; speedup vs baseline: 1.3550x; 1.3550x over previous
//
#include <hip/hip_runtime.h>

// Problem constants
#define B_    2
#define N_    2048
#define H_    16
#define HD_   64
#define ENC_  512
#define FP_   288
#define CHK_  64
#define NC_   32
#define SROW_ 68                     // state row stride (64 v + 1 ones + 3 pad, 16B-aligned)
#define SSZ_  (FP_*SROW_)            // 19584 floats per state
#define C2C_  0.17677669529663687f   // 1/(4*sqrt(2))
#define EPS_  1e-12f

using s8v   = __attribute__((ext_vector_type(8))) short;   // 8 bf16 (4 VGPRs)
using f4v   = __attribute__((ext_vector_type(4))) float;
using u16x4 = __attribute__((ext_vector_type(4))) unsigned short;

__device__ inline unsigned short bfh(float x) {
    unsigned int u = __float_as_uint(x);
    return (unsigned short)((u + 0x7FFF + ((u >> 16) & 1)) >> 16);
}
__device__ inline float bff(unsigned short h) {
    return __uint_as_float(((unsigned int)h) << 16);
}
__device__ inline void splitf4(float4 v, u16x4& h, u16x4& l) {
    float x0 = v.x, x1 = v.y, x2 = v.z, x3 = v.w;
    unsigned short h0 = bfh(x0), h1 = bfh(x1), h2 = bfh(x2), h3 = bfh(x3);
    h = (u16x4){h0, h1, h2, h3};
    l = (u16x4){bfh(x0 - bff(h0)), bfh(x1 - bff(h1)), bfh(x2 - bff(h2)), bfh(x3 - bff(h3))};
}

// ---------------------------------------------------------------------------
// Split-bf16 MFMA GEMM: C = A @ W^T (f32 in/out, ~f32 precision via 3-pass
// hi/lo bf16).  BM=128, BN=64, BK=32, 256 threads = 4 waves (2 row x 2 col).
// Row remap (a_row = (r/rpb)*rowjump + r%rpb) lets encoder GEMMs read
// x[b][:512].  mode 0: C[r*O+c]; mode 1: permuted [b][h][n][j] store.
// ---------------------------------------------------------------------------
__global__ __launch_bounds__(256) void mfma_gemm(
    const float* __restrict__ A, const float* __restrict__ W,
    float* __restrict__ C, int K, int O, int rpb, int rowjump, int mode)
{
    __shared__ unsigned short Ahi[128][40], Alo[128][40];
    __shared__ unsigned short Bhi[64][40],  Blo[64][40];
    int t = threadIdx.x;
    int row0 = blockIdx.y * 128, col0 = blockIdx.x * 64;

    int ar = t >> 1;               // A stage row 0..127 (B uses same for t<128)
    int kc = (t & 1) * 16;         // k offset 0/16
    int gr = row0 + ar;
    const float* ap = A + (size_t)((gr / rpb) * rowjump + (gr % rpb)) * K + kc;
    const float* wp = W + (size_t)(col0 + (ar & 63)) * K + kc;

    int w = t >> 6, lane = t & 63;
    int wrow = (w >> 1) * 64, wcol = (w & 1) * 32;
    int fr = lane & 15, g = lane >> 4;

    f4v acc[4][2];
    #pragma unroll
    for (int mt = 0; mt < 4; ++mt)
        #pragma unroll
        for (int nt = 0; nt < 2; ++nt) acc[mt][nt] = (f4v){0.f, 0.f, 0.f, 0.f};

    for (int k0 = 0; k0 < K; k0 += 32) {
        #pragma unroll
        for (int q = 0; q < 4; ++q) {
            float4 va = *(const float4*)(ap + k0 + q * 4);
            u16x4 h, l; splitf4(va, h, l);
            *(u16x4*)&Ahi[ar][kc + q * 4] = h;
            *(u16x4*)&Alo[ar][kc + q * 4] = l;
        }
        if (t < 128) {
            #pragma unroll
            for (int q = 0; q < 4; ++q) {
                float4 vb = *(const float4*)(wp + k0 + q * 4);
                u16x4 h, l; splitf4(vb, h, l);
                *(u16x4*)&Bhi[ar][kc + q * 4] = h;
                *(u16x4*)&Blo[ar][kc + q * 4] = l;
            }
        }
        __syncthreads();
        s8v ah[4], al_[4], bh_[2], bl_[2];
        #pragma unroll
        for (int mt = 0; mt < 4; ++mt) {
            ah[mt]  = *(const s8v*)&Ahi[wrow + mt * 16 + fr][g * 8];
            al_[mt] = *(const s8v*)&Alo[wrow + mt * 16 + fr][g * 8];
        }
        #pragma unroll
        for (int nt = 0; nt < 2; ++nt) {
            bh_[nt] = *(const s8v*)&Bhi[wcol + nt * 16 + fr][g * 8];
            bl_[nt] = *(const s8v*)&Blo[wcol + nt * 16 + fr][g * 8];
        }
        #pragma unroll
        for (int mt = 0; mt < 4; ++mt)
            #pragma unroll
            for (int nt = 0; nt < 2; ++nt) {
                acc[mt][nt] = __builtin_amdgcn_mfma_f32_16x16x32_bf16(ah[mt],  bh_[nt], acc[mt][nt], 0, 0, 0);
                acc[mt][nt] = __builtin_amdgcn_mfma_f32_16x16x32_bf16(ah[mt],  bl_[nt], acc[mt][nt], 0, 0, 0);
                acc[mt][nt] = __builtin_amdgcn_mfma_f32_16x16x32_bf16(al_[mt], bh_[nt], acc[mt][nt], 0, 0, 0);
            }
        __syncthreads();
    }
    // epilogue: C/D layout col=lane&15, row=(lane>>4)*4+reg  [m89]
    #pragma unroll
    for (int mt = 0; mt < 4; ++mt)
        #pragma unroll
        for (int nt = 0; nt < 2; ++nt)
            #pragma unroll
            for (int r4 = 0; r4 < 4; ++r4) {
                int r  = row0 + wrow + mt * 16 + g * 4 + r4;
                int cc = col0 + wcol + nt * 16 + fr;
                float val = acc[mt][nt][r4];
                if (mode == 0) {
                    C[(size_t)r * O + cc] = val;
                } else {
                    int bb = r / rpb, n = r % rpb;
                    int hh = cc >> 6, jj = cc & 63;
                    C[(((size_t)(bb * H_ + hh)) * rpb + n) * HD_ + jj] = val;
                }
            }
}

// ---------------------------------------------------------------------------
// Chunk state: S[f][j] = sum_m feat_f(k_m) * Vext[m][j], Vext=[V|1|0pad].
// One block per (bh, chunk-of-64, f-tile-group).  FTC f-tiles of 60 per block.
// Stage k/V once per 64-m piece; precompute feature tile fs[64][60] in LDS;
// 4x4 register tile: 2x ds_read_b128 per 16 FMA.
// ---------------------------------------------------------------------------
template <int FTC>
__global__ __launch_bounds__(256) void state_gemm(
    const float* __restrict__ Kp, const float* __restrict__ V,
    float* __restrict__ S, int mlen, int Npb, int nc)
{
    __shared__ float ks[64][17];
    __shared__ float vs[64][68];
    __shared__ float fs[64][64];
    const int nbft = 5 / FTC;
    int bid = blockIdx.x;
    int ftb = bid % nbft; int rest = bid / nbft;
    int c = rest % nc; int bh = rest / nc;
    int b = bh >> 4, h = bh & 15;
    int t = threadIdx.x;
    int fi4 = t / 17, ji4 = t % 17;        // 15x17 = 255 active
    bool active = fi4 < 15;
    int ft0 = ftb * FTC;

    float acc[FTC][4][4];
    #pragma unroll
    for (int ftc = 0; ftc < FTC; ++ftc)
        #pragma unroll
        for (int i = 0; i < 4; ++i)
            #pragma unroll
            for (int j = 0; j < 4; ++j) acc[ftc][i][j] = 0.f;

    for (int m0 = 0; m0 < mlen; m0 += 64) {
        for (int i = t; i < 64 * 16; i += 256) {
            int r = i >> 4, kk = i & 15;
            ks[r][kk] = Kp[((size_t)b * Npb + c * mlen + m0 + r) * 256 + h * 16 + kk];
        }
        for (int i = t; i < 64 * 68; i += 256) {
            int r = i / 68, j = i % 68;
            float val = 0.f;
            if (j < 64)       val = V[((size_t)bh * Npb + c * mlen + m0 + r) * HD_ + j];
            else if (j == 64) val = 1.f;
            vs[r][j] = val;
        }
        __syncthreads();
        #pragma unroll
        for (int ftc = 0; ftc < FTC; ++ftc) {
            int fbase = (ft0 + ftc) * 60;
            for (int i = t; i < 64 * 60; i += 256) {
                int m = i / 60, fl = i % 60;
                int f = fbase + fl;
                float val;
                if (f == 0)       val = 1.f;
                else if (f < 17)  val = ks[m][f - 1] * 0.5f;
                else if (f < 273) val = ks[m][(f - 17) >> 4] * ks[m][(f - 17) & 15] * C2C_;
                else              val = 0.f;
                fs[m][fl] = val;
            }
            __syncthreads();
            if (active) {
                for (int m = 0; m < 64; ++m) {
                    float4 fv = *(const float4*)&fs[m][fi4 * 4];
                    float4 vv = *(const float4*)&vs[m][ji4 * 4];
                    float fa[4] = {fv.x, fv.y, fv.z, fv.w};
                    float va[4] = {vv.x, vv.y, vv.z, vv.w};
                    #pragma unroll
                    for (int i = 0; i < 4; ++i)
                        #pragma unroll
                        for (int j = 0; j < 4; ++j)
                            acc[ftc][i][j] = fmaf(fa[i], va[j], acc[ftc][i][j]);
                }
            }
            __syncthreads();
        }
    }
    if (active) {
        size_t sb = ((size_t)bh * nc + c) * SSZ_;
        #pragma unroll
        for (int ftc = 0; ftc < FTC; ++ftc) {
            int fbase = (ft0 + ftc) * 60;
            #pragma unroll
            for (int i = 0; i < 4; ++i) {
                int f = fbase + fi4 * 4 + i;
                if (f < FP_) {
                    float4 o = make_float4(acc[ftc][i][0], acc[ftc][i][1],
                                           acc[ftc][i][2], acc[ftc][i][3]);
                    *(float4*)&S[sb + (size_t)f * SROW_ + ji4 * 4] = o;
                }
            }
        }
    }
}

// ---------------------------------------------------------------------------
// In-place exclusive prefix over chunk states; run starts at encoder state.
// ---------------------------------------------------------------------------
__global__ void prefix_scan(float* __restrict__ Sloc, const float* __restrict__ Senc)
{
    int gid = blockIdx.x * blockDim.x + threadIdx.x;
    if (gid >= 32 * SSZ_) return;
    int bh = gid / SSZ_, e = gid % SSZ_;
    float run = Senc[(size_t)bh * SSZ_ + e];
    size_t base = (size_t)bh * NC_ * SSZ_ + e;
    for (int c = 0; c < NC_; ++c) {
        size_t idx = base + (size_t)c * SSZ_;
        float tv = Sloc[idx];
        Sloc[idx] = run;
        run += tv;
    }
}

// ---------------------------------------------------------------------------
// Fused per-chunk attention (features on the fly):
//   s = q.k (16-dim);  A = tril(1 + s/4 + s^2/32)
//   Y = A @ [V|1]  +  qf @ S_prefix ;  out = Y[:, :64] / (Y[:, 64] + EPS)
// ---------------------------------------------------------------------------
__global__ __launch_bounds__(256) void attn_chunk(
    const float* __restrict__ qp, const float* __restrict__ kp,
    const float* __restrict__ v, const float* __restrict__ Spre,
    float* __restrict__ out)
{
    __shared__ float A_s[64 * 65];
    __shared__ float qs[64][17];
    __shared__ float buf[4736];      // ks[64][17] -> Vext[64][68] -> S piece [48][68]
    __shared__ float den_s[64];
    int bid = blockIdx.x;
    int bh = bid >> 5, c = bid & 31;
    int b = bh >> 4, h = bh & 15;
    int t = threadIdx.x;

    float* ks = buf;                 // [64][17]
    for (int i = t; i < 64 * 16; i += 256) {
        int r = i >> 4, ii = i & 15;
        size_t row = (size_t)b * N_ + c * CHK_ + r;
        qs[r][ii]      = qp[row * 256 + h * 16 + ii];
        ks[r * 17 + ii] = kp[row * 256 + h * 16 + ii];
    }
    __syncthreads();

    int tx = t & 15, ty = t >> 4;
    #pragma unroll
    for (int i2 = 0; i2 < 4; ++i2) {
        int r = ty * 4 + i2;
        #pragma unroll
        for (int j2 = 0; j2 < 4; ++j2) {
            int m = tx * 4 + j2;
            float s = 0.f;
            #pragma unroll
            for (int kk = 0; kk < 16; ++kk) s = fmaf(qs[r][kk], ks[m * 17 + kk], s);
            float a = fmaf(s, 0.25f, 1.0f) + s * s * 0.03125f;
            A_s[r * 65 + m] = (r >= m) ? a : 0.0f;
        }
    }
    __syncthreads();

    for (int i = t; i < 64 * 68; i += 256) {
        int r = i / 68, j = i % 68;
        float val = 0.0f;
        if (j < 64)       val = v[((size_t)bh * N_ + c * CHK_ + r) * HD_ + j];
        else if (j == 64) val = 1.0f;
        buf[i] = val;
    }
    __syncthreads();

    int r = t & 63, quad = t >> 6;
    int jbase = quad * 17;           // j=64 (denominator) at quad 3, jj=13
    float accy[17];
    #pragma unroll
    for (int jj = 0; jj < 17; ++jj) accy[jj] = 0.0f;

    for (int m = 0; m < CHK_; ++m) {
        float a = A_s[r * 65 + m];
        const float* vr = buf + m * 68 + jbase;
        #pragma unroll
        for (int jj = 0; jj < 17; ++jj) accy[jj] = fmaf(a, vr[jj], accy[jj]);
    }
    __syncthreads();

    const float* sp = Spre + ((size_t)bh * NC_ + c) * SSZ_;
    for (int p = 0; p < 6; ++p) {
        for (int i = t; i < 48 * 68; i += 256) buf[i] = sp[p * 48 * 68 + i];
        __syncthreads();
        for (int fl = 0; fl < 48; ++fl) {
            int f = p * 48 + fl;
            float qfv;
            if (f == 0)       qfv = 1.0f;
            else if (f < 17)  qfv = qs[r][f - 1] * 0.5f;
            else if (f < 273) qfv = qs[r][(f - 17) >> 4] * qs[r][(f - 17) & 15] * C2C_;
            else              qfv = 0.0f;
            const float* srw = buf + fl * 68 + jbase;
            #pragma unroll
            for (int jj = 0; jj < 17; ++jj) accy[jj] = fmaf(qfv, srw[jj], accy[jj]);
        }
        __syncthreads();
    }

    if (quad == 3) den_s[r] = accy[13];
    __syncthreads();
    float z = 1.0f / (den_s[r] + EPS_);
    float* orow = out + ((size_t)b * N_ + c * CHK_ + r) * (H_ * HD_) + h * HD_;
    #pragma unroll
    for (int jj = 0; jj < 17; ++jj) {
        int j = jbase + jj;
        if (j < 64) orow[j] = accy[jj] * z;
    }
}

// ---------------------------------------------------------------------------
extern "C" void kernel_launch(void* const* d_in, const int* in_sizes, int n_in,
                              void* d_out, int out_size, void* d_ws, size_t ws_size,
                              hipStream_t stream)
{
    const float* x    = (const float*)d_in[0];
    const float* Wq   = (const float*)d_in[1];
    const float* Wk   = (const float*)d_in[2];
    const float* Wv   = (const float*)d_in[3];
    const float* Wke  = (const float*)d_in[4];
    const float* Wve  = (const float*)d_in[5];
    const float* Wout = (const float*)d_in[6];
    float* out = (float*)d_out;
    float* ws  = (float*)d_ws;

    // workspace (floats): ~124 MiB total
    float* tmpq  = ws;                                 // [4096][256]
    float* tmpk  = tmpq  + (size_t)4096 * 256;         // [4096][256]
    float* tmpke = tmpk  + (size_t)4096 * 256;         // [1024][256]
    float* v     = tmpke + (size_t)1024 * 256;         // [32][2048][64]
    float* ve    = v     + (size_t)32 * N_ * HD_;      // [32][512][64]
    float* Sloc  = ve    + (size_t)32 * ENC_ * HD_;    // [32][32][19584] -> prefix
    float* Senc  = Sloc  + (size_t)32 * NC_ * SSZ_;    // [32][19584]
    float* attn  = Senc  + (size_t)32 * SSZ_;          // [4096][1024]

    dim3 blk(256);

    mfma_gemm<<<dim3(4, 32),  blk, 0, stream>>>(x, Wq,  tmpq,  1024, 256,  4096, 0,    0);
    mfma_gemm<<<dim3(4, 32),  blk, 0, stream>>>(x, Wk,  tmpk,  1024, 256,  4096, 0,    0);
    mfma_gemm<<<dim3(16, 32), blk, 0, stream>>>(x, Wv,  v,     1024, 1024, 2048, 2048, 1);
    mfma_gemm<<<dim3(4, 8),   blk, 0, stream>>>(x, Wke, tmpke, 1024, 256,  512,  2048, 0);
    mfma_gemm<<<dim3(16, 8),  blk, 0, stream>>>(x, Wve, ve,    1024, 1024, 512,  2048, 1);

    state_gemm<1><<<32 * 5,       blk, 0, stream>>>(tmpke, ve, Senc, 512, 512, 1);
    state_gemm<5><<<32 * NC_,     blk, 0, stream>>>(tmpk,  v,  Sloc, 64,  N_,  NC_);
    prefix_scan<<<(32 * SSZ_ + 255) / 256, blk, 0, stream>>>(Sloc, Senc);

    attn_chunk<<<32 * NC_, blk, 0, stream>>>(tmpq, tmpk, v, Sloc, attn);

    mfma_gemm<<<dim3(16, 32), blk, 0, stream>>>(attn, Wout, out, 1024, 1024, 4096, 0, 0);
}

// Round 4
// 318.290 us; speedup vs baseline: 2.8811x; 2.1262x over previous
//
#include <hip/hip_runtime.h>

// Problem constants
#define B_    2
#define N_    2048
#define H_    16
#define HD_   64
#define ENC_  512
#define FP_   288
#define CHK_  64
#define NC_   32
#define SSZ_  18720                  // transposed state: [65 j][288 f]
#define C2C_  0.17677669529663687f   // 1/(4*sqrt(2))
#define EPS_  1e-12f

using s8v   = __attribute__((ext_vector_type(8))) short;   // 8 bf16
using f4v   = __attribute__((ext_vector_type(4))) float;
using u16x4 = __attribute__((ext_vector_type(4))) unsigned short;

__device__ __forceinline__ unsigned short bfh(float x) {
    unsigned int u = __float_as_uint(x);
    return (unsigned short)((u + 0x7FFF + ((u >> 16) & 1)) >> 16);
}
__device__ __forceinline__ float bff(unsigned short h) {
    return __uint_as_float(((unsigned int)h) << 16);
}
__device__ __forceinline__ void splitf4(float4 v, u16x4& h, u16x4& l) {
    unsigned short h0 = bfh(v.x), h1 = bfh(v.y), h2 = bfh(v.z), h3 = bfh(v.w);
    h = (u16x4){h0, h1, h2, h3};
    l = (u16x4){bfh(v.x - bff(h0)), bfh(v.y - bff(h1)),
                bfh(v.z - bff(h2)), bfh(v.w - bff(h3))};
}
__device__ __forceinline__ void split1(float x, unsigned short& h, unsigned short& l) {
    h = bfh(x); l = bfh(x - bff(h));
}

#define MFMA_ __builtin_amdgcn_mfma_f32_16x16x32_bf16

// ---------------------------------------------------------------------------
// Split-bf16 MFMA GEMM body: C = A @ W^T (f32 in/out, 3-pass hi/lo).
// BM=128, BN=64, BK=32, 256 threads = 4 waves.  Shared buffers passed in.
// ---------------------------------------------------------------------------
__device__ __forceinline__ void mg(
    const float* __restrict__ A, const float* __restrict__ W,
    float* __restrict__ C, int bx, int by, int K, int O,
    int rpb, int rowjump, int mode,
    unsigned short* Ahi, unsigned short* Alo,
    unsigned short* Bhi, unsigned short* Blo)
{
    int t = threadIdx.x;
    int row0 = by * 128, col0 = bx * 64;
    int ar = t >> 1;
    int kc = (t & 1) * 16;
    int gr = row0 + ar;
    const float* ap = A + (size_t)((gr / rpb) * rowjump + (gr % rpb)) * K + kc;
    const float* wp = W + (size_t)(col0 + (ar & 63)) * K + kc;

    int w = t >> 6, lane = t & 63;
    int wrow = (w >> 1) * 64, wcol = (w & 1) * 32;
    int fr = lane & 15, g = lane >> 4;

    f4v acc[4][2];
    #pragma unroll
    for (int mt = 0; mt < 4; ++mt)
        #pragma unroll
        for (int nt = 0; nt < 2; ++nt) acc[mt][nt] = (f4v){0.f, 0.f, 0.f, 0.f};

    for (int k0 = 0; k0 < K; k0 += 32) {
        #pragma unroll
        for (int q = 0; q < 4; ++q) {
            float4 va = *(const float4*)(ap + k0 + q * 4);
            u16x4 h, l; splitf4(va, h, l);
            *(u16x4*)&Ahi[ar * 40 + kc + q * 4] = h;
            *(u16x4*)&Alo[ar * 40 + kc + q * 4] = l;
        }
        if (t < 128) {
            #pragma unroll
            for (int q = 0; q < 4; ++q) {
                float4 vb = *(const float4*)(wp + k0 + q * 4);
                u16x4 h, l; splitf4(vb, h, l);
                *(u16x4*)&Bhi[ar * 40 + kc + q * 4] = h;
                *(u16x4*)&Blo[ar * 40 + kc + q * 4] = l;
            }
        }
        __syncthreads();
        s8v ah[4], al_[4], bh_[2], bl_[2];
        #pragma unroll
        for (int mt = 0; mt < 4; ++mt) {
            ah[mt]  = *(const s8v*)&Ahi[(wrow + mt * 16 + fr) * 40 + g * 8];
            al_[mt] = *(const s8v*)&Alo[(wrow + mt * 16 + fr) * 40 + g * 8];
        }
        #pragma unroll
        for (int nt = 0; nt < 2; ++nt) {
            bh_[nt] = *(const s8v*)&Bhi[(wcol + nt * 16 + fr) * 40 + g * 8];
            bl_[nt] = *(const s8v*)&Blo[(wcol + nt * 16 + fr) * 40 + g * 8];
        }
        #pragma unroll
        for (int mt = 0; mt < 4; ++mt)
            #pragma unroll
            for (int nt = 0; nt < 2; ++nt) {
                acc[mt][nt] = MFMA_(ah[mt],  bh_[nt], acc[mt][nt], 0, 0, 0);
                acc[mt][nt] = MFMA_(ah[mt],  bl_[nt], acc[mt][nt], 0, 0, 0);
                acc[mt][nt] = MFMA_(al_[mt], bh_[nt], acc[mt][nt], 0, 0, 0);
            }
        __syncthreads();
    }
    #pragma unroll
    for (int mt = 0; mt < 4; ++mt)
        #pragma unroll
        for (int nt = 0; nt < 2; ++nt)
            #pragma unroll
            for (int r4 = 0; r4 < 4; ++r4) {
                int r  = row0 + wrow + mt * 16 + g * 4 + r4;
                int cc = col0 + wcol + nt * 16 + fr;
                float val = acc[mt][nt][r4];
                if (mode == 0) {
                    C[(size_t)r * O + cc] = val;
                } else {
                    int bb = r / rpb, n = r % rpb;
                    int hh = cc >> 6, jj = cc & 63;
                    C[(((size_t)(bb * H_ + hh)) * rpb + n) * HD_ + jj] = val;
                }
            }
}

// ---------------------------------------------------------------------------
// All 5 projections in one dispatch (block-range decode).
// ---------------------------------------------------------------------------
__global__ __launch_bounds__(256) void proj_all(
    const float* __restrict__ x,
    const float* __restrict__ Wq,  const float* __restrict__ Wk,
    const float* __restrict__ Wv,  const float* __restrict__ Wke,
    const float* __restrict__ Wve,
    float* __restrict__ tmpq, float* __restrict__ tmpk, float* __restrict__ v,
    float* __restrict__ tmpke, float* __restrict__ ve)
{
    __shared__ unsigned short SM[15360];
    unsigned short* Ahi = SM;
    unsigned short* Alo = SM + 5120;
    unsigned short* Bhi = SM + 10240;
    unsigned short* Blo = SM + 12800;
    int blk = blockIdx.x;
    if (blk < 128)       mg(x, Wq,  tmpq,  blk & 3,  blk >> 2,  1024, 256,  4096, 0,    0, Ahi, Alo, Bhi, Blo);
    else if (blk < 256)  { int r = blk - 128; mg(x, Wk,  tmpk,  r & 3,  r >> 2,  1024, 256,  4096, 0,    0, Ahi, Alo, Bhi, Blo); }
    else if (blk < 768)  { int r = blk - 256; mg(x, Wv,  v,     r & 15, r >> 4,  1024, 1024, 2048, 2048, 1, Ahi, Alo, Bhi, Blo); }
    else if (blk < 800)  { int r = blk - 768; mg(x, Wke, tmpke, r & 3,  r >> 2,  1024, 256,  512,  2048, 0, Ahi, Alo, Bhi, Blo); }
    else                 { int r = blk - 800; mg(x, Wve, ve,    r & 15, r >> 4,  1024, 1024, 512,  2048, 1, Ahi, Alo, Bhi, Blo); }
}

// standalone GEMM kernel (output projection)
__global__ __launch_bounds__(256) void mfma_gemm(
    const float* __restrict__ A, const float* __restrict__ W,
    float* __restrict__ C, int K, int O, int rpb, int rowjump, int mode)
{
    __shared__ unsigned short SM[15360];
    mg(A, W, C, blockIdx.x, blockIdx.y, K, O, rpb, rowjump, mode,
       SM, SM + 5120, SM + 10240, SM + 12800);
}

// ---------------------------------------------------------------------------
// Unified state kernel (encoder + chunk states), TRANSPOSED output:
//   St[j][f] = sum_m Vext[m][j] * feat_f(k_m),  j rows (65), f cols (288).
// First 160 blocks: encoder (mlen=512); rest 5120: chunk (mlen=64).
// Each block: one (bh, c, f-tile-of-60).
// ---------------------------------------------------------------------------
__global__ __launch_bounds__(256) void state_all(
    const float* __restrict__ Kpe, const float* __restrict__ Ve, float* __restrict__ Se,
    const float* __restrict__ Kpc, const float* __restrict__ Vc, float* __restrict__ Sc)
{
    __shared__ float ks[64][17];
    __shared__ float vs[64][68];
    __shared__ float fs[64][64];
    int blk = blockIdx.x;
    const float *Kp, *V; float* Sg;
    int mlen, Npb, c, bh, ftb;
    if (blk < 160) {
        ftb = blk % 5; bh = blk / 5; c = 0; mlen = 512; Npb = 512;
        Kp = Kpe; V = Ve; Sg = Se + (size_t)bh * SSZ_;
    } else {
        int b2 = blk - 160; ftb = b2 % 5; int rest = b2 / 5;
        c = rest & 31; bh = rest >> 5; mlen = 64; Npb = 2048;
        Kp = Kpc; V = Vc; Sg = Sc + ((size_t)bh * NC_ + c) * SSZ_;
    }
    int b = bh >> 4, h = bh & 15;
    int t = threadIdx.x;
    int fi4 = t / 17, ji4 = t % 17;
    bool active = fi4 < 15;
    int fbase = ftb * 60;

    float acc[4][4];
    #pragma unroll
    for (int i = 0; i < 4; ++i)
        #pragma unroll
        for (int j = 0; j < 4; ++j) acc[i][j] = 0.f;

    for (int m0 = 0; m0 < mlen; m0 += 64) {
        for (int i = t; i < 64 * 16; i += 256) {
            int r = i >> 4, kk = i & 15;
            ks[r][kk] = Kp[((size_t)b * Npb + c * mlen + m0 + r) * 256 + h * 16 + kk];
        }
        for (int i = t; i < 64 * 68; i += 256) {
            int r = i / 68, j = i % 68;
            float val = 0.f;
            if (j < 64)       val = V[((size_t)bh * Npb + c * mlen + m0 + r) * HD_ + j];
            else if (j == 64) val = 1.f;
            vs[r][j] = val;
        }
        __syncthreads();
        for (int i = t; i < 64 * 60; i += 256) {
            int m = i / 60, fl = i % 60;
            int f = fbase + fl;
            float val;
            if (f == 0)       val = 1.f;
            else if (f < 17)  val = ks[m][f - 1] * 0.5f;
            else if (f < 273) val = ks[m][(f - 17) >> 4] * ks[m][(f - 17) & 15] * C2C_;
            else              val = 0.f;
            fs[m][fl] = val;
        }
        __syncthreads();
        if (active) {
            for (int m = 0; m < 64; ++m) {
                float4 fv = *(const float4*)&fs[m][fi4 * 4];
                float4 vv = *(const float4*)&vs[m][ji4 * 4];
                float fa[4] = {fv.x, fv.y, fv.z, fv.w};
                float va[4] = {vv.x, vv.y, vv.z, vv.w};
                #pragma unroll
                for (int i = 0; i < 4; ++i)
                    #pragma unroll
                    for (int j = 0; j < 4; ++j)
                        acc[i][j] = fmaf(fa[i], va[j], acc[i][j]);
            }
        }
        __syncthreads();
    }
    if (active) {
        int f4b = fbase + fi4 * 4;
        if (f4b < FP_) {
            #pragma unroll
            for (int jj = 0; jj < 4; ++jj) {
                int jcol = ji4 * 4 + jj;
                if (jcol < 65) {
                    float4 o = make_float4(acc[0][jj], acc[1][jj], acc[2][jj], acc[3][jj]);
                    *(float4*)&Sg[(size_t)jcol * FP_ + f4b] = o;
                }
            }
        }
    }
}

// ---------------------------------------------------------------------------
// In-place exclusive prefix over chunk states; seeded by encoder state.
// ---------------------------------------------------------------------------
__global__ void prefix_scan(float* __restrict__ Sloc, const float* __restrict__ Senc)
{
    int gid = blockIdx.x * blockDim.x + threadIdx.x;
    if (gid >= 32 * SSZ_) return;
    int bh = gid / SSZ_, e = gid % SSZ_;
    float run = Senc[(size_t)bh * SSZ_ + e];
    size_t base = (size_t)bh * NC_ * SSZ_ + e;
    for (int c = 0; c < NC_; ++c) {
        size_t idx = base + (size_t)c * SSZ_;
        float tv = Sloc[idx];
        Sloc[idx] = run;
        run += tv;
    }
}

// ---------------------------------------------------------------------------
// MFMA attn_chunk.  Per (bh, c) block, 4 waves (wave w = m-tile, rows 16w..):
//   phase A: S_qk = Q K^T (K=16 pad 32, split-bf16) -> a = tril(1+s/4+s^2/32)
//            -> Ah/Al bf16 in LDS
//   Y1: acc += A @ VextT   (K=64, VextT[j][m] from v, split)
//   Y2: acc += QF @ StT    (K=288 in slices of 64/32; QF gen'd from qs, St staged)
//   out = acc[:, :64] / (acc[:, 64] + eps)
// ---------------------------------------------------------------------------
__shared__ unsigned short U_attn_dummy[1]; // (placeholder avoided; real decl in kernel)

template <int FW>
__device__ __forceinline__ void y2_slice(
    int f0, const float* __restrict__ Stg, const float* qs,
    unsigned short* QFH, unsigned short* QFL,
    unsigned short* STH, unsigned short* STL,
    f4v (&acc)[5], int w, int fr, int g, int t)
{
    // generate QF hi/lo [64][FW] (row stride 72)
    for (int i = t; i < 64 * FW; i += 256) {
        int row = i / FW, cc = i % FW;
        int f = f0 + cc;
        float qv;
        if (f == 0)       qv = 1.0f;
        else if (f < 17)  qv = qs[row * 20 + (f - 1)] * 0.5f;
        else if (f < 273) qv = qs[row * 20 + ((f - 17) >> 4)] * qs[row * 20 + ((f - 17) & 15)] * C2C_;
        else              qv = 0.0f;
        unsigned short h, l; split1(qv, h, l);
        QFH[row * 72 + cc] = h;
        QFL[row * 72 + cc] = l;
    }
    // stage St hi/lo [80][FW] (rows 65..79 zero)
    const int NB4 = FW / 4;
    for (int i = t; i < 80 * NB4; i += 256) {
        int j = i / NB4, c4 = i % NB4;
        float4 ld;
        if (j < 65) ld = *(const float4*)&Stg[(size_t)j * FP_ + f0 + c4 * 4];
        else        ld = make_float4(0.f, 0.f, 0.f, 0.f);
        u16x4 h, l; splitf4(ld, h, l);
        *(u16x4*)&STH[j * 72 + c4 * 4] = h;
        *(u16x4*)&STL[j * 72 + c4 * 4] = l;
    }
    __syncthreads();
    #pragma unroll
    for (int ks2 = 0; ks2 < FW / 32; ++ks2) {
        s8v ah = *(const s8v*)&QFH[(16 * w + fr) * 72 + ks2 * 32 + g * 8];
        s8v al = *(const s8v*)&QFL[(16 * w + fr) * 72 + ks2 * 32 + g * 8];
        #pragma unroll
        for (int jt = 0; jt < 5; ++jt) {
            s8v bh_ = *(const s8v*)&STH[(jt * 16 + fr) * 72 + ks2 * 32 + g * 8];
            s8v bl_ = *(const s8v*)&STL[(jt * 16 + fr) * 72 + ks2 * 32 + g * 8];
            acc[jt] = MFMA_(ah, bh_, acc[jt], 0, 0, 0);
            acc[jt] = MFMA_(ah, bl_, acc[jt], 0, 0, 0);
            acc[jt] = MFMA_(al, bh_, acc[jt], 0, 0, 0);
        }
    }
    __syncthreads();
}

__global__ __launch_bounds__(256) void attn_chunk(
    const float* __restrict__ qp, const float* __restrict__ kp,
    const float* __restrict__ v, const float* __restrict__ Spre,
    float* __restrict__ out)
{
    __shared__ unsigned short U[20736];
    __shared__ float qs[64 * 20];
    __shared__ float den_s[64];
    unsigned short* AH  = U;            // [64][72]
    unsigned short* AL  = U + 4608;
    unsigned short* QH  = U + 9216;     // [64][40]
    unsigned short* QL  = U + 11776;
    unsigned short* KH  = U + 14336;
    unsigned short* KL  = U + 16896;
    unsigned short* VTH = U + 9216;     // [80][72]
    unsigned short* VTL = U + 14976;
    unsigned short* QFH = U;            // [64][72]
    unsigned short* QFL = U + 4608;
    unsigned short* STH = U + 9216;     // [80][72]
    unsigned short* STL = U + 14976;

    int bid = blockIdx.x;
    int bh = bid >> 5, c = bid & 31;
    int b = bh >> 4, h = bh & 15;
    int t = threadIdx.x;
    int w = t >> 6, lane = t & 63, fr = lane & 15, g = lane >> 4;
    int rowbase = b * N_ + c * CHK_;

    // ---- stage q,k (16-dim) as bf16 hi/lo [64][40] (cols 16..31 zero), qs f32
    {
        int r = t >> 2, q4 = t & 3;
        float4 qv = *(const float4*)&qp[(size_t)(rowbase + r) * 256 + h * 16 + q4 * 4];
        float4 kv = *(const float4*)&kp[(size_t)(rowbase + r) * 256 + h * 16 + q4 * 4];
        u16x4 hh, ll;
        splitf4(qv, hh, ll);
        *(u16x4*)&QH[r * 40 + q4 * 4] = hh;
        *(u16x4*)&QL[r * 40 + q4 * 4] = ll;
        splitf4(kv, hh, ll);
        *(u16x4*)&KH[r * 40 + q4 * 4] = hh;
        *(u16x4*)&KL[r * 40 + q4 * 4] = ll;
        u16x4 z4 = (u16x4){0, 0, 0, 0};
        *(u16x4*)&QH[r * 40 + 16 + q4 * 4] = z4;
        *(u16x4*)&QL[r * 40 + 16 + q4 * 4] = z4;
        *(u16x4*)&KH[r * 40 + 16 + q4 * 4] = z4;
        *(u16x4*)&KL[r * 40 + 16 + q4 * 4] = z4;
        qs[r * 20 + q4 * 4 + 0] = qv.x;
        qs[r * 20 + q4 * 4 + 1] = qv.y;
        qs[r * 20 + q4 * 4 + 2] = qv.z;
        qs[r * 20 + q4 * 4 + 3] = qv.w;
    }
    __syncthreads();

    // ---- phase A: S_qk via MFMA, poly+tril, split into AH/AL
    {
        s8v qh = *(const s8v*)&QH[(16 * w + fr) * 40 + g * 8];
        s8v ql = *(const s8v*)&QL[(16 * w + fr) * 40 + g * 8];
        f4v sacc[4];
        #pragma unroll
        for (int jt = 0; jt < 4; ++jt) sacc[jt] = (f4v){0.f, 0.f, 0.f, 0.f};
        #pragma unroll
        for (int jt = 0; jt < 4; ++jt) {
            s8v kh = *(const s8v*)&KH[(jt * 16 + fr) * 40 + g * 8];
            s8v kl = *(const s8v*)&KL[(jt * 16 + fr) * 40 + g * 8];
            sacc[jt] = MFMA_(qh, kh, sacc[jt], 0, 0, 0);
            sacc[jt] = MFMA_(qh, kl, sacc[jt], 0, 0, 0);
            sacc[jt] = MFMA_(ql, kh, sacc[jt], 0, 0, 0);
        }
        #pragma unroll
        for (int jt = 0; jt < 4; ++jt)
            #pragma unroll
            for (int r4 = 0; r4 < 4; ++r4) {
                int row = 16 * w + g * 4 + r4, col = jt * 16 + fr;
                float s = sacc[jt][r4];
                float a = (row >= col) ? (fmaf(s, 0.25f, 1.0f) + s * s * 0.03125f) : 0.f;
                unsigned short hh, ll; split1(a, hh, ll);
                AH[row * 72 + col] = hh;
                AL[row * 72 + col] = ll;
            }
    }
    __syncthreads();   // everyone done reading QH..KL, writing AH/AL

    // ---- stage VextT hi/lo [80][72-stride] cols 0..63 (j rows; ones row 64)
    for (int i = t; i < 80 * 64; i += 256) {
        int j = i >> 6, m = i & 63;
        float val;
        if (j < 64)       val = v[((size_t)bh * N_ + c * CHK_ + m) * HD_ + j];
        else if (j == 64) val = 1.0f;
        else              val = 0.0f;
        unsigned short hh, ll; split1(val, hh, ll);
        VTH[j * 72 + m] = hh;
        VTL[j * 72 + m] = ll;
    }
    __syncthreads();

    // ---- Y1: acc += A @ VextT  (K=64)
    f4v acc[5];
    #pragma unroll
    for (int jt = 0; jt < 5; ++jt) acc[jt] = (f4v){0.f, 0.f, 0.f, 0.f};
    #pragma unroll
    for (int ks2 = 0; ks2 < 2; ++ks2) {
        s8v ah = *(const s8v*)&AH[(16 * w + fr) * 72 + ks2 * 32 + g * 8];
        s8v al = *(const s8v*)&AL[(16 * w + fr) * 72 + ks2 * 32 + g * 8];
        #pragma unroll
        for (int jt = 0; jt < 5; ++jt) {
            s8v bh_ = *(const s8v*)&VTH[(jt * 16 + fr) * 72 + ks2 * 32 + g * 8];
            s8v bl_ = *(const s8v*)&VTL[(jt * 16 + fr) * 72 + ks2 * 32 + g * 8];
            acc[jt] = MFMA_(ah, bh_, acc[jt], 0, 0, 0);
            acc[jt] = MFMA_(ah, bl_, acc[jt], 0, 0, 0);
            acc[jt] = MFMA_(al, bh_, acc[jt], 0, 0, 0);
        }
    }
    __syncthreads();

    // ---- Y2: acc += QF @ StT over f-slices
    const float* Stg = Spre + ((size_t)bh * NC_ + c) * SSZ_;
    for (int p = 0; p < 4; ++p)
        y2_slice<64>(p * 64, Stg, qs, QFH, QFL, STH, STL, acc, w, fr, g, t);
    y2_slice<32>(256, Stg, qs, QFH, QFL, STH, STL, acc, w, fr, g, t);

    // ---- epilogue: divide by denominator (col 64 = j-tile 4, fr 0)
    if (fr == 0) {
        #pragma unroll
        for (int r4 = 0; r4 < 4; ++r4)
            den_s[16 * w + g * 4 + r4] = acc[4][r4];
    }
    __syncthreads();
    #pragma unroll
    for (int r4 = 0; r4 < 4; ++r4) {
        float z = 1.0f / (den_s[16 * w + g * 4 + r4] + EPS_);
        int row = rowbase + 16 * w + g * 4 + r4;
        #pragma unroll
        for (int jt = 0; jt < 4; ++jt)
            out[(size_t)row * 1024 + h * 64 + jt * 16 + fr] = acc[jt][r4] * z;
    }
}

// ---------------------------------------------------------------------------
extern "C" void kernel_launch(void* const* d_in, const int* in_sizes, int n_in,
                              void* d_out, int out_size, void* d_ws, size_t ws_size,
                              hipStream_t stream)
{
    const float* x    = (const float*)d_in[0];
    const float* Wq   = (const float*)d_in[1];
    const float* Wk   = (const float*)d_in[2];
    const float* Wv   = (const float*)d_in[3];
    const float* Wke  = (const float*)d_in[4];
    const float* Wve  = (const float*)d_in[5];
    const float* Wout = (const float*)d_in[6];
    float* out = (float*)d_out;
    float* ws  = (float*)d_ws;

    // workspace (floats): ~120.4 MiB
    float* tmpq  = ws;                                 // [4096][256]
    float* tmpk  = tmpq  + (size_t)4096 * 256;         // [4096][256]
    float* tmpke = tmpk  + (size_t)4096 * 256;         // [1024][256]
    float* v     = tmpke + (size_t)1024 * 256;         // [32][2048][64]
    float* ve    = v     + (size_t)32 * N_ * HD_;      // [32][512][64]
    float* Sloc  = ve    + (size_t)32 * ENC_ * HD_;    // [32][32][18720]
    float* Senc  = Sloc  + (size_t)32 * NC_ * SSZ_;    // [32][18720]
    float* attn  = Senc  + (size_t)32 * SSZ_;          // [4096][1024]

    dim3 blk(256);

    proj_all<<<928, blk, 0, stream>>>(x, Wq, Wk, Wv, Wke, Wve,
                                      tmpq, tmpk, v, tmpke, ve);
    state_all<<<160 + 32 * NC_ * 5, blk, 0, stream>>>(tmpke, ve, Senc, tmpk, v, Sloc);
    prefix_scan<<<(32 * SSZ_ + 255) / 256, blk, 0, stream>>>(Sloc, Senc);
    attn_chunk<<<32 * NC_, blk, 0, stream>>>(tmpq, tmpk, v, Sloc, attn);
    mfma_gemm<<<dim3(16, 32), blk, 0, stream>>>(attn, Wout, out, 1024, 1024, 4096, 0, 0);
}

// Round 5
// 240.793 us; speedup vs baseline: 3.8084x; 1.3218x over previous
//
#include <hip/hip_runtime.h>

// Problem constants
#define B_    2
#define N_    2048
#define H_    16
#define HD_   64
#define ENC_  512
#define FP_   288
#define CHK_  64
#define NC_   32
#define SSZ_  18720                  // transposed state: [65 j][288 f]
#define C2C_  0.17677669529663687f   // 1/(4*sqrt(2))
#define EPS_  1e-12f

using s8v   = __attribute__((ext_vector_type(8))) short;   // 8 bf16
using f4v   = __attribute__((ext_vector_type(4))) float;
using u16x4 = __attribute__((ext_vector_type(4))) unsigned short;

__device__ __forceinline__ unsigned short bfh(float x) {
    unsigned int u = __float_as_uint(x);
    return (unsigned short)((u + 0x7FFF + ((u >> 16) & 1)) >> 16);
}
__device__ __forceinline__ float bff(unsigned short h) {
    return __uint_as_float(((unsigned int)h) << 16);
}
__device__ __forceinline__ void splitf4(float4 v, u16x4& h, u16x4& l) {
    unsigned short h0 = bfh(v.x), h1 = bfh(v.y), h2 = bfh(v.z), h3 = bfh(v.w);
    h = (u16x4){h0, h1, h2, h3};
    l = (u16x4){bfh(v.x - bff(h0)), bfh(v.y - bff(h1)),
                bfh(v.z - bff(h2)), bfh(v.w - bff(h3))};
}
__device__ __forceinline__ void split1(float x, unsigned short& h, unsigned short& l) {
    h = bfh(x); l = bfh(x - bff(h));
}
__device__ __forceinline__ float4 add4(float4 a, float4 b) {
    return make_float4(a.x + b.x, a.y + b.y, a.z + b.z, a.w + b.w);
}

#define MFMA_ __builtin_amdgcn_mfma_f32_16x16x32_bf16

// ---------------------------------------------------------------------------
// Split-bf16 MFMA GEMM body: C = A @ W^T (f32 in/out, 3-pass hi/lo).
// BM=128, BN=64, BK=32, 256 threads = 4 waves.
// ---------------------------------------------------------------------------
__device__ __forceinline__ void mg(
    const float* __restrict__ A, const float* __restrict__ W,
    float* __restrict__ C, int bx, int by, int K, int O,
    int rpb, int rowjump, int mode,
    unsigned short* Ahi, unsigned short* Alo,
    unsigned short* Bhi, unsigned short* Blo)
{
    int t = threadIdx.x;
    int row0 = by * 128, col0 = bx * 64;
    int ar = t >> 1;
    int kc = (t & 1) * 16;
    int gr = row0 + ar;
    const float* ap = A + (size_t)((gr / rpb) * rowjump + (gr % rpb)) * K + kc;
    const float* wp = W + (size_t)(col0 + (ar & 63)) * K + kc;

    int w = t >> 6, lane = t & 63;
    int wrow = (w >> 1) * 64, wcol = (w & 1) * 32;
    int fr = lane & 15, g = lane >> 4;

    f4v acc[4][2];
    #pragma unroll
    for (int mt = 0; mt < 4; ++mt)
        #pragma unroll
        for (int nt = 0; nt < 2; ++nt) acc[mt][nt] = (f4v){0.f, 0.f, 0.f, 0.f};

    for (int k0 = 0; k0 < K; k0 += 32) {
        #pragma unroll
        for (int q = 0; q < 4; ++q) {
            float4 va = *(const float4*)(ap + k0 + q * 4);
            u16x4 h, l; splitf4(va, h, l);
            *(u16x4*)&Ahi[ar * 40 + kc + q * 4] = h;
            *(u16x4*)&Alo[ar * 40 + kc + q * 4] = l;
        }
        if (t < 128) {
            #pragma unroll
            for (int q = 0; q < 4; ++q) {
                float4 vb = *(const float4*)(wp + k0 + q * 4);
                u16x4 h, l; splitf4(vb, h, l);
                *(u16x4*)&Bhi[ar * 40 + kc + q * 4] = h;
                *(u16x4*)&Blo[ar * 40 + kc + q * 4] = l;
            }
        }
        __syncthreads();
        s8v ah[4], al_[4], bh_[2], bl_[2];
        #pragma unroll
        for (int mt = 0; mt < 4; ++mt) {
            ah[mt]  = *(const s8v*)&Ahi[(wrow + mt * 16 + fr) * 40 + g * 8];
            al_[mt] = *(const s8v*)&Alo[(wrow + mt * 16 + fr) * 40 + g * 8];
        }
        #pragma unroll
        for (int nt = 0; nt < 2; ++nt) {
            bh_[nt] = *(const s8v*)&Bhi[(wcol + nt * 16 + fr) * 40 + g * 8];
            bl_[nt] = *(const s8v*)&Blo[(wcol + nt * 16 + fr) * 40 + g * 8];
        }
        #pragma unroll
        for (int mt = 0; mt < 4; ++mt)
            #pragma unroll
            for (int nt = 0; nt < 2; ++nt) {
                acc[mt][nt] = MFMA_(ah[mt],  bh_[nt], acc[mt][nt], 0, 0, 0);
                acc[mt][nt] = MFMA_(ah[mt],  bl_[nt], acc[mt][nt], 0, 0, 0);
                acc[mt][nt] = MFMA_(al_[mt], bh_[nt], acc[mt][nt], 0, 0, 0);
            }
        __syncthreads();
    }
    #pragma unroll
    for (int mt = 0; mt < 4; ++mt)
        #pragma unroll
        for (int nt = 0; nt < 2; ++nt)
            #pragma unroll
            for (int r4 = 0; r4 < 4; ++r4) {
                int r  = row0 + wrow + mt * 16 + g * 4 + r4;
                int cc = col0 + wcol + nt * 16 + fr;
                float val = acc[mt][nt][r4];
                if (mode == 0) {
                    C[(size_t)r * O + cc] = val;
                } else {
                    int bb = r / rpb, n = r % rpb;
                    int hh = cc >> 6, jj = cc & 63;
                    C[(((size_t)(bb * H_ + hh)) * rpb + n) * HD_ + jj] = val;
                }
            }
}

// ---------------------------------------------------------------------------
// All 5 projections in one dispatch (block-range decode).
// ---------------------------------------------------------------------------
__global__ __launch_bounds__(256) void proj_all(
    const float* __restrict__ x,
    const float* __restrict__ Wq,  const float* __restrict__ Wk,
    const float* __restrict__ Wv,  const float* __restrict__ Wke,
    const float* __restrict__ Wve,
    float* __restrict__ tmpq, float* __restrict__ tmpk, float* __restrict__ v,
    float* __restrict__ tmpke, float* __restrict__ ve)
{
    __shared__ unsigned short SM[15360];
    unsigned short* Ahi = SM;
    unsigned short* Alo = SM + 5120;
    unsigned short* Bhi = SM + 10240;
    unsigned short* Blo = SM + 12800;
    int blk = blockIdx.x;
    if (blk < 128)       mg(x, Wq,  tmpq,  blk & 3,  blk >> 2,  1024, 256,  4096, 0,    0, Ahi, Alo, Bhi, Blo);
    else if (blk < 256)  { int r = blk - 128; mg(x, Wk,  tmpk,  r & 3,  r >> 2,  1024, 256,  4096, 0,    0, Ahi, Alo, Bhi, Blo); }
    else if (blk < 768)  { int r = blk - 256; mg(x, Wv,  v,     r & 15, r >> 4,  1024, 1024, 2048, 2048, 1, Ahi, Alo, Bhi, Blo); }
    else if (blk < 800)  { int r = blk - 768; mg(x, Wke, tmpke, r & 3,  r >> 2,  1024, 256,  512,  2048, 0, Ahi, Alo, Bhi, Blo); }
    else                 { int r = blk - 800; mg(x, Wve, ve,    r & 15, r >> 4,  1024, 1024, 512,  2048, 1, Ahi, Alo, Bhi, Blo); }
}

// standalone GEMM kernel (output projection)
__global__ __launch_bounds__(256) void mfma_gemm(
    const float* __restrict__ A, const float* __restrict__ W,
    float* __restrict__ C, int K, int O, int rpb, int rowjump, int mode)
{
    __shared__ unsigned short SM[15360];
    mg(A, W, C, blockIdx.x, blockIdx.y, K, O, rpb, rowjump, mode,
       SM, SM + 5120, SM + 10240, SM + 12800);
}

// ---------------------------------------------------------------------------
// MFMA state kernel.  St[j][f] = sum_m VextT[j][m] * feat_f(k_m).
// A = VextT (hi/lo bf16 in LDS, rows j=0..79, row 64 = ones, 65..79 zero),
// B-fragments generated per-lane from transposed ksT[17][68] (row 16 = ones):
//   feat_f(k_m) = ksT[fi][m] * ksT[fj][m] * scale   (uniform for all f).
// Chunk blocks: one (bh,c), waves cover 18 f-tiles.  Encoder blocks: one
// (bh, f-group), wave = 1 f-tile, 8 m-pieces accumulated.
// ---------------------------------------------------------------------------
__device__ __forceinline__ void st_stage(
    const float* __restrict__ Kp, const float* __restrict__ V,
    size_t krow0, size_t vrow0, int h, int t,
    float* ksT, unsigned short* VTH, unsigned short* VTL)
{
    {
        int r = t >> 2, q4 = t & 3;
        float4 kv = *(const float4*)&Kp[(krow0 + r) * 256 + h * 16 + q4 * 4];
        ksT[(q4 * 4 + 0) * 68 + r] = kv.x;
        ksT[(q4 * 4 + 1) * 68 + r] = kv.y;
        ksT[(q4 * 4 + 2) * 68 + r] = kv.z;
        ksT[(q4 * 4 + 3) * 68 + r] = kv.w;
    }
    if (t < 64) ksT[16 * 68 + t] = 1.0f;
    {
        int r = t & 63, jg = t >> 6;
        #pragma unroll
        for (int cc = 0; cc < 4; ++cc) {
            float4 vv = *(const float4*)&V[(vrow0 + r) * HD_ + jg * 16 + cc * 4];
            float vals[4] = {vv.x, vv.y, vv.z, vv.w};
            #pragma unroll
            for (int e = 0; e < 4; ++e) {
                int j = jg * 16 + cc * 4 + e;
                unsigned short hh, ll; split1(vals[e], hh, ll);
                VTH[j * 72 + r] = hh;
                VTL[j * 72 + r] = ll;
            }
        }
    }
    if (t < 64) { VTH[64 * 72 + t] = 0x3F80; VTL[64 * 72 + t] = 0; }
}

__device__ __forceinline__ void st_ftile(
    const float* ksT, int ft, int fr, int g,
    const s8v (&AHf)[2][5], const s8v (&ALf)[2][5], f4v (&acc)[5])
{
    int f = ft * 16 + fr;
    int fi, fj; float scale;
    if (f == 0)       { fi = 16; fj = 16; scale = 1.0f; }
    else if (f < 17)  { fi = f - 1; fj = 16; scale = 0.5f; }
    else if (f < 273) { fi = (f - 17) >> 4; fj = (f - 17) & 15; scale = C2C_; }
    else              { fi = 16; fj = 16; scale = 0.0f; }
    #pragma unroll
    for (int ks2 = 0; ks2 < 2; ++ks2) {
        const float* pa = ksT + fi * 68 + ks2 * 32 + g * 8;
        const float* pb = ksT + fj * 68 + ks2 * 32 + g * 8;
        s8v bhv, blv;
        #pragma unroll
        for (int e = 0; e < 8; ++e) {
            float val = pa[e] * pb[e] * scale;
            unsigned short hh, ll; split1(val, hh, ll);
            bhv[e] = (short)hh; blv[e] = (short)ll;
        }
        #pragma unroll
        for (int jt = 0; jt < 5; ++jt) {
            acc[jt] = MFMA_(AHf[ks2][jt], bhv, acc[jt], 0, 0, 0);
            acc[jt] = MFMA_(AHf[ks2][jt], blv, acc[jt], 0, 0, 0);
            acc[jt] = MFMA_(ALf[ks2][jt], bhv, acc[jt], 0, 0, 0);
        }
    }
}

__global__ __launch_bounds__(256) void state_all(
    const float* __restrict__ Kpe, const float* __restrict__ Ve, float* __restrict__ Se,
    const float* __restrict__ Kpc, const float* __restrict__ Vc, float* __restrict__ Sc)
{
    __shared__ float ksT[17 * 68];
    __shared__ unsigned short VTH[80 * 72], VTL[80 * 72];
    int blk = blockIdx.x, t = threadIdx.x;
    int w = t >> 6, lane = t & 63, fr = lane & 15, g = lane >> 4;

    for (int i = t; i < 15 * 72; i += 256) { VTH[65 * 72 + i] = 0; VTL[65 * 72 + i] = 0; }

    if (blk >= 160) {
        // ---- chunk state (mlen = 64)
        int b2 = blk - 160;
        int c = b2 & 31, bh = b2 >> 5;
        int b = bh >> 4, h = bh & 15;
        float* Sg = Sc + ((size_t)bh * NC_ + c) * SSZ_;
        st_stage(Kpc, Vc, (size_t)b * 2048 + c * 64, (size_t)bh * 2048 + c * 64,
                 h, t, ksT, VTH, VTL);
        __syncthreads();
        s8v AHf[2][5], ALf[2][5];
        #pragma unroll
        for (int ks2 = 0; ks2 < 2; ++ks2)
            #pragma unroll
            for (int jt = 0; jt < 5; ++jt) {
                AHf[ks2][jt] = *(const s8v*)&VTH[(jt * 16 + fr) * 72 + ks2 * 32 + g * 8];
                ALf[ks2][jt] = *(const s8v*)&VTL[(jt * 16 + fr) * 72 + ks2 * 32 + g * 8];
            }
        for (int ft = w; ft < 18; ft += 4) {
            f4v acc[5];
            #pragma unroll
            for (int jt = 0; jt < 5; ++jt) acc[jt] = (f4v){0.f, 0.f, 0.f, 0.f};
            st_ftile(ksT, ft, fr, g, AHf, ALf, acc);
            #pragma unroll
            for (int jt = 0; jt < 5; ++jt)
                #pragma unroll
                for (int r4 = 0; r4 < 4; ++r4) {
                    int j = jt * 16 + g * 4 + r4;
                    if (j < 65) Sg[(size_t)j * FP_ + ft * 16 + fr] = acc[jt][r4];
                }
        }
    } else {
        // ---- encoder state (mlen = 512), wave = one f-tile
        int bh = blk / 5, fg = blk % 5;
        int b = bh >> 4, h = bh & 15;
        int ft = fg * 4 + w;
        float* Sg = Se + (size_t)bh * SSZ_;
        f4v acc[5];
        #pragma unroll
        for (int jt = 0; jt < 5; ++jt) acc[jt] = (f4v){0.f, 0.f, 0.f, 0.f};
        for (int m0 = 0; m0 < 512; m0 += 64) {
            if (m0) __syncthreads();
            st_stage(Kpe, Ve, (size_t)b * 512 + m0, (size_t)bh * 512 + m0,
                     h, t, ksT, VTH, VTL);
            __syncthreads();
            if (ft < 18) {
                s8v AHf[2][5], ALf[2][5];
                #pragma unroll
                for (int ks2 = 0; ks2 < 2; ++ks2)
                    #pragma unroll
                    for (int jt = 0; jt < 5; ++jt) {
                        AHf[ks2][jt] = *(const s8v*)&VTH[(jt * 16 + fr) * 72 + ks2 * 32 + g * 8];
                        ALf[ks2][jt] = *(const s8v*)&VTL[(jt * 16 + fr) * 72 + ks2 * 32 + g * 8];
                    }
                st_ftile(ksT, ft, fr, g, AHf, ALf, acc);
            }
        }
        if (ft < 18) {
            #pragma unroll
            for (int jt = 0; jt < 5; ++jt)
                #pragma unroll
                for (int r4 = 0; r4 < 4; ++r4) {
                    int j = jt * 16 + g * 4 + r4;
                    if (j < 65) Sg[(size_t)j * FP_ + ft * 16 + fr] = acc[jt][r4];
                }
        }
    }
}

// ---------------------------------------------------------------------------
// Exclusive prefix over chunk states (float4, 4 batched loads per step).
// ---------------------------------------------------------------------------
__global__ __launch_bounds__(256) void prefix_scan(
    float* __restrict__ Sloc, const float* __restrict__ Senc)
{
    const int Q = SSZ_ / 4;    // 4680
    int gid = blockIdx.x * 256 + threadIdx.x;
    if (gid >= 32 * Q) return;
    int bh = gid / Q, e = gid - bh * Q;
    float4 run = ((const float4*)Senc)[(size_t)bh * Q + e];
    float4* sl = (float4*)Sloc + (size_t)bh * NC_ * Q + e;
    #pragma unroll 1
    for (int cb = 0; cb < 8; ++cb) {
        float4 t0 = sl[(size_t)(cb * 4 + 0) * Q];
        float4 t1 = sl[(size_t)(cb * 4 + 1) * Q];
        float4 t2 = sl[(size_t)(cb * 4 + 2) * Q];
        float4 t3 = sl[(size_t)(cb * 4 + 3) * Q];
        sl[(size_t)(cb * 4 + 0) * Q] = run; run = add4(run, t0);
        sl[(size_t)(cb * 4 + 1) * Q] = run; run = add4(run, t1);
        sl[(size_t)(cb * 4 + 2) * Q] = run; run = add4(run, t2);
        sl[(size_t)(cb * 4 + 3) * Q] = run; run = add4(run, t3);
    }
}

// ---------------------------------------------------------------------------
// MFMA attn_chunk (unchanged from round 4).
// ---------------------------------------------------------------------------
template <int FW>
__device__ __forceinline__ void y2_slice(
    int f0, const float* __restrict__ Stg, const float* qs,
    unsigned short* QFH, unsigned short* QFL,
    unsigned short* STH, unsigned short* STL,
    f4v (&acc)[5], int w, int fr, int g, int t)
{
    for (int i = t; i < 64 * FW; i += 256) {
        int row = i / FW, cc = i % FW;
        int f = f0 + cc;
        float qv;
        if (f == 0)       qv = 1.0f;
        else if (f < 17)  qv = qs[row * 20 + (f - 1)] * 0.5f;
        else if (f < 273) qv = qs[row * 20 + ((f - 17) >> 4)] * qs[row * 20 + ((f - 17) & 15)] * C2C_;
        else              qv = 0.0f;
        unsigned short h, l; split1(qv, h, l);
        QFH[row * 72 + cc] = h;
        QFL[row * 72 + cc] = l;
    }
    const int NB4 = FW / 4;
    for (int i = t; i < 80 * NB4; i += 256) {
        int j = i / NB4, c4 = i % NB4;
        float4 ld;
        if (j < 65) ld = *(const float4*)&Stg[(size_t)j * FP_ + f0 + c4 * 4];
        else        ld = make_float4(0.f, 0.f, 0.f, 0.f);
        u16x4 h, l; splitf4(ld, h, l);
        *(u16x4*)&STH[j * 72 + c4 * 4] = h;
        *(u16x4*)&STL[j * 72 + c4 * 4] = l;
    }
    __syncthreads();
    #pragma unroll
    for (int ks2 = 0; ks2 < FW / 32; ++ks2) {
        s8v ah = *(const s8v*)&QFH[(16 * w + fr) * 72 + ks2 * 32 + g * 8];
        s8v al = *(const s8v*)&QFL[(16 * w + fr) * 72 + ks2 * 32 + g * 8];
        #pragma unroll
        for (int jt = 0; jt < 5; ++jt) {
            s8v bh_ = *(const s8v*)&STH[(jt * 16 + fr) * 72 + ks2 * 32 + g * 8];
            s8v bl_ = *(const s8v*)&STL[(jt * 16 + fr) * 72 + ks2 * 32 + g * 8];
            acc[jt] = MFMA_(ah, bh_, acc[jt], 0, 0, 0);
            acc[jt] = MFMA_(ah, bl_, acc[jt], 0, 0, 0);
            acc[jt] = MFMA_(al, bh_, acc[jt], 0, 0, 0);
        }
    }
    __syncthreads();
}

__global__ __launch_bounds__(256) void attn_chunk(
    const float* __restrict__ qp, const float* __restrict__ kp,
    const float* __restrict__ v, const float* __restrict__ Spre,
    float* __restrict__ out)
{
    __shared__ unsigned short U[20736];
    __shared__ float qs[64 * 20];
    __shared__ float den_s[64];
    unsigned short* AH  = U;            // [64][72]
    unsigned short* AL  = U + 4608;
    unsigned short* QH  = U + 9216;     // [64][40]
    unsigned short* QL  = U + 11776;
    unsigned short* KH  = U + 14336;
    unsigned short* KL  = U + 16896;
    unsigned short* VTH = U + 9216;     // [80][72]
    unsigned short* VTL = U + 14976;
    unsigned short* QFH = U;            // [64][72]
    unsigned short* QFL = U + 4608;
    unsigned short* STH = U + 9216;     // [80][72]
    unsigned short* STL = U + 14976;

    int bid = blockIdx.x;
    int bh = bid >> 5, c = bid & 31;
    int b = bh >> 4, h = bh & 15;
    int t = threadIdx.x;
    int w = t >> 6, lane = t & 63, fr = lane & 15, g = lane >> 4;
    int rowbase = b * N_ + c * CHK_;

    {
        int r = t >> 2, q4 = t & 3;
        float4 qv = *(const float4*)&qp[(size_t)(rowbase + r) * 256 + h * 16 + q4 * 4];
        float4 kv = *(const float4*)&kp[(size_t)(rowbase + r) * 256 + h * 16 + q4 * 4];
        u16x4 hh, ll;
        splitf4(qv, hh, ll);
        *(u16x4*)&QH[r * 40 + q4 * 4] = hh;
        *(u16x4*)&QL[r * 40 + q4 * 4] = ll;
        splitf4(kv, hh, ll);
        *(u16x4*)&KH[r * 40 + q4 * 4] = hh;
        *(u16x4*)&KL[r * 40 + q4 * 4] = ll;
        u16x4 z4 = (u16x4){0, 0, 0, 0};
        *(u16x4*)&QH[r * 40 + 16 + q4 * 4] = z4;
        *(u16x4*)&QL[r * 40 + 16 + q4 * 4] = z4;
        *(u16x4*)&KH[r * 40 + 16 + q4 * 4] = z4;
        *(u16x4*)&KL[r * 40 + 16 + q4 * 4] = z4;
        qs[r * 20 + q4 * 4 + 0] = qv.x;
        qs[r * 20 + q4 * 4 + 1] = qv.y;
        qs[r * 20 + q4 * 4 + 2] = qv.z;
        qs[r * 20 + q4 * 4 + 3] = qv.w;
    }
    __syncthreads();

    {
        s8v qh = *(const s8v*)&QH[(16 * w + fr) * 40 + g * 8];
        s8v ql = *(const s8v*)&QL[(16 * w + fr) * 40 + g * 8];
        f4v sacc[4];
        #pragma unroll
        for (int jt = 0; jt < 4; ++jt) sacc[jt] = (f4v){0.f, 0.f, 0.f, 0.f};
        #pragma unroll
        for (int jt = 0; jt < 4; ++jt) {
            s8v kh = *(const s8v*)&KH[(jt * 16 + fr) * 40 + g * 8];
            s8v kl = *(const s8v*)&KL[(jt * 16 + fr) * 40 + g * 8];
            sacc[jt] = MFMA_(qh, kh, sacc[jt], 0, 0, 0);
            sacc[jt] = MFMA_(qh, kl, sacc[jt], 0, 0, 0);
            sacc[jt] = MFMA_(ql, kh, sacc[jt], 0, 0, 0);
        }
        #pragma unroll
        for (int jt = 0; jt < 4; ++jt)
            #pragma unroll
            for (int r4 = 0; r4 < 4; ++r4) {
                int row = 16 * w + g * 4 + r4, col = jt * 16 + fr;
                float s = sacc[jt][r4];
                float a = (row >= col) ? (fmaf(s, 0.25f, 1.0f) + s * s * 0.03125f) : 0.f;
                unsigned short hh, ll; split1(a, hh, ll);
                AH[row * 72 + col] = hh;
                AL[row * 72 + col] = ll;
            }
    }
    __syncthreads();

    for (int i = t; i < 80 * 64; i += 256) {
        int j = i >> 6, m = i & 63;
        float val;
        if (j < 64)       val = v[((size_t)bh * N_ + c * CHK_ + m) * HD_ + j];
        else if (j == 64) val = 1.0f;
        else              val = 0.0f;
        unsigned short hh, ll; split1(val, hh, ll);
        VTH[j * 72 + m] = hh;
        VTL[j * 72 + m] = ll;
    }
    __syncthreads();

    f4v acc[5];
    #pragma unroll
    for (int jt = 0; jt < 5; ++jt) acc[jt] = (f4v){0.f, 0.f, 0.f, 0.f};
    #pragma unroll
    for (int ks2 = 0; ks2 < 2; ++ks2) {
        s8v ah = *(const s8v*)&AH[(16 * w + fr) * 72 + ks2 * 32 + g * 8];
        s8v al = *(const s8v*)&AL[(16 * w + fr) * 72 + ks2 * 32 + g * 8];
        #pragma unroll
        for (int jt = 0; jt < 5; ++jt) {
            s8v bh_ = *(const s8v*)&VTH[(jt * 16 + fr) * 72 + ks2 * 32 + g * 8];
            s8v bl_ = *(const s8v*)&VTL[(jt * 16 + fr) * 72 + ks2 * 32 + g * 8];
            acc[jt] = MFMA_(ah, bh_, acc[jt], 0, 0, 0);
            acc[jt] = MFMA_(ah, bl_, acc[jt], 0, 0, 0);
            acc[jt] = MFMA_(al, bh_, acc[jt], 0, 0, 0);
        }
    }
    __syncthreads();

    const float* Stg = Spre + ((size_t)bh * NC_ + c) * SSZ_;
    for (int p = 0; p < 4; ++p)
        y2_slice<64>(p * 64, Stg, qs, QFH, QFL, STH, STL, acc, w, fr, g, t);
    y2_slice<32>(256, Stg, qs, QFH, QFL, STH, STL, acc, w, fr, g, t);

    if (fr == 0) {
        #pragma unroll
        for (int r4 = 0; r4 < 4; ++r4)
            den_s[16 * w + g * 4 + r4] = acc[4][r4];
    }
    __syncthreads();
    #pragma unroll
    for (int r4 = 0; r4 < 4; ++r4) {
        float z = 1.0f / (den_s[16 * w + g * 4 + r4] + EPS_);
        int row = rowbase + 16 * w + g * 4 + r4;
        #pragma unroll
        for (int jt = 0; jt < 4; ++jt)
            out[(size_t)row * 1024 + h * 64 + jt * 16 + fr] = acc[jt][r4] * z;
    }
}

// ---------------------------------------------------------------------------
extern "C" void kernel_launch(void* const* d_in, const int* in_sizes, int n_in,
                              void* d_out, int out_size, void* d_ws, size_t ws_size,
                              hipStream_t stream)
{
    const float* x    = (const float*)d_in[0];
    const float* Wq   = (const float*)d_in[1];
    const float* Wk   = (const float*)d_in[2];
    const float* Wv   = (const float*)d_in[3];
    const float* Wke  = (const float*)d_in[4];
    const float* Wve  = (const float*)d_in[5];
    const float* Wout = (const float*)d_in[6];
    float* out = (float*)d_out;
    float* ws  = (float*)d_ws;

    float* tmpq  = ws;                                 // [4096][256]
    float* tmpk  = tmpq  + (size_t)4096 * 256;         // [4096][256]
    float* tmpke = tmpk  + (size_t)4096 * 256;         // [1024][256]
    float* v     = tmpke + (size_t)1024 * 256;         // [32][2048][64]
    float* ve    = v     + (size_t)32 * N_ * HD_;      // [32][512][64]
    float* Sloc  = ve    + (size_t)32 * ENC_ * HD_;    // [32][32][18720]
    float* Senc  = Sloc  + (size_t)32 * NC_ * SSZ_;    // [32][18720]
    float* attn  = Senc  + (size_t)32 * SSZ_;          // [4096][1024]

    dim3 blk(256);

    proj_all<<<928, blk, 0, stream>>>(x, Wq, Wk, Wv, Wke, Wve,
                                      tmpq, tmpk, v, tmpke, ve);
    state_all<<<160 + 32 * NC_, blk, 0, stream>>>(tmpke, ve, Senc, tmpk, v, Sloc);
    prefix_scan<<<(32 * (SSZ_ / 4) + 255) / 256, blk, 0, stream>>>(Sloc, Senc);
    attn_chunk<<<32 * NC_, blk, 0, stream>>>(tmpq, tmpk, v, Sloc, attn);
    mfma_gemm<<<dim3(16, 32), blk, 0, stream>>>(attn, Wout, out, 1024, 1024, 4096, 0, 0);
}

// Round 6
// 234.865 us; speedup vs baseline: 3.9045x; 1.0252x over previous
//
#include <hip/hip_runtime.h>

// Problem constants
#define B_    2
#define N_    2048
#define H_    16
#define HD_   64
#define ENC_  512
#define FP_   288
#define CHK_  64
#define NC_   32
#define SSZ_  18720                  // transposed state: [65 j][288 f]
#define C2C_  0.17677669529663687f   // 1/(4*sqrt(2))
#define EPS_  1e-12f

using s8v   = __attribute__((ext_vector_type(8))) short;   // 8 bf16
using f4v   = __attribute__((ext_vector_type(4))) float;
using u16x4 = __attribute__((ext_vector_type(4))) unsigned short;
typedef unsigned short ushort_t;

__device__ __forceinline__ unsigned short bfh(float x) {
    unsigned int u = __float_as_uint(x);
    return (unsigned short)((u + 0x7FFF + ((u >> 16) & 1)) >> 16);
}
__device__ __forceinline__ float bff(unsigned short h) {
    return __uint_as_float(((unsigned int)h) << 16);
}
__device__ __forceinline__ void splitf4(float4 v, u16x4& h, u16x4& l) {
    unsigned short h0 = bfh(v.x), h1 = bfh(v.y), h2 = bfh(v.z), h3 = bfh(v.w);
    h = (u16x4){h0, h1, h2, h3};
    l = (u16x4){bfh(v.x - bff(h0)), bfh(v.y - bff(h1)),
                bfh(v.z - bff(h2)), bfh(v.w - bff(h3))};
}
__device__ __forceinline__ void split1(float x, unsigned short& h, unsigned short& l) {
    h = bfh(x); l = bfh(x - bff(h));
}
__device__ __forceinline__ float4 add4(float4 a, float4 b) {
    return make_float4(a.x + b.x, a.y + b.y, a.z + b.z, a.w + b.w);
}

#define MFMA_ __builtin_amdgcn_mfma_f32_16x16x32_bf16

// ---------------------------------------------------------------------------
// split_all: x -> xh/xl ; [Wq;Wk;Wv] -> w1h/w1l ; [Wke;Wve] -> w2h/w2l.
// One float4 per thread, exact grid (6912 blocks).
// ---------------------------------------------------------------------------
#define X_F4   1048576      // 4096*1024/4
#define W1_F4  393216       // 1536*256
#define W2_F4  327680       // 1280*256

__global__ __launch_bounds__(256) void split_all(
    const float* __restrict__ x,
    const float* __restrict__ Wq, const float* __restrict__ Wk,
    const float* __restrict__ Wv, const float* __restrict__ Wke,
    const float* __restrict__ Wve,
    ushort_t* __restrict__ xh, ushort_t* __restrict__ xl,
    ushort_t* __restrict__ w1h, ushort_t* __restrict__ w1l,
    ushort_t* __restrict__ w2h, ushort_t* __restrict__ w2l)
{
    int gid = blockIdx.x * 256 + threadIdx.x;
    if (gid < X_F4) {
        float4 vv = ((const float4*)x)[gid];
        u16x4 h, l; splitf4(vv, h, l);
        ((u16x4*)xh)[gid] = h; ((u16x4*)xl)[gid] = l;
    } else if (gid < X_F4 + W1_F4) {
        int i = gid - X_F4;
        int row = i >> 8, c4 = i & 255;
        const float* s = (row < 256) ? Wq + (size_t)row * 1024
                       : (row < 512) ? Wk + (size_t)(row - 256) * 1024
                                     : Wv + (size_t)(row - 512) * 1024;
        float4 vv = *(const float4*)(s + c4 * 4);
        u16x4 h, l; splitf4(vv, h, l);
        ((u16x4*)w1h)[i] = h; ((u16x4*)w1l)[i] = l;
    } else {
        int i = gid - X_F4 - W1_F4;
        int row = i >> 8, c4 = i & 255;
        const float* s = (row < 256) ? Wke + (size_t)row * 1024
                                     : Wve + (size_t)(row - 256) * 1024;
        float4 vv = *(const float4*)(s + c4 * 4);
        u16x4 h, l; splitf4(vv, h, l);
        ((u16x4*)w2h)[i] = h; ((u16x4*)w2l)[i] = l;
    }
}

// Wout split (runs late; dest overlays dead tmpq region)
__global__ __launch_bounds__(256) void split_wo(
    const float* __restrict__ Wout, ushort_t* __restrict__ woh, ushort_t* __restrict__ wol)
{
    int gid = blockIdx.x * 256 + threadIdx.x;   // 262144 f4
    float4 vv = ((const float4*)Wout)[gid];
    u16x4 h, l; splitf4(vv, h, l);
    ((u16x4*)woh)[gid] = h; ((u16x4*)wol)[gid] = l;
}

// ---------------------------------------------------------------------------
// Pure-bf16 3-pass GEMM body: acc = A @ W^T, A/W pre-split hi/lo bf16.
// BM=128, BN=64, BK=32, K=1024 fixed, 256 threads = 4 waves.
// Row remap a_row = (gr/rpb)*rowjump + gr%rpb.
// ---------------------------------------------------------------------------
__device__ __forceinline__ void bg_body(
    const ushort_t* __restrict__ Ah, const ushort_t* __restrict__ Al,
    const ushort_t* __restrict__ Wh, const ushort_t* __restrict__ Wl,
    int bx, int by, int rpb, int rowjump,
    ushort_t* SAh, ushort_t* SAl, ushort_t* SBh, ushort_t* SBl,
    f4v (&acc)[4][2])
{
    int t = threadIdx.x;
    int row0 = by * 128, col0 = bx * 64;
    int ar = t >> 1;
    int kc = (t & 1) * 16;
    int gr = row0 + ar;
    size_t arow = (size_t)(gr / rpb) * rowjump + (gr % rpb);
    const ushort_t* aph = Ah + arow * 1024 + kc;
    const ushort_t* apl = Al + arow * 1024 + kc;
    const ushort_t* wph = Wh + (size_t)(col0 + (ar & 63)) * 1024 + kc;
    const ushort_t* wpl = Wl + (size_t)(col0 + (ar & 63)) * 1024 + kc;

    int w = t >> 6, lane = t & 63;
    int wrow = (w >> 1) * 64, wcol = (w & 1) * 32;
    int fr = lane & 15, g = lane >> 4;

    #pragma unroll
    for (int mt = 0; mt < 4; ++mt)
        #pragma unroll
        for (int nt = 0; nt < 2; ++nt) acc[mt][nt] = (f4v){0.f, 0.f, 0.f, 0.f};

    for (int k0 = 0; k0 < 1024; k0 += 32) {
        *(s8v*)&SAh[ar * 40 + kc]     = *(const s8v*)(aph + k0);
        *(s8v*)&SAh[ar * 40 + kc + 8] = *(const s8v*)(aph + k0 + 8);
        *(s8v*)&SAl[ar * 40 + kc]     = *(const s8v*)(apl + k0);
        *(s8v*)&SAl[ar * 40 + kc + 8] = *(const s8v*)(apl + k0 + 8);
        if (t < 128) {
            *(s8v*)&SBh[ar * 40 + kc]     = *(const s8v*)(wph + k0);
            *(s8v*)&SBh[ar * 40 + kc + 8] = *(const s8v*)(wph + k0 + 8);
            *(s8v*)&SBl[ar * 40 + kc]     = *(const s8v*)(wpl + k0);
            *(s8v*)&SBl[ar * 40 + kc + 8] = *(const s8v*)(wpl + k0 + 8);
        }
        __syncthreads();
        s8v ah[4], al_[4], bh_[2], bl_[2];
        #pragma unroll
        for (int mt = 0; mt < 4; ++mt) {
            ah[mt]  = *(const s8v*)&SAh[(wrow + mt * 16 + fr) * 40 + g * 8];
            al_[mt] = *(const s8v*)&SAl[(wrow + mt * 16 + fr) * 40 + g * 8];
        }
        #pragma unroll
        for (int nt = 0; nt < 2; ++nt) {
            bh_[nt] = *(const s8v*)&SBh[(wcol + nt * 16 + fr) * 40 + g * 8];
            bl_[nt] = *(const s8v*)&SBl[(wcol + nt * 16 + fr) * 40 + g * 8];
        }
        #pragma unroll
        for (int mt = 0; mt < 4; ++mt)
            #pragma unroll
            for (int nt = 0; nt < 2; ++nt) {
                acc[mt][nt] = MFMA_(ah[mt],  bh_[nt], acc[mt][nt], 0, 0, 0);
                acc[mt][nt] = MFMA_(ah[mt],  bl_[nt], acc[mt][nt], 0, 0, 0);
                acc[mt][nt] = MFMA_(al_[mt], bh_[nt], acc[mt][nt], 0, 0, 0);
            }
        __syncthreads();
    }
}

// ---------------------------------------------------------------------------
// proj2: main (x @ [Wq;Wk;Wv]^T, 768 blocks) + enc (x[b][:512] @ [Wke;Wve]^T,
// 160 blocks) with column-routed epilogue.
// ---------------------------------------------------------------------------
__global__ __launch_bounds__(256) void proj2(
    const ushort_t* __restrict__ xh, const ushort_t* __restrict__ xl,
    const ushort_t* __restrict__ w1h, const ushort_t* __restrict__ w1l,
    const ushort_t* __restrict__ w2h, const ushort_t* __restrict__ w2l,
    float* __restrict__ tmpq, float* __restrict__ tmpk, float* __restrict__ v,
    float* __restrict__ tmpke, float* __restrict__ ve)
{
    __shared__ ushort_t SM[15360];
    f4v acc[4][2];
    int blk = blockIdx.x;
    int t = threadIdx.x, w = t >> 6, lane = t & 63;
    int wrow = (w >> 1) * 64, wcol = (w & 1) * 32;
    int fr = lane & 15, g = lane >> 4;

    if (blk < 768) {
        int bx = blk % 24, by = blk / 24;
        bg_body(xh, xl, w1h, w1l, bx, by, 4096, 0,
                SM, SM + 5120, SM + 10240, SM + 12800, acc);
        int row0 = by * 128, col0 = bx * 64;
        #pragma unroll
        for (int mt = 0; mt < 4; ++mt)
            #pragma unroll
            for (int nt = 0; nt < 2; ++nt)
                #pragma unroll
                for (int r4 = 0; r4 < 4; ++r4) {
                    int r  = row0 + wrow + mt * 16 + g * 4 + r4;
                    int cc = col0 + wcol + nt * 16 + fr;
                    float val = acc[mt][nt][r4];
                    if (cc < 256)      tmpq[(size_t)r * 256 + cc] = val;
                    else if (cc < 512) tmpk[(size_t)r * 256 + (cc - 256)] = val;
                    else {
                        int c2 = cc - 512, hh = c2 >> 6, jj = c2 & 63;
                        int bb = r >> 11, n = r & 2047;
                        v[(((size_t)(bb * 16 + hh)) * 2048 + n) * 64 + jj] = val;
                    }
                }
    } else {
        int r2 = blk - 768;
        int bx = r2 % 20, by = r2 / 20;
        bg_body(xh, xl, w2h, w2l, bx, by, 512, 2048,
                SM, SM + 5120, SM + 10240, SM + 12800, acc);
        int row0 = by * 128, col0 = bx * 64;
        #pragma unroll
        for (int mt = 0; mt < 4; ++mt)
            #pragma unroll
            for (int nt = 0; nt < 2; ++nt)
                #pragma unroll
                for (int r4 = 0; r4 < 4; ++r4) {
                    int r  = row0 + wrow + mt * 16 + g * 4 + r4;
                    int cc = col0 + wcol + nt * 16 + fr;
                    float val = acc[mt][nt][r4];
                    if (cc < 256) tmpke[(size_t)r * 256 + cc] = val;
                    else {
                        int c2 = cc - 256, hh = c2 >> 6, jj = c2 & 63;
                        int bb = r >> 9, n = r & 511;
                        ve[(((size_t)(bb * 16 + hh)) * 512 + n) * 64 + jj] = val;
                    }
                }
    }
}

// out_gemm: attn(bf16 hi/lo) @ Wout^T -> f32 d_out
__global__ __launch_bounds__(256) void out_gemm(
    const ushort_t* __restrict__ Ah, const ushort_t* __restrict__ Al,
    const ushort_t* __restrict__ Wh, const ushort_t* __restrict__ Wl,
    float* __restrict__ out)
{
    __shared__ ushort_t SM[15360];
    f4v acc[4][2];
    bg_body(Ah, Al, Wh, Wl, blockIdx.x, blockIdx.y, 4096, 0,
            SM, SM + 5120, SM + 10240, SM + 12800, acc);
    int t = threadIdx.x, w = t >> 6, lane = t & 63;
    int wrow = (w >> 1) * 64, wcol = (w & 1) * 32;
    int fr = lane & 15, g = lane >> 4;
    int row0 = blockIdx.y * 128, col0 = blockIdx.x * 64;
    #pragma unroll
    for (int mt = 0; mt < 4; ++mt)
        #pragma unroll
        for (int nt = 0; nt < 2; ++nt)
            #pragma unroll
            for (int r4 = 0; r4 < 4; ++r4) {
                int r  = row0 + wrow + mt * 16 + g * 4 + r4;
                int cc = col0 + wcol + nt * 16 + fr;
                out[(size_t)r * 1024 + cc] = acc[mt][nt][r4];
            }
}

// ---------------------------------------------------------------------------
// MFMA state kernel (unchanged from round 5).
// ---------------------------------------------------------------------------
__device__ __forceinline__ void st_stage(
    const float* __restrict__ Kp, const float* __restrict__ V,
    size_t krow0, size_t vrow0, int h, int t,
    float* ksT, ushort_t* VTH, ushort_t* VTL)
{
    {
        int r = t >> 2, q4 = t & 3;
        float4 kv = *(const float4*)&Kp[(krow0 + r) * 256 + h * 16 + q4 * 4];
        ksT[(q4 * 4 + 0) * 68 + r] = kv.x;
        ksT[(q4 * 4 + 1) * 68 + r] = kv.y;
        ksT[(q4 * 4 + 2) * 68 + r] = kv.z;
        ksT[(q4 * 4 + 3) * 68 + r] = kv.w;
    }
    if (t < 64) ksT[16 * 68 + t] = 1.0f;
    {
        int r = t & 63, jg = t >> 6;
        #pragma unroll
        for (int cc = 0; cc < 4; ++cc) {
            float4 vv = *(const float4*)&V[(vrow0 + r) * HD_ + jg * 16 + cc * 4];
            float vals[4] = {vv.x, vv.y, vv.z, vv.w};
            #pragma unroll
            for (int e = 0; e < 4; ++e) {
                int j = jg * 16 + cc * 4 + e;
                unsigned short hh, ll; split1(vals[e], hh, ll);
                VTH[j * 72 + r] = hh;
                VTL[j * 72 + r] = ll;
            }
        }
    }
    if (t < 64) { VTH[64 * 72 + t] = 0x3F80; VTL[64 * 72 + t] = 0; }
}

__device__ __forceinline__ void st_ftile(
    const float* ksT, int ft, int fr, int g,
    const s8v (&AHf)[2][5], const s8v (&ALf)[2][5], f4v (&acc)[5])
{
    int f = ft * 16 + fr;
    int fi, fj; float scale;
    if (f == 0)       { fi = 16; fj = 16; scale = 1.0f; }
    else if (f < 17)  { fi = f - 1; fj = 16; scale = 0.5f; }
    else if (f < 273) { fi = (f - 17) >> 4; fj = (f - 17) & 15; scale = C2C_; }
    else              { fi = 16; fj = 16; scale = 0.0f; }
    #pragma unroll
    for (int ks2 = 0; ks2 < 2; ++ks2) {
        const float* pa = ksT + fi * 68 + ks2 * 32 + g * 8;
        const float* pb = ksT + fj * 68 + ks2 * 32 + g * 8;
        s8v bhv, blv;
        #pragma unroll
        for (int e = 0; e < 8; ++e) {
            float val = pa[e] * pb[e] * scale;
            unsigned short hh, ll; split1(val, hh, ll);
            bhv[e] = (short)hh; blv[e] = (short)ll;
        }
        #pragma unroll
        for (int jt = 0; jt < 5; ++jt) {
            acc[jt] = MFMA_(AHf[ks2][jt], bhv, acc[jt], 0, 0, 0);
            acc[jt] = MFMA_(AHf[ks2][jt], blv, acc[jt], 0, 0, 0);
            acc[jt] = MFMA_(ALf[ks2][jt], bhv, acc[jt], 0, 0, 0);
        }
    }
}

__global__ __launch_bounds__(256) void state_all(
    const float* __restrict__ Kpe, const float* __restrict__ Ve, float* __restrict__ Se,
    const float* __restrict__ Kpc, const float* __restrict__ Vc, float* __restrict__ Sc)
{
    __shared__ float ksT[17 * 68];
    __shared__ ushort_t VTH[80 * 72], VTL[80 * 72];
    int blk = blockIdx.x, t = threadIdx.x;
    int w = t >> 6, lane = t & 63, fr = lane & 15, g = lane >> 4;

    for (int i = t; i < 15 * 72; i += 256) { VTH[65 * 72 + i] = 0; VTL[65 * 72 + i] = 0; }

    if (blk >= 160) {
        int b2 = blk - 160;
        int c = b2 & 31, bh = b2 >> 5;
        int b = bh >> 4, h = bh & 15;
        float* Sg = Sc + ((size_t)bh * NC_ + c) * SSZ_;
        st_stage(Kpc, Vc, (size_t)b * 2048 + c * 64, (size_t)bh * 2048 + c * 64,
                 h, t, ksT, VTH, VTL);
        __syncthreads();
        s8v AHf[2][5], ALf[2][5];
        #pragma unroll
        for (int ks2 = 0; ks2 < 2; ++ks2)
            #pragma unroll
            for (int jt = 0; jt < 5; ++jt) {
                AHf[ks2][jt] = *(const s8v*)&VTH[(jt * 16 + fr) * 72 + ks2 * 32 + g * 8];
                ALf[ks2][jt] = *(const s8v*)&VTL[(jt * 16 + fr) * 72 + ks2 * 32 + g * 8];
            }
        for (int ft = w; ft < 18; ft += 4) {
            f4v acc[5];
            #pragma unroll
            for (int jt = 0; jt < 5; ++jt) acc[jt] = (f4v){0.f, 0.f, 0.f, 0.f};
            st_ftile(ksT, ft, fr, g, AHf, ALf, acc);
            #pragma unroll
            for (int jt = 0; jt < 5; ++jt)
                #pragma unroll
                for (int r4 = 0; r4 < 4; ++r4) {
                    int j = jt * 16 + g * 4 + r4;
                    if (j < 65) Sg[(size_t)j * FP_ + ft * 16 + fr] = acc[jt][r4];
                }
        }
    } else {
        int bh = blk / 5, fg = blk % 5;
        int b = bh >> 4, h = bh & 15;
        int ft = fg * 4 + w;
        float* Sg = Se + (size_t)bh * SSZ_;
        f4v acc[5];
        #pragma unroll
        for (int jt = 0; jt < 5; ++jt) acc[jt] = (f4v){0.f, 0.f, 0.f, 0.f};
        for (int m0 = 0; m0 < 512; m0 += 64) {
            if (m0) __syncthreads();
            st_stage(Kpe, Ve, (size_t)b * 512 + m0, (size_t)bh * 512 + m0,
                     h, t, ksT, VTH, VTL);
            __syncthreads();
            if (ft < 18) {
                s8v AHf[2][5], ALf[2][5];
                #pragma unroll
                for (int ks2 = 0; ks2 < 2; ++ks2)
                    #pragma unroll
                    for (int jt = 0; jt < 5; ++jt) {
                        AHf[ks2][jt] = *(const s8v*)&VTH[(jt * 16 + fr) * 72 + ks2 * 32 + g * 8];
                        ALf[ks2][jt] = *(const s8v*)&VTL[(jt * 16 + fr) * 72 + ks2 * 32 + g * 8];
                    }
                st_ftile(ksT, ft, fr, g, AHf, ALf, acc);
            }
        }
        if (ft < 18) {
            #pragma unroll
            for (int jt = 0; jt < 5; ++jt)
                #pragma unroll
                for (int r4 = 0; r4 < 4; ++r4) {
                    int j = jt * 16 + g * 4 + r4;
                    if (j < 65) Sg[(size_t)j * FP_ + ft * 16 + fr] = acc[jt][r4];
                }
        }
    }
}

// ---------------------------------------------------------------------------
// Exclusive prefix over chunk states (float4, 4 batched loads per step).
// ---------------------------------------------------------------------------
__global__ __launch_bounds__(256) void prefix_scan(
    float* __restrict__ Sloc, const float* __restrict__ Senc)
{
    const int Q = SSZ_ / 4;    // 4680
    int gid = blockIdx.x * 256 + threadIdx.x;
    if (gid >= 32 * Q) return;
    int bh = gid / Q, e = gid - bh * Q;
    float4 run = ((const float4*)Senc)[(size_t)bh * Q + e];
    float4* sl = (float4*)Sloc + (size_t)bh * NC_ * Q + e;
    #pragma unroll 1
    for (int cb = 0; cb < 8; ++cb) {
        float4 t0 = sl[(size_t)(cb * 4 + 0) * Q];
        float4 t1 = sl[(size_t)(cb * 4 + 1) * Q];
        float4 t2 = sl[(size_t)(cb * 4 + 2) * Q];
        float4 t3 = sl[(size_t)(cb * 4 + 3) * Q];
        sl[(size_t)(cb * 4 + 0) * Q] = run; run = add4(run, t0);
        sl[(size_t)(cb * 4 + 1) * Q] = run; run = add4(run, t1);
        sl[(size_t)(cb * 4 + 2) * Q] = run; run = add4(run, t2);
        sl[(size_t)(cb * 4 + 3) * Q] = run; run = add4(run, t3);
    }
}

// ---------------------------------------------------------------------------
// MFMA attn_chunk; epilogue writes pre-split bf16 (for the bf16 out-proj).
// ---------------------------------------------------------------------------
template <int FW>
__device__ __forceinline__ void y2_slice(
    int f0, const float* __restrict__ Stg, const float* qs,
    ushort_t* QFH, ushort_t* QFL,
    ushort_t* STH, ushort_t* STL,
    f4v (&acc)[5], int w, int fr, int g, int t)
{
    for (int i = t; i < 64 * FW; i += 256) {
        int row = i / FW, cc = i % FW;
        int f = f0 + cc;
        float qv;
        if (f == 0)       qv = 1.0f;
        else if (f < 17)  qv = qs[row * 20 + (f - 1)] * 0.5f;
        else if (f < 273) qv = qs[row * 20 + ((f - 17) >> 4)] * qs[row * 20 + ((f - 17) & 15)] * C2C_;
        else              qv = 0.0f;
        unsigned short h, l; split1(qv, h, l);
        QFH[row * 72 + cc] = h;
        QFL[row * 72 + cc] = l;
    }
    const int NB4 = FW / 4;
    for (int i = t; i < 80 * NB4; i += 256) {
        int j = i / NB4, c4 = i % NB4;
        float4 ld;
        if (j < 65) ld = *(const float4*)&Stg[(size_t)j * FP_ + f0 + c4 * 4];
        else        ld = make_float4(0.f, 0.f, 0.f, 0.f);
        u16x4 h, l; splitf4(ld, h, l);
        *(u16x4*)&STH[j * 72 + c4 * 4] = h;
        *(u16x4*)&STL[j * 72 + c4 * 4] = l;
    }
    __syncthreads();
    #pragma unroll
    for (int ks2 = 0; ks2 < FW / 32; ++ks2) {
        s8v ah = *(const s8v*)&QFH[(16 * w + fr) * 72 + ks2 * 32 + g * 8];
        s8v al = *(const s8v*)&QFL[(16 * w + fr) * 72 + ks2 * 32 + g * 8];
        #pragma unroll
        for (int jt = 0; jt < 5; ++jt) {
            s8v bh_ = *(const s8v*)&STH[(jt * 16 + fr) * 72 + ks2 * 32 + g * 8];
            s8v bl_ = *(const s8v*)&STL[(jt * 16 + fr) * 72 + ks2 * 32 + g * 8];
            acc[jt] = MFMA_(ah, bh_, acc[jt], 0, 0, 0);
            acc[jt] = MFMA_(ah, bl_, acc[jt], 0, 0, 0);
            acc[jt] = MFMA_(al, bh_, acc[jt], 0, 0, 0);
        }
    }
    __syncthreads();
}

__global__ __launch_bounds__(256) void attn_chunk(
    const float* __restrict__ qp, const float* __restrict__ kp,
    const float* __restrict__ v, const float* __restrict__ Spre,
    ushort_t* __restrict__ atnh, ushort_t* __restrict__ atnl)
{
    __shared__ ushort_t U[20736];
    __shared__ float qs[64 * 20];
    __shared__ float den_s[64];
    ushort_t* AH  = U;            // [64][72]
    ushort_t* AL  = U + 4608;
    ushort_t* QH  = U + 9216;     // [64][40]
    ushort_t* QL  = U + 11776;
    ushort_t* KH  = U + 14336;
    ushort_t* KL  = U + 16896;
    ushort_t* VTH = U + 9216;     // [80][72]
    ushort_t* VTL = U + 14976;
    ushort_t* QFH = U;            // [64][72]
    ushort_t* QFL = U + 4608;
    ushort_t* STH = U + 9216;     // [80][72]
    ushort_t* STL = U + 14976;

    int bid = blockIdx.x;
    int bh = bid >> 5, c = bid & 31;
    int b = bh >> 4, h = bh & 15;
    int t = threadIdx.x;
    int w = t >> 6, lane = t & 63, fr = lane & 15, g = lane >> 4;
    int rowbase = b * N_ + c * CHK_;

    {
        int r = t >> 2, q4 = t & 3;
        float4 qv = *(const float4*)&qp[(size_t)(rowbase + r) * 256 + h * 16 + q4 * 4];
        float4 kv = *(const float4*)&kp[(size_t)(rowbase + r) * 256 + h * 16 + q4 * 4];
        u16x4 hh, ll;
        splitf4(qv, hh, ll);
        *(u16x4*)&QH[r * 40 + q4 * 4] = hh;
        *(u16x4*)&QL[r * 40 + q4 * 4] = ll;
        splitf4(kv, hh, ll);
        *(u16x4*)&KH[r * 40 + q4 * 4] = hh;
        *(u16x4*)&KL[r * 40 + q4 * 4] = ll;
        u16x4 z4 = (u16x4){0, 0, 0, 0};
        *(u16x4*)&QH[r * 40 + 16 + q4 * 4] = z4;
        *(u16x4*)&QL[r * 40 + 16 + q4 * 4] = z4;
        *(u16x4*)&KH[r * 40 + 16 + q4 * 4] = z4;
        *(u16x4*)&KL[r * 40 + 16 + q4 * 4] = z4;
        qs[r * 20 + q4 * 4 + 0] = qv.x;
        qs[r * 20 + q4 * 4 + 1] = qv.y;
        qs[r * 20 + q4 * 4 + 2] = qv.z;
        qs[r * 20 + q4 * 4 + 3] = qv.w;
    }
    __syncthreads();

    {
        s8v qh = *(const s8v*)&QH[(16 * w + fr) * 40 + g * 8];
        s8v ql = *(const s8v*)&QL[(16 * w + fr) * 40 + g * 8];
        f4v sacc[4];
        #pragma unroll
        for (int jt = 0; jt < 4; ++jt) sacc[jt] = (f4v){0.f, 0.f, 0.f, 0.f};
        #pragma unroll
        for (int jt = 0; jt < 4; ++jt) {
            s8v kh = *(const s8v*)&KH[(jt * 16 + fr) * 40 + g * 8];
            s8v kl = *(const s8v*)&KL[(jt * 16 + fr) * 40 + g * 8];
            sacc[jt] = MFMA_(qh, kh, sacc[jt], 0, 0, 0);
            sacc[jt] = MFMA_(qh, kl, sacc[jt], 0, 0, 0);
            sacc[jt] = MFMA_(ql, kh, sacc[jt], 0, 0, 0);
        }
        #pragma unroll
        for (int jt = 0; jt < 4; ++jt)
            #pragma unroll
            for (int r4 = 0; r4 < 4; ++r4) {
                int row = 16 * w + g * 4 + r4, col = jt * 16 + fr;
                float s = sacc[jt][r4];
                float a = (row >= col) ? (fmaf(s, 0.25f, 1.0f) + s * s * 0.03125f) : 0.f;
                unsigned short hh, ll; split1(a, hh, ll);
                AH[row * 72 + col] = hh;
                AL[row * 72 + col] = ll;
            }
    }
    __syncthreads();

    for (int i = t; i < 80 * 64; i += 256) {
        int j = i >> 6, m = i & 63;
        float val;
        if (j < 64)       val = v[((size_t)bh * N_ + c * CHK_ + m) * HD_ + j];
        else if (j == 64) val = 1.0f;
        else              val = 0.0f;
        unsigned short hh, ll; split1(val, hh, ll);
        VTH[j * 72 + m] = hh;
        VTL[j * 72 + m] = ll;
    }
    __syncthreads();

    f4v acc[5];
    #pragma unroll
    for (int jt = 0; jt < 5; ++jt) acc[jt] = (f4v){0.f, 0.f, 0.f, 0.f};
    #pragma unroll
    for (int ks2 = 0; ks2 < 2; ++ks2) {
        s8v ah = *(const s8v*)&AH[(16 * w + fr) * 72 + ks2 * 32 + g * 8];
        s8v al = *(const s8v*)&AL[(16 * w + fr) * 72 + ks2 * 32 + g * 8];
        #pragma unroll
        for (int jt = 0; jt < 5; ++jt) {
            s8v bh_ = *(const s8v*)&VTH[(jt * 16 + fr) * 72 + ks2 * 32 + g * 8];
            s8v bl_ = *(const s8v*)&VTL[(jt * 16 + fr) * 72 + ks2 * 32 + g * 8];
            acc[jt] = MFMA_(ah, bh_, acc[jt], 0, 0, 0);
            acc[jt] = MFMA_(ah, bl_, acc[jt], 0, 0, 0);
            acc[jt] = MFMA_(al, bh_, acc[jt], 0, 0, 0);
        }
    }
    __syncthreads();

    const float* Stg = Spre + ((size_t)bh * NC_ + c) * SSZ_;
    for (int p = 0; p < 4; ++p)
        y2_slice<64>(p * 64, Stg, qs, QFH, QFL, STH, STL, acc, w, fr, g, t);
    y2_slice<32>(256, Stg, qs, QFH, QFL, STH, STL, acc, w, fr, g, t);

    if (fr == 0) {
        #pragma unroll
        for (int r4 = 0; r4 < 4; ++r4)
            den_s[16 * w + g * 4 + r4] = acc[4][r4];
    }
    __syncthreads();
    #pragma unroll
    for (int r4 = 0; r4 < 4; ++r4) {
        float z = 1.0f / (den_s[16 * w + g * 4 + r4] + EPS_);
        int row = rowbase + 16 * w + g * 4 + r4;
        #pragma unroll
        for (int jt = 0; jt < 4; ++jt) {
            float val = acc[jt][r4] * z;
            unsigned short hh, ll; split1(val, hh, ll);
            size_t idx = (size_t)row * 1024 + h * 64 + jt * 16 + fr;
            atnh[idx] = hh;
            atnl[idx] = ll;
        }
    }
}

// ---------------------------------------------------------------------------
extern "C" void kernel_launch(void* const* d_in, const int* in_sizes, int n_in,
                              void* d_out, int out_size, void* d_ws, size_t ws_size,
                              hipStream_t stream)
{
    const float* x    = (const float*)d_in[0];
    const float* Wq   = (const float*)d_in[1];
    const float* Wk   = (const float*)d_in[2];
    const float* Wv   = (const float*)d_in[3];
    const float* Wke  = (const float*)d_in[4];
    const float* Wve  = (const float*)d_in[5];
    const float* Wout = (const float*)d_in[6];
    float* out = (float*)d_out;
    float* ws  = (float*)d_ws;

    // f32 region (~109.5 MB)
    float* tmpq  = ws;                                 // 1,048,576
    float* tmpk  = tmpq  + (size_t)1048576;            // 1,048,576
    float* tmpke = tmpk  + (size_t)1048576;            //   262,144
    float* v     = tmpke + (size_t)262144;             // 4,194,304
    float* ve    = v     + (size_t)4194304;            // 1,048,576
    float* Sloc  = ve    + (size_t)1048576;            // 19,169,280
    float* Senc  = Sloc  + (size_t)19169280;           //   599,040
    // bf16 region (~16.8 MB)
    ushort_t* xh = (ushort_t*)(Senc + 599040);         // 4,194,304 shorts
    ushort_t* xl = xh + (size_t)4194304;               // 4,194,304 shorts
    // overlays:
    ushort_t* w1h = (ushort_t*)Sloc;                   // 1,572,864 (dead before state_all)
    ushort_t* w1l = w1h + (size_t)1572864;
    ushort_t* w2h = w1l + (size_t)1572864;             // 1,310,720
    ushort_t* w2l = w2h + (size_t)1310720;
    ushort_t* woh = (ushort_t*)tmpq;                   // 1,048,576 (tmpq dead after attn)
    ushort_t* wol = woh + (size_t)1048576;
    ushort_t* atnh = xh;                               // xh/xl dead after proj2
    ushort_t* atnl = xl;

    dim3 blk(256);

    split_all<<<6912, blk, 0, stream>>>(x, Wq, Wk, Wv, Wke, Wve,
                                        xh, xl, w1h, w1l, w2h, w2l);
    proj2<<<928, blk, 0, stream>>>(xh, xl, w1h, w1l, w2h, w2l,
                                   tmpq, tmpk, v, tmpke, ve);
    state_all<<<160 + 32 * NC_, blk, 0, stream>>>(tmpke, ve, Senc, tmpk, v, Sloc);
    prefix_scan<<<(32 * (SSZ_ / 4) + 255) / 256, blk, 0, stream>>>(Sloc, Senc);
    attn_chunk<<<32 * NC_, blk, 0, stream>>>(tmpq, tmpk, v, Sloc, atnh, atnl);
    split_wo<<<1024, blk, 0, stream>>>(Wout, woh, wol);
    out_gemm<<<dim3(16, 32), blk, 0, stream>>>(atnh, atnl, woh, wol, out);
}

// Round 7
// 223.032 us; speedup vs baseline: 4.1117x; 1.0531x over previous
//
#include <hip/hip_runtime.h>

// Problem constants
#define B_    2
#define N_    2048
#define H_    16
#define HD_   64
#define ENC_  512
#define FP_   288
#define CHK_  64
#define NC_   32
#define SSZ_  18720                  // state elems: [65 j][288 f]; stored as hi/lo bf16 planes
#define C2C_  0.17677669529663687f   // 1/(4*sqrt(2))
#define EPS_  1e-12f

using s8v   = __attribute__((ext_vector_type(8))) short;   // 8 bf16
using f4v   = __attribute__((ext_vector_type(4))) float;
using u16x4 = __attribute__((ext_vector_type(4))) unsigned short;
typedef unsigned short ushort_t;

__device__ __forceinline__ unsigned short bfh(float x) {
    unsigned int u = __float_as_uint(x);
    return (unsigned short)((u + 0x7FFF + ((u >> 16) & 1)) >> 16);
}
__device__ __forceinline__ float bff(unsigned short h) {
    return __uint_as_float(((unsigned int)h) << 16);
}
__device__ __forceinline__ void splitf4(float4 v, u16x4& h, u16x4& l) {
    unsigned short h0 = bfh(v.x), h1 = bfh(v.y), h2 = bfh(v.z), h3 = bfh(v.w);
    h = (u16x4){h0, h1, h2, h3};
    l = (u16x4){bfh(v.x - bff(h0)), bfh(v.y - bff(h1)),
                bfh(v.z - bff(h2)), bfh(v.w - bff(h3))};
}
__device__ __forceinline__ void split1(float x, unsigned short& h, unsigned short& l) {
    h = bfh(x); l = bfh(x - bff(h));
}

#define MFMA_ __builtin_amdgcn_mfma_f32_16x16x32_bf16

// bijective XCD swizzle (m204): group ~nwg/8 consecutive ids per XCD
__device__ __forceinline__ int xcd_swz(int b, int nwg) {
    int q = nwg >> 3, r = nwg & 7;
    int xcd = b & 7, loc = b >> 3;
    return (xcd < r ? xcd * (q + 1) : r * (q + 1) + (xcd - r) * q) + loc;
}

// ---------------------------------------------------------------------------
// split_all: x -> xh/xl ; [Wq;Wk;Wv] -> w1h/w1l ; [Wke;Wve] -> w2h/w2l.
// ---------------------------------------------------------------------------
#define X_F4   1048576      // 4096*1024/4
#define W1_F4  393216       // 1536*256
#define W2_F4  327680       // 1280*256

__global__ __launch_bounds__(256) void split_all(
    const float* __restrict__ x,
    const float* __restrict__ Wq, const float* __restrict__ Wk,
    const float* __restrict__ Wv, const float* __restrict__ Wke,
    const float* __restrict__ Wve,
    ushort_t* __restrict__ xh, ushort_t* __restrict__ xl,
    ushort_t* __restrict__ w1h, ushort_t* __restrict__ w1l,
    ushort_t* __restrict__ w2h, ushort_t* __restrict__ w2l)
{
    int gid = blockIdx.x * 256 + threadIdx.x;
    if (gid < X_F4) {
        float4 vv = ((const float4*)x)[gid];
        u16x4 h, l; splitf4(vv, h, l);
        ((u16x4*)xh)[gid] = h; ((u16x4*)xl)[gid] = l;
    } else if (gid < X_F4 + W1_F4) {
        int i = gid - X_F4;
        int row = i >> 8, c4 = i & 255;
        const float* s = (row < 256) ? Wq + (size_t)row * 1024
                       : (row < 512) ? Wk + (size_t)(row - 256) * 1024
                                     : Wv + (size_t)(row - 512) * 1024;
        float4 vv = *(const float4*)(s + c4 * 4);
        u16x4 h, l; splitf4(vv, h, l);
        ((u16x4*)w1h)[i] = h; ((u16x4*)w1l)[i] = l;
    } else {
        int i = gid - X_F4 - W1_F4;
        int row = i >> 8, c4 = i & 255;
        const float* s = (row < 256) ? Wke + (size_t)row * 1024
                                     : Wve + (size_t)(row - 256) * 1024;
        float4 vv = *(const float4*)(s + c4 * 4);
        u16x4 h, l; splitf4(vv, h, l);
        ((u16x4*)w2h)[i] = h; ((u16x4*)w2l)[i] = l;
    }
}

__global__ __launch_bounds__(256) void split_wo(
    const float* __restrict__ Wout, ushort_t* __restrict__ woh, ushort_t* __restrict__ wol)
{
    int gid = blockIdx.x * 256 + threadIdx.x;   // 262144 f4
    float4 vv = ((const float4*)Wout)[gid];
    u16x4 h, l; splitf4(vv, h, l);
    ((u16x4*)woh)[gid] = h; ((u16x4*)wol)[gid] = l;
}

// ---------------------------------------------------------------------------
// Pure-bf16 3-pass GEMM body, BM=128, BN=128, BK=32, 4 waves (2x2).
// 16 ds_read_b128 per 48 MFMAs per wave per K-step (MFMA-bound balance).
// ---------------------------------------------------------------------------
__device__ __forceinline__ void bg128(
    const ushort_t* __restrict__ Ah, const ushort_t* __restrict__ Al,
    const ushort_t* __restrict__ Wh, const ushort_t* __restrict__ Wl,
    int bx, int by, int rpb, int rowjump,
    ushort_t* SAh, ushort_t* SAl, ushort_t* SBh, ushort_t* SBl,
    f4v (&acc)[4][4])
{
    int t = threadIdx.x;
    int row0 = by * 128, col0 = bx * 128;
    int ar = t >> 1;
    int kc = (t & 1) * 16;
    int gr = row0 + ar;
    size_t arow = (size_t)(gr / rpb) * rowjump + (gr % rpb);
    const ushort_t* aph = Ah + arow * 1024 + kc;
    const ushort_t* apl = Al + arow * 1024 + kc;
    const ushort_t* wph = Wh + (size_t)(col0 + ar) * 1024 + kc;
    const ushort_t* wpl = Wl + (size_t)(col0 + ar) * 1024 + kc;

    int w = t >> 6, lane = t & 63;
    int wrow = (w >> 1) * 64, wcol = (w & 1) * 64;
    int fr = lane & 15, g = lane >> 4;

    #pragma unroll
    for (int mt = 0; mt < 4; ++mt)
        #pragma unroll
        for (int nt = 0; nt < 4; ++nt) acc[mt][nt] = (f4v){0.f, 0.f, 0.f, 0.f};

    for (int k0 = 0; k0 < 1024; k0 += 32) {
        *(s8v*)&SAh[ar * 40 + kc]     = *(const s8v*)(aph + k0);
        *(s8v*)&SAh[ar * 40 + kc + 8] = *(const s8v*)(aph + k0 + 8);
        *(s8v*)&SAl[ar * 40 + kc]     = *(const s8v*)(apl + k0);
        *(s8v*)&SAl[ar * 40 + kc + 8] = *(const s8v*)(apl + k0 + 8);
        *(s8v*)&SBh[ar * 40 + kc]     = *(const s8v*)(wph + k0);
        *(s8v*)&SBh[ar * 40 + kc + 8] = *(const s8v*)(wph + k0 + 8);
        *(s8v*)&SBl[ar * 40 + kc]     = *(const s8v*)(wpl + k0);
        *(s8v*)&SBl[ar * 40 + kc + 8] = *(const s8v*)(wpl + k0 + 8);
        __syncthreads();
        s8v ah[4], al_[4], bh_[4], bl_[4];
        #pragma unroll
        for (int mt = 0; mt < 4; ++mt) {
            ah[mt]  = *(const s8v*)&SAh[(wrow + mt * 16 + fr) * 40 + g * 8];
            al_[mt] = *(const s8v*)&SAl[(wrow + mt * 16 + fr) * 40 + g * 8];
        }
        #pragma unroll
        for (int nt = 0; nt < 4; ++nt) {
            bh_[nt] = *(const s8v*)&SBh[(wcol + nt * 16 + fr) * 40 + g * 8];
            bl_[nt] = *(const s8v*)&SBl[(wcol + nt * 16 + fr) * 40 + g * 8];
        }
        #pragma unroll
        for (int mt = 0; mt < 4; ++mt)
            #pragma unroll
            for (int nt = 0; nt < 4; ++nt) {
                acc[mt][nt] = MFMA_(ah[mt],  bh_[nt], acc[mt][nt], 0, 0, 0);
                acc[mt][nt] = MFMA_(ah[mt],  bl_[nt], acc[mt][nt], 0, 0, 0);
                acc[mt][nt] = MFMA_(al_[mt], bh_[nt], acc[mt][nt], 0, 0, 0);
            }
        __syncthreads();
    }
}

// ---------------------------------------------------------------------------
// proj2: main (384 blocks: 32 by x 12 bx) + enc (80 blocks: 8 by x 10 bx).
// ---------------------------------------------------------------------------
__global__ __launch_bounds__(256, 1) void proj2(
    const ushort_t* __restrict__ xh, const ushort_t* __restrict__ xl,
    const ushort_t* __restrict__ w1h, const ushort_t* __restrict__ w1l,
    const ushort_t* __restrict__ w2h, const ushort_t* __restrict__ w2l,
    float* __restrict__ tmpq, float* __restrict__ tmpk, float* __restrict__ v,
    float* __restrict__ tmpke, float* __restrict__ ve)
{
    __shared__ ushort_t SM[20480];
    f4v acc[4][4];
    int blk = xcd_swz(blockIdx.x, 464);
    int t = threadIdx.x, w = t >> 6, lane = t & 63;
    int wrow = (w >> 1) * 64, wcol = (w & 1) * 64;
    int fr = lane & 15, g = lane >> 4;

    if (blk < 384) {
        int bx = blk % 12, by = blk / 12;
        bg128(xh, xl, w1h, w1l, bx, by, 4096, 0,
              SM, SM + 5120, SM + 10240, SM + 15360, acc);
        int row0 = by * 128, col0 = bx * 128;
        #pragma unroll
        for (int mt = 0; mt < 4; ++mt)
            #pragma unroll
            for (int nt = 0; nt < 4; ++nt)
                #pragma unroll
                for (int r4 = 0; r4 < 4; ++r4) {
                    int r  = row0 + wrow + mt * 16 + g * 4 + r4;
                    int cc = col0 + wcol + nt * 16 + fr;
                    float val = acc[mt][nt][r4];
                    if (cc < 256)      tmpq[(size_t)r * 256 + cc] = val;
                    else if (cc < 512) tmpk[(size_t)r * 256 + (cc - 256)] = val;
                    else {
                        int c2 = cc - 512, hh = c2 >> 6, jj = c2 & 63;
                        int bb = r >> 11, n = r & 2047;
                        v[(((size_t)(bb * 16 + hh)) * 2048 + n) * 64 + jj] = val;
                    }
                }
    } else {
        int r2 = blk - 384;
        int bx = r2 % 10, by = r2 / 10;
        bg128(xh, xl, w2h, w2l, bx, by, 512, 2048,
              SM, SM + 5120, SM + 10240, SM + 15360, acc);
        int row0 = by * 128, col0 = bx * 128;
        #pragma unroll
        for (int mt = 0; mt < 4; ++mt)
            #pragma unroll
            for (int nt = 0; nt < 4; ++nt)
                #pragma unroll
                for (int r4 = 0; r4 < 4; ++r4) {
                    int r  = row0 + wrow + mt * 16 + g * 4 + r4;
                    int cc = col0 + wcol + nt * 16 + fr;
                    float val = acc[mt][nt][r4];
                    if (cc < 256) tmpke[(size_t)r * 256 + cc] = val;
                    else {
                        int c2 = cc - 256, hh = c2 >> 6, jj = c2 & 63;
                        int bb = r >> 9, n = r & 511;
                        ve[(((size_t)(bb * 16 + hh)) * 512 + n) * 64 + jj] = val;
                    }
                }
    }
}

// out_gemm: attn(bf16 hi/lo) @ Wout^T -> f32 d_out.  256 blocks (8 bx x 32 by).
__global__ __launch_bounds__(256, 1) void out_gemm(
    const ushort_t* __restrict__ Ah, const ushort_t* __restrict__ Al,
    const ushort_t* __restrict__ Wh, const ushort_t* __restrict__ Wl,
    float* __restrict__ out)
{
    __shared__ ushort_t SM[20480];
    f4v acc[4][4];
    int blk = xcd_swz(blockIdx.x, 256);
    int bx = blk & 7, by = blk >> 3;
    bg128(Ah, Al, Wh, Wl, bx, by, 4096, 0,
          SM, SM + 5120, SM + 10240, SM + 15360, acc);
    int t = threadIdx.x, w = t >> 6, lane = t & 63;
    int wrow = (w >> 1) * 64, wcol = (w & 1) * 64;
    int fr = lane & 15, g = lane >> 4;
    int row0 = by * 128, col0 = bx * 128;
    #pragma unroll
    for (int mt = 0; mt < 4; ++mt)
        #pragma unroll
        for (int nt = 0; nt < 4; ++nt)
            #pragma unroll
            for (int r4 = 0; r4 < 4; ++r4) {
                int r  = row0 + wrow + mt * 16 + g * 4 + r4;
                int cc = col0 + wcol + nt * 16 + fr;
                out[(size_t)r * 1024 + cc] = acc[mt][nt][r4];
            }
}

// ---------------------------------------------------------------------------
// MFMA state kernel; output now bf16 hi/lo PLANES (each state = 2*SSZ_ shorts:
// hi plane [65][288] then lo plane).
// ---------------------------------------------------------------------------
__device__ __forceinline__ void st_stage(
    const float* __restrict__ Kp, const float* __restrict__ V,
    size_t krow0, size_t vrow0, int h, int t,
    float* ksT, ushort_t* VTH, ushort_t* VTL)
{
    {
        int r = t >> 2, q4 = t & 3;
        float4 kv = *(const float4*)&Kp[(krow0 + r) * 256 + h * 16 + q4 * 4];
        ksT[(q4 * 4 + 0) * 68 + r] = kv.x;
        ksT[(q4 * 4 + 1) * 68 + r] = kv.y;
        ksT[(q4 * 4 + 2) * 68 + r] = kv.z;
        ksT[(q4 * 4 + 3) * 68 + r] = kv.w;
    }
    if (t < 64) ksT[16 * 68 + t] = 1.0f;
    {
        int r = t & 63, jg = t >> 6;
        #pragma unroll
        for (int cc = 0; cc < 4; ++cc) {
            float4 vv = *(const float4*)&V[(vrow0 + r) * HD_ + jg * 16 + cc * 4];
            float vals[4] = {vv.x, vv.y, vv.z, vv.w};
            #pragma unroll
            for (int e = 0; e < 4; ++e) {
                int j = jg * 16 + cc * 4 + e;
                unsigned short hh, ll; split1(vals[e], hh, ll);
                VTH[j * 72 + r] = hh;
                VTL[j * 72 + r] = ll;
            }
        }
    }
    if (t < 64) { VTH[64 * 72 + t] = 0x3F80; VTL[64 * 72 + t] = 0; }
}

__device__ __forceinline__ void st_ftile(
    const float* ksT, int ft, int fr, int g,
    const s8v (&AHf)[2][5], const s8v (&ALf)[2][5], f4v (&acc)[5])
{
    int f = ft * 16 + fr;
    int fi, fj; float scale;
    if (f == 0)       { fi = 16; fj = 16; scale = 1.0f; }
    else if (f < 17)  { fi = f - 1; fj = 16; scale = 0.5f; }
    else if (f < 273) { fi = (f - 17) >> 4; fj = (f - 17) & 15; scale = C2C_; }
    else              { fi = 16; fj = 16; scale = 0.0f; }
    #pragma unroll
    for (int ks2 = 0; ks2 < 2; ++ks2) {
        const float* pa = ksT + fi * 68 + ks2 * 32 + g * 8;
        const float* pb = ksT + fj * 68 + ks2 * 32 + g * 8;
        s8v bhv, blv;
        #pragma unroll
        for (int e = 0; e < 8; ++e) {
            float val = pa[e] * pb[e] * scale;
            unsigned short hh, ll; split1(val, hh, ll);
            bhv[e] = (short)hh; blv[e] = (short)ll;
        }
        #pragma unroll
        for (int jt = 0; jt < 5; ++jt) {
            acc[jt] = MFMA_(AHf[ks2][jt], bhv, acc[jt], 0, 0, 0);
            acc[jt] = MFMA_(AHf[ks2][jt], blv, acc[jt], 0, 0, 0);
            acc[jt] = MFMA_(ALf[ks2][jt], bhv, acc[jt], 0, 0, 0);
        }
    }
}

__global__ __launch_bounds__(256) void state_all(
    const float* __restrict__ Kpe, const float* __restrict__ Ve, ushort_t* __restrict__ Se,
    const float* __restrict__ Kpc, const float* __restrict__ Vc, ushort_t* __restrict__ Sc)
{
    __shared__ float ksT[17 * 68];
    __shared__ ushort_t VTH[80 * 72], VTL[80 * 72];
    int blk = blockIdx.x, t = threadIdx.x;
    int w = t >> 6, lane = t & 63, fr = lane & 15, g = lane >> 4;

    for (int i = t; i < 15 * 72; i += 256) { VTH[65 * 72 + i] = 0; VTL[65 * 72 + i] = 0; }

    if (blk >= 160) {
        int b2 = blk - 160;
        int c = b2 & 31, bh = b2 >> 5;
        int b = bh >> 4, h = bh & 15;
        ushort_t* Sg = Sc + ((size_t)bh * NC_ + c) * 2 * SSZ_;
        st_stage(Kpc, Vc, (size_t)b * 2048 + c * 64, (size_t)bh * 2048 + c * 64,
                 h, t, ksT, VTH, VTL);
        __syncthreads();
        s8v AHf[2][5], ALf[2][5];
        #pragma unroll
        for (int ks2 = 0; ks2 < 2; ++ks2)
            #pragma unroll
            for (int jt = 0; jt < 5; ++jt) {
                AHf[ks2][jt] = *(const s8v*)&VTH[(jt * 16 + fr) * 72 + ks2 * 32 + g * 8];
                ALf[ks2][jt] = *(const s8v*)&VTL[(jt * 16 + fr) * 72 + ks2 * 32 + g * 8];
            }
        for (int ft = w; ft < 18; ft += 4) {
            f4v acc[5];
            #pragma unroll
            for (int jt = 0; jt < 5; ++jt) acc[jt] = (f4v){0.f, 0.f, 0.f, 0.f};
            st_ftile(ksT, ft, fr, g, AHf, ALf, acc);
            #pragma unroll
            for (int jt = 0; jt < 5; ++jt)
                #pragma unroll
                for (int r4 = 0; r4 < 4; ++r4) {
                    int j = jt * 16 + g * 4 + r4;
                    if (j < 65) {
                        unsigned short hh, ll; split1(acc[jt][r4], hh, ll);
                        Sg[(size_t)j * FP_ + ft * 16 + fr] = hh;
                        Sg[SSZ_ + (size_t)j * FP_ + ft * 16 + fr] = ll;
                    }
                }
        }
    } else {
        int bh = blk / 5, fg = blk % 5;
        int b = bh >> 4, h = bh & 15;
        int ft = fg * 4 + w;
        ushort_t* Sg = Se + (size_t)bh * 2 * SSZ_;
        f4v acc[5];
        #pragma unroll
        for (int jt = 0; jt < 5; ++jt) acc[jt] = (f4v){0.f, 0.f, 0.f, 0.f};
        for (int m0 = 0; m0 < 512; m0 += 64) {
            if (m0) __syncthreads();
            st_stage(Kpe, Ve, (size_t)b * 512 + m0, (size_t)bh * 512 + m0,
                     h, t, ksT, VTH, VTL);
            __syncthreads();
            if (ft < 18) {
                s8v AHf[2][5], ALf[2][5];
                #pragma unroll
                for (int ks2 = 0; ks2 < 2; ++ks2)
                    #pragma unroll
                    for (int jt = 0; jt < 5; ++jt) {
                        AHf[ks2][jt] = *(const s8v*)&VTH[(jt * 16 + fr) * 72 + ks2 * 32 + g * 8];
                        ALf[ks2][jt] = *(const s8v*)&VTL[(jt * 16 + fr) * 72 + ks2 * 32 + g * 8];
                    }
                st_ftile(ksT, ft, fr, g, AHf, ALf, acc);
            }
        }
        if (ft < 18) {
            #pragma unroll
            for (int jt = 0; jt < 5; ++jt)
                #pragma unroll
                for (int r4 = 0; r4 < 4; ++r4) {
                    int j = jt * 16 + g * 4 + r4;
                    if (j < 65) {
                        unsigned short hh, ll; split1(acc[jt][r4], hh, ll);
                        Sg[(size_t)j * FP_ + ft * 16 + fr] = hh;
                        Sg[SSZ_ + (size_t)j * FP_ + ft * 16 + fr] = ll;
                    }
                }
        }
    }
}

// ---------------------------------------------------------------------------
// Exclusive prefix over bf16-pair states, in place (element-wise, same thread
// reads then rewrites the same bytes -> race-free).
// ---------------------------------------------------------------------------
__global__ __launch_bounds__(256) void prefix_scan(
    ushort_t* __restrict__ Sloc, const ushort_t* __restrict__ Senc)
{
    const int Q = SSZ_ / 4;    // 4680 quad-groups
    int gid = blockIdx.x * 256 + threadIdx.x;
    if (gid >= 32 * Q) return;
    int bh = gid / Q, e = gid - bh * Q;
    const ushort_t* Eb = Senc + (size_t)bh * 2 * SSZ_;
    u16x4 h4 = *(const u16x4*)(Eb + e * 4);
    u16x4 l4 = *(const u16x4*)(Eb + SSZ_ + e * 4);
    float run[4];
    #pragma unroll
    for (int u = 0; u < 4; ++u) run[u] = bff(h4[u]) + bff(l4[u]);
    ushort_t* Sb = Sloc + (size_t)bh * NC_ * 2 * SSZ_;
    #pragma unroll 1
    for (int cb = 0; cb < 8; ++cb) {
        u16x4 th[4], tl[4];
        #pragma unroll
        for (int u2 = 0; u2 < 4; ++u2) {
            const ushort_t* P = Sb + (size_t)(cb * 4 + u2) * 2 * SSZ_;
            th[u2] = *(const u16x4*)(P + e * 4);
            tl[u2] = *(const u16x4*)(P + SSZ_ + e * 4);
        }
        #pragma unroll
        for (int u2 = 0; u2 < 4; ++u2) {
            ushort_t* P = Sb + (size_t)(cb * 4 + u2) * 2 * SSZ_;
            u16x4 oh, ol;
            #pragma unroll
            for (int u = 0; u < 4; ++u) {
                unsigned short hh, ll; split1(run[u], hh, ll);
                oh[u] = hh; ol[u] = ll;
                run[u] += bff(th[u2][u]) + bff(tl[u2][u]);
            }
            *(u16x4*)(P + e * 4) = oh;
            *(u16x4*)(P + SSZ_ + e * 4) = ol;
        }
    }
}

// ---------------------------------------------------------------------------
// MFMA attn_chunk; Y2 stages pre-split bf16 state planes (no split math).
// ---------------------------------------------------------------------------
template <int FW>
__device__ __forceinline__ void y2_slice(
    int f0, const ushort_t* __restrict__ Sth, const ushort_t* __restrict__ Stl,
    const float* qs,
    ushort_t* QFH, ushort_t* QFL,
    ushort_t* STH, ushort_t* STL,
    f4v (&acc)[5], int w, int fr, int g, int t)
{
    for (int i = t; i < 64 * FW; i += 256) {
        int row = i / FW, cc = i % FW;
        int f = f0 + cc;
        float qv;
        if (f == 0)       qv = 1.0f;
        else if (f < 17)  qv = qs[row * 20 + (f - 1)] * 0.5f;
        else if (f < 273) qv = qs[row * 20 + ((f - 17) >> 4)] * qs[row * 20 + ((f - 17) & 15)] * C2C_;
        else              qv = 0.0f;
        unsigned short h, l; split1(qv, h, l);
        QFH[row * 72 + cc] = h;
        QFL[row * 72 + cc] = l;
    }
    const int NS = FW / 8;
    for (int i = t; i < 65 * NS; i += 256) {
        int j = i / NS, seg = i % NS;
        *(s8v*)&STH[j * 72 + seg * 8] = *(const s8v*)(Sth + (size_t)j * FP_ + f0 + seg * 8);
        *(s8v*)&STL[j * 72 + seg * 8] = *(const s8v*)(Stl + (size_t)j * FP_ + f0 + seg * 8);
    }
    __syncthreads();
    #pragma unroll
    for (int ks2 = 0; ks2 < FW / 32; ++ks2) {
        s8v ah = *(const s8v*)&QFH[(16 * w + fr) * 72 + ks2 * 32 + g * 8];
        s8v al = *(const s8v*)&QFL[(16 * w + fr) * 72 + ks2 * 32 + g * 8];
        #pragma unroll
        for (int jt = 0; jt < 5; ++jt) {
            s8v bh_ = *(const s8v*)&STH[(jt * 16 + fr) * 72 + ks2 * 32 + g * 8];
            s8v bl_ = *(const s8v*)&STL[(jt * 16 + fr) * 72 + ks2 * 32 + g * 8];
            acc[jt] = MFMA_(ah, bh_, acc[jt], 0, 0, 0);
            acc[jt] = MFMA_(ah, bl_, acc[jt], 0, 0, 0);
            acc[jt] = MFMA_(al, bh_, acc[jt], 0, 0, 0);
        }
    }
    __syncthreads();
}

__global__ __launch_bounds__(256) void attn_chunk(
    const float* __restrict__ qp, const float* __restrict__ kp,
    const float* __restrict__ v, const ushort_t* __restrict__ Spre,
    ushort_t* __restrict__ atnh, ushort_t* __restrict__ atnl)
{
    __shared__ ushort_t U[20736];
    __shared__ float qs[64 * 20];
    __shared__ float den_s[64];
    ushort_t* AH  = U;            // [64][72]
    ushort_t* AL  = U + 4608;
    ushort_t* QH  = U + 9216;     // [64][40]
    ushort_t* QL  = U + 11776;
    ushort_t* KH  = U + 14336;
    ushort_t* KL  = U + 16896;
    ushort_t* VTH = U + 9216;     // [80][72]
    ushort_t* VTL = U + 14976;
    ushort_t* QFH = U;            // [64][72]
    ushort_t* QFL = U + 4608;
    ushort_t* STH = U + 9216;     // [80][72]
    ushort_t* STL = U + 14976;

    int bid = blockIdx.x;
    int bh = bid >> 5, c = bid & 31;
    int b = bh >> 4, h = bh & 15;
    int t = threadIdx.x;
    int w = t >> 6, lane = t & 63, fr = lane & 15, g = lane >> 4;
    int rowbase = b * N_ + c * CHK_;

    {
        int r = t >> 2, q4 = t & 3;
        float4 qv = *(const float4*)&qp[(size_t)(rowbase + r) * 256 + h * 16 + q4 * 4];
        float4 kv = *(const float4*)&kp[(size_t)(rowbase + r) * 256 + h * 16 + q4 * 4];
        u16x4 hh, ll;
        splitf4(qv, hh, ll);
        *(u16x4*)&QH[r * 40 + q4 * 4] = hh;
        *(u16x4*)&QL[r * 40 + q4 * 4] = ll;
        splitf4(kv, hh, ll);
        *(u16x4*)&KH[r * 40 + q4 * 4] = hh;
        *(u16x4*)&KL[r * 40 + q4 * 4] = ll;
        u16x4 z4 = (u16x4){0, 0, 0, 0};
        *(u16x4*)&QH[r * 40 + 16 + q4 * 4] = z4;
        *(u16x4*)&QL[r * 40 + 16 + q4 * 4] = z4;
        *(u16x4*)&KH[r * 40 + 16 + q4 * 4] = z4;
        *(u16x4*)&KL[r * 40 + 16 + q4 * 4] = z4;
        qs[r * 20 + q4 * 4 + 0] = qv.x;
        qs[r * 20 + q4 * 4 + 1] = qv.y;
        qs[r * 20 + q4 * 4 + 2] = qv.z;
        qs[r * 20 + q4 * 4 + 3] = qv.w;
    }
    __syncthreads();

    {
        s8v qh = *(const s8v*)&QH[(16 * w + fr) * 40 + g * 8];
        s8v ql = *(const s8v*)&QL[(16 * w + fr) * 40 + g * 8];
        f4v sacc[4];
        #pragma unroll
        for (int jt = 0; jt < 4; ++jt) sacc[jt] = (f4v){0.f, 0.f, 0.f, 0.f};
        #pragma unroll
        for (int jt = 0; jt < 4; ++jt) {
            s8v kh = *(const s8v*)&KH[(jt * 16 + fr) * 40 + g * 8];
            s8v kl = *(const s8v*)&KL[(jt * 16 + fr) * 40 + g * 8];
            sacc[jt] = MFMA_(qh, kh, sacc[jt], 0, 0, 0);
            sacc[jt] = MFMA_(qh, kl, sacc[jt], 0, 0, 0);
            sacc[jt] = MFMA_(ql, kh, sacc[jt], 0, 0, 0);
        }
        #pragma unroll
        for (int jt = 0; jt < 4; ++jt)
            #pragma unroll
            for (int r4 = 0; r4 < 4; ++r4) {
                int row = 16 * w + g * 4 + r4, col = jt * 16 + fr;
                float s = sacc[jt][r4];
                float a = (row >= col) ? (fmaf(s, 0.25f, 1.0f) + s * s * 0.03125f) : 0.f;
                unsigned short hh, ll; split1(a, hh, ll);
                AH[row * 72 + col] = hh;
                AL[row * 72 + col] = ll;
            }
    }
    __syncthreads();

    for (int i = t; i < 80 * 64; i += 256) {
        int j = i >> 6, m = i & 63;
        float val;
        if (j < 64)       val = v[((size_t)bh * N_ + c * CHK_ + m) * HD_ + j];
        else if (j == 64) val = 1.0f;
        else              val = 0.0f;
        unsigned short hh, ll; split1(val, hh, ll);
        VTH[j * 72 + m] = hh;
        VTL[j * 72 + m] = ll;
    }
    __syncthreads();

    f4v acc[5];
    #pragma unroll
    for (int jt = 0; jt < 5; ++jt) acc[jt] = (f4v){0.f, 0.f, 0.f, 0.f};
    #pragma unroll
    for (int ks2 = 0; ks2 < 2; ++ks2) {
        s8v ah = *(const s8v*)&AH[(16 * w + fr) * 72 + ks2 * 32 + g * 8];
        s8v al = *(const s8v*)&AL[(16 * w + fr) * 72 + ks2 * 32 + g * 8];
        #pragma unroll
        for (int jt = 0; jt < 5; ++jt) {
            s8v bh_ = *(const s8v*)&VTH[(jt * 16 + fr) * 72 + ks2 * 32 + g * 8];
            s8v bl_ = *(const s8v*)&VTL[(jt * 16 + fr) * 72 + ks2 * 32 + g * 8];
            acc[jt] = MFMA_(ah, bh_, acc[jt], 0, 0, 0);
            acc[jt] = MFMA_(ah, bl_, acc[jt], 0, 0, 0);
            acc[jt] = MFMA_(al, bh_, acc[jt], 0, 0, 0);
        }
    }
    __syncthreads();

    const ushort_t* Sth = Spre + ((size_t)bh * NC_ + c) * 2 * SSZ_;
    const ushort_t* Stl = Sth + SSZ_;
    for (int p = 0; p < 4; ++p)
        y2_slice<64>(p * 64, Sth, Stl, qs, QFH, QFL, STH, STL, acc, w, fr, g, t);
    y2_slice<32>(256, Sth, Stl, qs, QFH, QFL, STH, STL, acc, w, fr, g, t);

    if (fr == 0) {
        #pragma unroll
        for (int r4 = 0; r4 < 4; ++r4)
            den_s[16 * w + g * 4 + r4] = acc[4][r4];
    }
    __syncthreads();
    #pragma unroll
    for (int r4 = 0; r4 < 4; ++r4) {
        float z = 1.0f / (den_s[16 * w + g * 4 + r4] + EPS_);
        int row = rowbase + 16 * w + g * 4 + r4;
        #pragma unroll
        for (int jt = 0; jt < 4; ++jt) {
            float val = acc[jt][r4] * z;
            unsigned short hh, ll; split1(val, hh, ll);
            size_t idx = (size_t)row * 1024 + h * 64 + jt * 16 + fr;
            atnh[idx] = hh;
            atnl[idx] = ll;
        }
    }
}

// ---------------------------------------------------------------------------
extern "C" void kernel_launch(void* const* d_in, const int* in_sizes, int n_in,
                              void* d_out, int out_size, void* d_ws, size_t ws_size,
                              hipStream_t stream)
{
    const float* x    = (const float*)d_in[0];
    const float* Wq   = (const float*)d_in[1];
    const float* Wk   = (const float*)d_in[2];
    const float* Wv   = (const float*)d_in[3];
    const float* Wke  = (const float*)d_in[4];
    const float* Wve  = (const float*)d_in[5];
    const float* Wout = (const float*)d_in[6];
    float* out = (float*)d_out;
    float* ws  = (float*)d_ws;

    // f32 region
    float* tmpq  = ws;                                 // 1,048,576
    float* tmpk  = tmpq  + (size_t)1048576;            // 1,048,576
    float* tmpke = tmpk  + (size_t)1048576;            //   262,144
    float* v     = tmpke + (size_t)262144;             // 4,194,304
    float* ve    = v     + (size_t)4194304;            // 1,048,576
    float* Sloc  = ve    + (size_t)1048576;            // 19,169,280 (bf16-pair planes)
    float* Senc  = Sloc  + (size_t)19169280;           //   599,040  (bf16-pair planes)
    // bf16 region
    ushort_t* xh = (ushort_t*)(Senc + 599040);         // 4,194,304 shorts
    ushort_t* xl = xh + (size_t)4194304;               // 4,194,304 shorts
    // overlays:
    ushort_t* w1h = (ushort_t*)Sloc;                   // dead before state_all
    ushort_t* w1l = w1h + (size_t)1572864;
    ushort_t* w2h = w1l + (size_t)1572864;
    ushort_t* w2l = w2h + (size_t)1310720;
    ushort_t* woh = (ushort_t*)tmpq;                   // tmpq dead after attn
    ushort_t* wol = woh + (size_t)1048576;
    ushort_t* atnh = xh;                               // xh/xl dead after proj2
    ushort_t* atnl = xl;
    ushort_t* Sloc_us = (ushort_t*)Sloc;
    ushort_t* Senc_us = (ushort_t*)Senc;

    dim3 blk(256);

    split_all<<<6912, blk, 0, stream>>>(x, Wq, Wk, Wv, Wke, Wve,
                                        xh, xl, w1h, w1l, w2h, w2l);
    proj2<<<464, blk, 0, stream>>>(xh, xl, w1h, w1l, w2h, w2l,
                                   tmpq, tmpk, v, tmpke, ve);
    state_all<<<160 + 32 * NC_, blk, 0, stream>>>(tmpke, ve, Senc_us, tmpk, v, Sloc_us);
    prefix_scan<<<585, blk, 0, stream>>>(Sloc_us, Senc_us);
    attn_chunk<<<32 * NC_, blk, 0, stream>>>(tmpq, tmpk, v, Sloc_us, atnh, atnl);
    split_wo<<<1024, blk, 0, stream>>>(Wout, woh, wol);
    out_gemm<<<256, blk, 0, stream>>>(atnh, atnl, woh, wol, out);
}

// Round 8
// 192.541 us; speedup vs baseline: 4.7628x; 1.1584x over previous
//
#include <hip/hip_runtime.h>

// Problem constants
#define B_    2
#define N_    2048
#define H_    16
#define HD_   64
#define ENC_  512
#define FP_   288
#define CHK_  64
#define NC_   32
#define SSZ_  18720                  // state elems: [65 j][288 f]; stored as f16 hi/lo planes
#define C2C_  0.17677669529663687f   // 1/(4*sqrt(2))
#define EPS_  1e-12f

using s8v   = __attribute__((ext_vector_type(8))) short;     // 8x16-bit carrier
using h8v   = __attribute__((ext_vector_type(8))) _Float16;  // 8 f16 (4 VGPRs)
using f4v   = __attribute__((ext_vector_type(4))) float;
using u16x4 = __attribute__((ext_vector_type(4))) unsigned short;
typedef unsigned short ushort_t;

// ---- bf16 helpers (used by attn QK^T / Y1 only)
__device__ __forceinline__ unsigned short bfh(float x) {
    unsigned int u = __float_as_uint(x);
    return (unsigned short)((u + 0x7FFF + ((u >> 16) & 1)) >> 16);
}
__device__ __forceinline__ float bff(unsigned short h) {
    return __uint_as_float(((unsigned int)h) << 16);
}
__device__ __forceinline__ void split1(float x, unsigned short& h, unsigned short& l) {
    h = bfh(x); l = bfh(x - bff(h));
}
__device__ __forceinline__ void splitf4(float4 v, u16x4& h, u16x4& l) {
    unsigned short h0 = bfh(v.x), h1 = bfh(v.y), h2 = bfh(v.z), h3 = bfh(v.w);
    h = (u16x4){h0, h1, h2, h3};
    l = (u16x4){bfh(v.x - bff(h0)), bfh(v.y - bff(h1)),
                bfh(v.z - bff(h2)), bfh(v.w - bff(h3))};
}

// ---- f16 helpers
__device__ __forceinline__ unsigned short f16q(float x) {
    _Float16 h = (_Float16)x;
    return __builtin_bit_cast(unsigned short, h);
}
__device__ __forceinline__ float f16f(unsigned short u) {
    return (float)__builtin_bit_cast(_Float16, u);
}
__device__ __forceinline__ void splitf16(float x, unsigned short& h, unsigned short& l) {
    _Float16 hh = (_Float16)x;
    h = __builtin_bit_cast(unsigned short, hh);
    l = f16q(x - (float)hh);
}
__device__ __forceinline__ void splitf16_4(float4 v, u16x4& h, u16x4& l) {
    unsigned short h0, l0, h1, l1, h2, l2, h3, l3;
    splitf16(v.x, h0, l0); splitf16(v.y, h1, l1);
    splitf16(v.z, h2, l2); splitf16(v.w, h3, l3);
    h = (u16x4){h0, h1, h2, h3};
    l = (u16x4){l0, l1, l2, l3};
}
__device__ __forceinline__ u16x4 f16q4(float4 v) {
    return (u16x4){f16q(v.x), f16q(v.y), f16q(v.z), f16q(v.w)};
}

#define MFMA_  __builtin_amdgcn_mfma_f32_16x16x32_bf16
#define MFMAH_ __builtin_amdgcn_mfma_f32_16x16x32_f16

// bijective XCD swizzle (m204)
__device__ __forceinline__ int xcd_swz(int b, int nwg) {
    int q = nwg >> 3, r = nwg & 7;
    int xcd = b & 7, loc = b >> 3;
    return (xcd < r ? xcd * (q + 1) : r * (q + 1) + (xcd - r) * q) + loc;
}

// ---------------------------------------------------------------------------
// split_all: x -> f16 pair xh/xl ; [Wq;Wk;Wv] -> single f16 w1 ; [Wke;Wve] -> w2.
// ---------------------------------------------------------------------------
#define X_F4   1048576      // 4096*1024/4
#define W1_F4  393216       // 1536*256
#define W2_F4  327680       // 1280*256

__global__ __launch_bounds__(256) void split_all(
    const float* __restrict__ x,
    const float* __restrict__ Wq, const float* __restrict__ Wk,
    const float* __restrict__ Wv, const float* __restrict__ Wke,
    const float* __restrict__ Wve,
    ushort_t* __restrict__ xh, ushort_t* __restrict__ xl,
    ushort_t* __restrict__ w1, ushort_t* __restrict__ w2)
{
    int gid = blockIdx.x * 256 + threadIdx.x;
    if (gid < X_F4) {
        float4 vv = ((const float4*)x)[gid];
        u16x4 h, l; splitf16_4(vv, h, l);
        ((u16x4*)xh)[gid] = h; ((u16x4*)xl)[gid] = l;
    } else if (gid < X_F4 + W1_F4) {
        int i = gid - X_F4;
        int row = i >> 8, c4 = i & 255;
        const float* s = (row < 256) ? Wq + (size_t)row * 1024
                       : (row < 512) ? Wk + (size_t)(row - 256) * 1024
                                     : Wv + (size_t)(row - 512) * 1024;
        ((u16x4*)w1)[i] = f16q4(*(const float4*)(s + c4 * 4));
    } else {
        int i = gid - X_F4 - W1_F4;
        int row = i >> 8, c4 = i & 255;
        const float* s = (row < 256) ? Wke + (size_t)row * 1024
                                     : Wve + (size_t)(row - 256) * 1024;
        ((u16x4*)w2)[i] = f16q4(*(const float4*)(s + c4 * 4));
    }
}

__global__ __launch_bounds__(256) void split_wo(
    const float* __restrict__ Wout, ushort_t* __restrict__ wo)
{
    int gid = blockIdx.x * 256 + threadIdx.x;   // 262144 f4
    ((u16x4*)wo)[gid] = f16q4(((const float4*)Wout)[gid]);
}

// ---------------------------------------------------------------------------
// f16 2-pass GEMM body: acc = (Ah+Al) @ W^T, A = f16 pair, W = single f16.
// BM=128, BN=128, BK=32, 4 waves (2x2).  12 ds_read_b128 per 32 MFMA/wave.
// ---------------------------------------------------------------------------
__device__ __forceinline__ void bg128(
    const ushort_t* __restrict__ Ah, const ushort_t* __restrict__ Al,
    const ushort_t* __restrict__ Wh,
    int bx, int by, int rpb, int rowjump,
    ushort_t* SAh, ushort_t* SAl, ushort_t* SBh,
    f4v (&acc)[4][4])
{
    int t = threadIdx.x;
    int row0 = by * 128, col0 = bx * 128;
    int ar = t >> 1;
    int kc = (t & 1) * 16;
    int gr = row0 + ar;
    size_t arow = (size_t)(gr / rpb) * rowjump + (gr % rpb);
    const ushort_t* aph = Ah + arow * 1024 + kc;
    const ushort_t* apl = Al + arow * 1024 + kc;
    const ushort_t* wph = Wh + (size_t)(col0 + ar) * 1024 + kc;

    int w = t >> 6, lane = t & 63;
    int wrow = (w >> 1) * 64, wcol = (w & 1) * 64;
    int fr = lane & 15, g = lane >> 4;

    #pragma unroll
    for (int mt = 0; mt < 4; ++mt)
        #pragma unroll
        for (int nt = 0; nt < 4; ++nt) acc[mt][nt] = (f4v){0.f, 0.f, 0.f, 0.f};

    for (int k0 = 0; k0 < 1024; k0 += 32) {
        *(s8v*)&SAh[ar * 40 + kc]     = *(const s8v*)(aph + k0);
        *(s8v*)&SAh[ar * 40 + kc + 8] = *(const s8v*)(aph + k0 + 8);
        *(s8v*)&SAl[ar * 40 + kc]     = *(const s8v*)(apl + k0);
        *(s8v*)&SAl[ar * 40 + kc + 8] = *(const s8v*)(apl + k0 + 8);
        *(s8v*)&SBh[ar * 40 + kc]     = *(const s8v*)(wph + k0);
        *(s8v*)&SBh[ar * 40 + kc + 8] = *(const s8v*)(wph + k0 + 8);
        __syncthreads();
        h8v a_h[4], a_l[4], b_[4];
        #pragma unroll
        for (int mt = 0; mt < 4; ++mt) {
            a_h[mt] = *(const h8v*)&SAh[(wrow + mt * 16 + fr) * 40 + g * 8];
            a_l[mt] = *(const h8v*)&SAl[(wrow + mt * 16 + fr) * 40 + g * 8];
        }
        #pragma unroll
        for (int nt = 0; nt < 4; ++nt)
            b_[nt] = *(const h8v*)&SBh[(wcol + nt * 16 + fr) * 40 + g * 8];
        #pragma unroll
        for (int mt = 0; mt < 4; ++mt)
            #pragma unroll
            for (int nt = 0; nt < 4; ++nt) {
                acc[mt][nt] = MFMAH_(a_h[mt], b_[nt], acc[mt][nt], 0, 0, 0);
                acc[mt][nt] = MFMAH_(a_l[mt], b_[nt], acc[mt][nt], 0, 0, 0);
            }
        __syncthreads();
    }
}

// ---------------------------------------------------------------------------
// proj2: main (384 blocks: 32 by x 12 bx) + enc (80 blocks: 8 by x 10 bx).
// ---------------------------------------------------------------------------
__global__ __launch_bounds__(256) void proj2(
    const ushort_t* __restrict__ xh, const ushort_t* __restrict__ xl,
    const ushort_t* __restrict__ w1, const ushort_t* __restrict__ w2,
    float* __restrict__ tmpq, float* __restrict__ tmpk, float* __restrict__ v,
    float* __restrict__ tmpke, float* __restrict__ ve)
{
    __shared__ ushort_t SM[15360];
    f4v acc[4][4];
    int blk = xcd_swz(blockIdx.x, 464);
    int t = threadIdx.x, w = t >> 6, lane = t & 63;
    int wrow = (w >> 1) * 64, wcol = (w & 1) * 64;
    int fr = lane & 15, g = lane >> 4;

    if (blk < 384) {
        int bx = blk % 12, by = blk / 12;
        bg128(xh, xl, w1, bx, by, 4096, 0, SM, SM + 5120, SM + 10240, acc);
        int row0 = by * 128, col0 = bx * 128;
        #pragma unroll
        for (int mt = 0; mt < 4; ++mt)
            #pragma unroll
            for (int nt = 0; nt < 4; ++nt)
                #pragma unroll
                for (int r4 = 0; r4 < 4; ++r4) {
                    int r  = row0 + wrow + mt * 16 + g * 4 + r4;
                    int cc = col0 + wcol + nt * 16 + fr;
                    float val = acc[mt][nt][r4];
                    if (cc < 256)      tmpq[(size_t)r * 256 + cc] = val;
                    else if (cc < 512) tmpk[(size_t)r * 256 + (cc - 256)] = val;
                    else {
                        int c2 = cc - 512, hh = c2 >> 6, jj = c2 & 63;
                        int bb = r >> 11, n = r & 2047;
                        v[(((size_t)(bb * 16 + hh)) * 2048 + n) * 64 + jj] = val;
                    }
                }
    } else {
        int r2 = blk - 384;
        int bx = r2 % 10, by = r2 / 10;
        bg128(xh, xl, w2, bx, by, 512, 2048, SM, SM + 5120, SM + 10240, acc);
        int row0 = by * 128, col0 = bx * 128;
        #pragma unroll
        for (int mt = 0; mt < 4; ++mt)
            #pragma unroll
            for (int nt = 0; nt < 4; ++nt)
                #pragma unroll
                for (int r4 = 0; r4 < 4; ++r4) {
                    int r  = row0 + wrow + mt * 16 + g * 4 + r4;
                    int cc = col0 + wcol + nt * 16 + fr;
                    float val = acc[mt][nt][r4];
                    if (cc < 256) tmpke[(size_t)r * 256 + cc] = val;
                    else {
                        int c2 = cc - 256, hh = c2 >> 6, jj = c2 & 63;
                        int bb = r >> 9, n = r & 511;
                        ve[(((size_t)(bb * 16 + hh)) * 512 + n) * 64 + jj] = val;
                    }
                }
    }
}

// out_gemm: attn(f16 pair) @ Wout(f16)^T -> f32 d_out.  256 blocks.
__global__ __launch_bounds__(256) void out_gemm(
    const ushort_t* __restrict__ Ah, const ushort_t* __restrict__ Al,
    const ushort_t* __restrict__ Wh, float* __restrict__ out)
{
    __shared__ ushort_t SM[15360];
    f4v acc[4][4];
    int blk = xcd_swz(blockIdx.x, 256);
    int bx = blk & 7, by = blk >> 3;
    bg128(Ah, Al, Wh, bx, by, 4096, 0, SM, SM + 5120, SM + 10240, acc);
    int t = threadIdx.x, w = t >> 6, lane = t & 63;
    int wrow = (w >> 1) * 64, wcol = (w & 1) * 64;
    int fr = lane & 15, g = lane >> 4;
    int row0 = by * 128, col0 = bx * 128;
    #pragma unroll
    for (int mt = 0; mt < 4; ++mt)
        #pragma unroll
        for (int nt = 0; nt < 4; ++nt)
            #pragma unroll
            for (int r4 = 0; r4 < 4; ++r4) {
                int r  = row0 + wrow + mt * 16 + g * 4 + r4;
                int cc = col0 + wcol + nt * 16 + fr;
                out[(size_t)r * 1024 + cc] = acc[mt][nt][r4];
            }
}

// ---------------------------------------------------------------------------
// MFMA state kernel, f16 2-pass: A = Vext f16 pair, B = on-the-fly feature
// fragments single f16.  Output: f16 hi/lo planes.
// ---------------------------------------------------------------------------
__device__ __forceinline__ void st_stage(
    const float* __restrict__ Kp, const float* __restrict__ V,
    size_t krow0, size_t vrow0, int h, int t,
    float* ksT, ushort_t* VTH, ushort_t* VTL)
{
    {
        int r = t >> 2, q4 = t & 3;
        float4 kv = *(const float4*)&Kp[(krow0 + r) * 256 + h * 16 + q4 * 4];
        ksT[(q4 * 4 + 0) * 68 + r] = kv.x;
        ksT[(q4 * 4 + 1) * 68 + r] = kv.y;
        ksT[(q4 * 4 + 2) * 68 + r] = kv.z;
        ksT[(q4 * 4 + 3) * 68 + r] = kv.w;
    }
    if (t < 64) ksT[16 * 68 + t] = 1.0f;
    {
        int r = t & 63, jg = t >> 6;
        #pragma unroll
        for (int cc = 0; cc < 4; ++cc) {
            float4 vv = *(const float4*)&V[(vrow0 + r) * HD_ + jg * 16 + cc * 4];
            float vals[4] = {vv.x, vv.y, vv.z, vv.w};
            #pragma unroll
            for (int e = 0; e < 4; ++e) {
                int j = jg * 16 + cc * 4 + e;
                unsigned short hh, ll; splitf16(vals[e], hh, ll);
                VTH[j * 72 + r] = hh;
                VTL[j * 72 + r] = ll;
            }
        }
    }
    if (t < 64) { VTH[64 * 72 + t] = 0x3C00; VTL[64 * 72 + t] = 0; }  // f16 1.0
}

__device__ __forceinline__ void st_ftile(
    const float* ksT, int ft, int fr, int g,
    const h8v (&AHf)[2][5], const h8v (&ALf)[2][5], f4v (&acc)[5])
{
    int f = ft * 16 + fr;
    int fi, fj; float scale;
    if (f == 0)       { fi = 16; fj = 16; scale = 1.0f; }
    else if (f < 17)  { fi = f - 1; fj = 16; scale = 0.5f; }
    else if (f < 273) { fi = (f - 17) >> 4; fj = (f - 17) & 15; scale = C2C_; }
    else              { fi = 16; fj = 16; scale = 0.0f; }
    #pragma unroll
    for (int ks2 = 0; ks2 < 2; ++ks2) {
        const float* pa = ksT + fi * 68 + ks2 * 32 + g * 8;
        const float* pb = ksT + fj * 68 + ks2 * 32 + g * 8;
        h8v bv;
        #pragma unroll
        for (int e = 0; e < 8; ++e) bv[e] = (_Float16)(pa[e] * pb[e] * scale);
        #pragma unroll
        for (int jt = 0; jt < 5; ++jt) {
            acc[jt] = MFMAH_(AHf[ks2][jt], bv, acc[jt], 0, 0, 0);
            acc[jt] = MFMAH_(ALf[ks2][jt], bv, acc[jt], 0, 0, 0);
        }
    }
}

__global__ __launch_bounds__(256) void state_all(
    const float* __restrict__ Kpe, const float* __restrict__ Ve, ushort_t* __restrict__ Se,
    const float* __restrict__ Kpc, const float* __restrict__ Vc, ushort_t* __restrict__ Sc)
{
    __shared__ float ksT[17 * 68];
    __shared__ ushort_t VTH[80 * 72], VTL[80 * 72];
    int blk = blockIdx.x, t = threadIdx.x;
    int w = t >> 6, lane = t & 63, fr = lane & 15, g = lane >> 4;

    for (int i = t; i < 15 * 72; i += 256) { VTH[65 * 72 + i] = 0; VTL[65 * 72 + i] = 0; }

    if (blk >= 160) {
        int b2 = blk - 160;
        int c = b2 & 31, bh = b2 >> 5;
        int b = bh >> 4, h = bh & 15;
        ushort_t* Sg = Sc + ((size_t)bh * NC_ + c) * 2 * SSZ_;
        st_stage(Kpc, Vc, (size_t)b * 2048 + c * 64, (size_t)bh * 2048 + c * 64,
                 h, t, ksT, VTH, VTL);
        __syncthreads();
        h8v AHf[2][5], ALf[2][5];
        #pragma unroll
        for (int ks2 = 0; ks2 < 2; ++ks2)
            #pragma unroll
            for (int jt = 0; jt < 5; ++jt) {
                AHf[ks2][jt] = *(const h8v*)&VTH[(jt * 16 + fr) * 72 + ks2 * 32 + g * 8];
                ALf[ks2][jt] = *(const h8v*)&VTL[(jt * 16 + fr) * 72 + ks2 * 32 + g * 8];
            }
        for (int ft = w; ft < 18; ft += 4) {
            f4v acc[5];
            #pragma unroll
            for (int jt = 0; jt < 5; ++jt) acc[jt] = (f4v){0.f, 0.f, 0.f, 0.f};
            st_ftile(ksT, ft, fr, g, AHf, ALf, acc);
            #pragma unroll
            for (int jt = 0; jt < 5; ++jt)
                #pragma unroll
                for (int r4 = 0; r4 < 4; ++r4) {
                    int j = jt * 16 + g * 4 + r4;
                    if (j < 65) {
                        unsigned short hh, ll; splitf16(acc[jt][r4], hh, ll);
                        Sg[(size_t)j * FP_ + ft * 16 + fr] = hh;
                        Sg[SSZ_ + (size_t)j * FP_ + ft * 16 + fr] = ll;
                    }
                }
        }
    } else {
        int bh = blk / 5, fg = blk % 5;
        int b = bh >> 4, h = bh & 15;
        int ft = fg * 4 + w;
        ushort_t* Sg = Se + (size_t)bh * 2 * SSZ_;
        f4v acc[5];
        #pragma unroll
        for (int jt = 0; jt < 5; ++jt) acc[jt] = (f4v){0.f, 0.f, 0.f, 0.f};
        for (int m0 = 0; m0 < 512; m0 += 64) {
            if (m0) __syncthreads();
            st_stage(Kpe, Ve, (size_t)b * 512 + m0, (size_t)bh * 512 + m0,
                     h, t, ksT, VTH, VTL);
            __syncthreads();
            if (ft < 18) {
                h8v AHf[2][5], ALf[2][5];
                #pragma unroll
                for (int ks2 = 0; ks2 < 2; ++ks2)
                    #pragma unroll
                    for (int jt = 0; jt < 5; ++jt) {
                        AHf[ks2][jt] = *(const h8v*)&VTH[(jt * 16 + fr) * 72 + ks2 * 32 + g * 8];
                        ALf[ks2][jt] = *(const h8v*)&VTL[(jt * 16 + fr) * 72 + ks2 * 32 + g * 8];
                    }
                st_ftile(ksT, ft, fr, g, AHf, ALf, acc);
            }
        }
        if (ft < 18) {
            #pragma unroll
            for (int jt = 0; jt < 5; ++jt)
                #pragma unroll
                for (int r4 = 0; r4 < 4; ++r4) {
                    int j = jt * 16 + g * 4 + r4;
                    if (j < 65) {
                        unsigned short hh, ll; splitf16(acc[jt][r4], hh, ll);
                        Sg[(size_t)j * FP_ + ft * 16 + fr] = hh;
                        Sg[SSZ_ + (size_t)j * FP_ + ft * 16 + fr] = ll;
                    }
                }
        }
    }
}

// ---------------------------------------------------------------------------
// Exclusive prefix over f16-pair states, in place (element-wise, race-free).
// ---------------------------------------------------------------------------
__global__ __launch_bounds__(256) void prefix_scan(
    ushort_t* __restrict__ Sloc, const ushort_t* __restrict__ Senc)
{
    const int Q = SSZ_ / 4;    // 4680 quad-groups
    int gid = blockIdx.x * 256 + threadIdx.x;
    if (gid >= 32 * Q) return;
    int bh = gid / Q, e = gid - bh * Q;
    const ushort_t* Eb = Senc + (size_t)bh * 2 * SSZ_;
    u16x4 h4 = *(const u16x4*)(Eb + e * 4);
    u16x4 l4 = *(const u16x4*)(Eb + SSZ_ + e * 4);
    float run[4];
    #pragma unroll
    for (int u = 0; u < 4; ++u) run[u] = f16f(h4[u]) + f16f(l4[u]);
    ushort_t* Sb = Sloc + (size_t)bh * NC_ * 2 * SSZ_;
    #pragma unroll 1
    for (int cb = 0; cb < 8; ++cb) {
        u16x4 th[4], tl[4];
        #pragma unroll
        for (int u2 = 0; u2 < 4; ++u2) {
            const ushort_t* P = Sb + (size_t)(cb * 4 + u2) * 2 * SSZ_;
            th[u2] = *(const u16x4*)(P + e * 4);
            tl[u2] = *(const u16x4*)(P + SSZ_ + e * 4);
        }
        #pragma unroll
        for (int u2 = 0; u2 < 4; ++u2) {
            ushort_t* P = Sb + (size_t)(cb * 4 + u2) * 2 * SSZ_;
            u16x4 oh, ol;
            #pragma unroll
            for (int u = 0; u < 4; ++u) {
                unsigned short hh, ll; splitf16(run[u], hh, ll);
                oh[u] = hh; ol[u] = ll;
                run[u] += f16f(th[u2][u]) + f16f(tl[u2][u]);
            }
            *(u16x4*)(P + e * 4) = oh;
            *(u16x4*)(P + SSZ_ + e * 4) = ol;
        }
    }
}

// ---------------------------------------------------------------------------
// MFMA attn_chunk.  QK^T + Y1 = bf16 3-pass (unchanged).  Y2 = f16 2-pass:
// QF single f16 (A), state f16 pair (B).  Epilogue writes f16 pair.
// ---------------------------------------------------------------------------
template <int FW>
__device__ __forceinline__ void y2_slice(
    int f0, const ushort_t* __restrict__ Sth, const ushort_t* __restrict__ Stl,
    const float* qs,
    ushort_t* QF1, ushort_t* STH, ushort_t* STL,
    f4v (&acc)[5], int w, int fr, int g, int t)
{
    for (int i = t; i < 64 * FW; i += 256) {
        int row = i / FW, cc = i % FW;
        int f = f0 + cc;
        float qv;
        if (f == 0)       qv = 1.0f;
        else if (f < 17)  qv = qs[row * 20 + (f - 1)] * 0.5f;
        else if (f < 273) qv = qs[row * 20 + ((f - 17) >> 4)] * qs[row * 20 + ((f - 17) & 15)] * C2C_;
        else              qv = 0.0f;
        QF1[row * 72 + cc] = f16q(qv);
    }
    const int NS = FW / 8;
    for (int i = t; i < 65 * NS; i += 256) {
        int j = i / NS, seg = i % NS;
        *(s8v*)&STH[j * 72 + seg * 8] = *(const s8v*)(Sth + (size_t)j * FP_ + f0 + seg * 8);
        *(s8v*)&STL[j * 72 + seg * 8] = *(const s8v*)(Stl + (size_t)j * FP_ + f0 + seg * 8);
    }
    __syncthreads();
    #pragma unroll
    for (int ks2 = 0; ks2 < FW / 32; ++ks2) {
        h8v a = *(const h8v*)&QF1[(16 * w + fr) * 72 + ks2 * 32 + g * 8];
        #pragma unroll
        for (int jt = 0; jt < 5; ++jt) {
            h8v bh_ = *(const h8v*)&STH[(jt * 16 + fr) * 72 + ks2 * 32 + g * 8];
            h8v bl_ = *(const h8v*)&STL[(jt * 16 + fr) * 72 + ks2 * 32 + g * 8];
            acc[jt] = MFMAH_(a, bh_, acc[jt], 0, 0, 0);
            acc[jt] = MFMAH_(a, bl_, acc[jt], 0, 0, 0);
        }
    }
    __syncthreads();
}

__global__ __launch_bounds__(256) void attn_chunk(
    const float* __restrict__ qp, const float* __restrict__ kp,
    const float* __restrict__ v, const ushort_t* __restrict__ Spre,
    ushort_t* __restrict__ atnh, ushort_t* __restrict__ atnl)
{
    __shared__ ushort_t U[20736];
    __shared__ float qs[64 * 20];
    __shared__ float den_s[64];
    ushort_t* AH  = U;            // [64][72]  (bf16)
    ushort_t* AL  = U + 4608;
    ushort_t* QH  = U + 9216;     // [64][40]  (bf16)
    ushort_t* QL  = U + 11776;
    ushort_t* KH  = U + 14336;
    ushort_t* KL  = U + 16896;
    ushort_t* VTH = U + 9216;     // [80][72]  (bf16)
    ushort_t* VTL = U + 14976;
    ushort_t* QF1 = U;            // [64][72]  (f16)
    ushort_t* STH = U + 9216;     // [80][72]  (f16)
    ushort_t* STL = U + 14976;

    int bid = blockIdx.x;
    int bh = bid >> 5, c = bid & 31;
    int b = bh >> 4, h = bh & 15;
    int t = threadIdx.x;
    int w = t >> 6, lane = t & 63, fr = lane & 15, g = lane >> 4;
    int rowbase = b * N_ + c * CHK_;

    {
        int r = t >> 2, q4 = t & 3;
        float4 qv = *(const float4*)&qp[(size_t)(rowbase + r) * 256 + h * 16 + q4 * 4];
        float4 kv = *(const float4*)&kp[(size_t)(rowbase + r) * 256 + h * 16 + q4 * 4];
        u16x4 hh, ll;
        splitf4(qv, hh, ll);
        *(u16x4*)&QH[r * 40 + q4 * 4] = hh;
        *(u16x4*)&QL[r * 40 + q4 * 4] = ll;
        splitf4(kv, hh, ll);
        *(u16x4*)&KH[r * 40 + q4 * 4] = hh;
        *(u16x4*)&KL[r * 40 + q4 * 4] = ll;
        u16x4 z4 = (u16x4){0, 0, 0, 0};
        *(u16x4*)&QH[r * 40 + 16 + q4 * 4] = z4;
        *(u16x4*)&QL[r * 40 + 16 + q4 * 4] = z4;
        *(u16x4*)&KH[r * 40 + 16 + q4 * 4] = z4;
        *(u16x4*)&KL[r * 40 + 16 + q4 * 4] = z4;
        qs[r * 20 + q4 * 4 + 0] = qv.x;
        qs[r * 20 + q4 * 4 + 1] = qv.y;
        qs[r * 20 + q4 * 4 + 2] = qv.z;
        qs[r * 20 + q4 * 4 + 3] = qv.w;
    }
    __syncthreads();

    {
        s8v qh = *(const s8v*)&QH[(16 * w + fr) * 40 + g * 8];
        s8v ql = *(const s8v*)&QL[(16 * w + fr) * 40 + g * 8];
        f4v sacc[4];
        #pragma unroll
        for (int jt = 0; jt < 4; ++jt) sacc[jt] = (f4v){0.f, 0.f, 0.f, 0.f};
        #pragma unroll
        for (int jt = 0; jt < 4; ++jt) {
            s8v kh = *(const s8v*)&KH[(jt * 16 + fr) * 40 + g * 8];
            s8v kl = *(const s8v*)&KL[(jt * 16 + fr) * 40 + g * 8];
            sacc[jt] = MFMA_(qh, kh, sacc[jt], 0, 0, 0);
            sacc[jt] = MFMA_(qh, kl, sacc[jt], 0, 0, 0);
            sacc[jt] = MFMA_(ql, kh, sacc[jt], 0, 0, 0);
        }
        #pragma unroll
        for (int jt = 0; jt < 4; ++jt)
            #pragma unroll
            for (int r4 = 0; r4 < 4; ++r4) {
                int row = 16 * w + g * 4 + r4, col = jt * 16 + fr;
                float s = sacc[jt][r4];
                float a = (row >= col) ? (fmaf(s, 0.25f, 1.0f) + s * s * 0.03125f) : 0.f;
                unsigned short hh, ll; split1(a, hh, ll);
                AH[row * 72 + col] = hh;
                AL[row * 72 + col] = ll;
            }
    }
    __syncthreads();

    for (int i = t; i < 80 * 64; i += 256) {
        int j = i >> 6, m = i & 63;
        float val;
        if (j < 64)       val = v[((size_t)bh * N_ + c * CHK_ + m) * HD_ + j];
        else if (j == 64) val = 1.0f;
        else              val = 0.0f;
        unsigned short hh, ll; split1(val, hh, ll);
        VTH[j * 72 + m] = hh;
        VTL[j * 72 + m] = ll;
    }
    __syncthreads();

    f4v acc[5];
    #pragma unroll
    for (int jt = 0; jt < 5; ++jt) acc[jt] = (f4v){0.f, 0.f, 0.f, 0.f};
    #pragma unroll
    for (int ks2 = 0; ks2 < 2; ++ks2) {
        s8v ah = *(const s8v*)&AH[(16 * w + fr) * 72 + ks2 * 32 + g * 8];
        s8v al = *(const s8v*)&AL[(16 * w + fr) * 72 + ks2 * 32 + g * 8];
        #pragma unroll
        for (int jt = 0; jt < 5; ++jt) {
            s8v bh_ = *(const s8v*)&VTH[(jt * 16 + fr) * 72 + ks2 * 32 + g * 8];
            s8v bl_ = *(const s8v*)&VTL[(jt * 16 + fr) * 72 + ks2 * 32 + g * 8];
            acc[jt] = MFMA_(ah, bh_, acc[jt], 0, 0, 0);
            acc[jt] = MFMA_(ah, bl_, acc[jt], 0, 0, 0);
            acc[jt] = MFMA_(al, bh_, acc[jt], 0, 0, 0);
        }
    }
    __syncthreads();

    const ushort_t* Sth = Spre + ((size_t)bh * NC_ + c) * 2 * SSZ_;
    const ushort_t* Stl = Sth + SSZ_;
    for (int p = 0; p < 4; ++p)
        y2_slice<64>(p * 64, Sth, Stl, qs, QF1, STH, STL, acc, w, fr, g, t);
    y2_slice<32>(256, Sth, Stl, qs, QF1, STH, STL, acc, w, fr, g, t);

    if (fr == 0) {
        #pragma unroll
        for (int r4 = 0; r4 < 4; ++r4)
            den_s[16 * w + g * 4 + r4] = acc[4][r4];
    }
    __syncthreads();
    #pragma unroll
    for (int r4 = 0; r4 < 4; ++r4) {
        float z = 1.0f / (den_s[16 * w + g * 4 + r4] + EPS_);
        int row = rowbase + 16 * w + g * 4 + r4;
        #pragma unroll
        for (int jt = 0; jt < 4; ++jt) {
            float val = acc[jt][r4] * z;
            unsigned short hh, ll; splitf16(val, hh, ll);
            size_t idx = (size_t)row * 1024 + h * 64 + jt * 16 + fr;
            atnh[idx] = hh;
            atnl[idx] = ll;
        }
    }
}

// ---------------------------------------------------------------------------
extern "C" void kernel_launch(void* const* d_in, const int* in_sizes, int n_in,
                              void* d_out, int out_size, void* d_ws, size_t ws_size,
                              hipStream_t stream)
{
    const float* x    = (const float*)d_in[0];
    const float* Wq   = (const float*)d_in[1];
    const float* Wk   = (const float*)d_in[2];
    const float* Wv   = (const float*)d_in[3];
    const float* Wke  = (const float*)d_in[4];
    const float* Wve  = (const float*)d_in[5];
    const float* Wout = (const float*)d_in[6];
    float* out = (float*)d_out;
    float* ws  = (float*)d_ws;

    // f32 region
    float* tmpq  = ws;                                 // 1,048,576
    float* tmpk  = tmpq  + (size_t)1048576;            // 1,048,576
    float* tmpke = tmpk  + (size_t)1048576;            //   262,144
    float* v     = tmpke + (size_t)262144;             // 4,194,304
    float* ve    = v     + (size_t)4194304;            // 1,048,576
    float* Sloc  = ve    + (size_t)1048576;            // 19,169,280 (f16-pair states)
    float* Senc  = Sloc  + (size_t)19169280;           //   599,040  (f16-pair states)
    // f16 region
    ushort_t* xh = (ushort_t*)(Senc + 599040);         // 4,194,304 shorts
    ushort_t* xl = xh + (size_t)4194304;               // 4,194,304 shorts
    // overlays:
    ushort_t* w1 = (ushort_t*)Sloc;                    // 1,572,864 shorts (dead before state_all)
    ushort_t* w2 = w1 + (size_t)1572864;               // 1,310,720 shorts
    ushort_t* wo = (ushort_t*)tmpq;                    // 1,048,576 shorts (tmpq dead after attn)
    ushort_t* atnh = xh;                               // xh/xl dead after proj2
    ushort_t* atnl = xl;
    ushort_t* Sloc_us = (ushort_t*)Sloc;
    ushort_t* Senc_us = (ushort_t*)Senc;

    dim3 blk(256);

    split_all<<<6912, blk, 0, stream>>>(x, Wq, Wk, Wv, Wke, Wve, xh, xl, w1, w2);
    proj2<<<464, blk, 0, stream>>>(xh, xl, w1, w2, tmpq, tmpk, v, tmpke, ve);
    state_all<<<160 + 32 * NC_, blk, 0, stream>>>(tmpke, ve, Senc_us, tmpk, v, Sloc_us);
    prefix_scan<<<585, blk, 0, stream>>>(Sloc_us, Senc_us);
    attn_chunk<<<32 * NC_, blk, 0, stream>>>(tmpq, tmpk, v, Sloc_us, atnh, atnl);
    split_wo<<<1024, blk, 0, stream>>>(Wout, wo);
    out_gemm<<<256, blk, 0, stream>>>(atnh, atnl, wo, out);
}

// Round 9
// 180.123 us; speedup vs baseline: 5.0912x; 1.0689x over previous
//
#include <hip/hip_runtime.h>

// Problem constants
#define B_    2
#define N_    2048
#define H_    16
#define HD_   64
#define ENC_  512
#define FP_   288
#define CHK_  64
#define NC_   32
#define SSZ_  18720                  // state elems: [65 j][288 f]; f16 hi/lo planes
#define C2C_  0.17677669529663687f   // 1/(4*sqrt(2))
#define EPS_  1e-12f

using s8v   = __attribute__((ext_vector_type(8))) short;     // 8x16-bit carrier
using h8v   = __attribute__((ext_vector_type(8))) _Float16;  // 8 f16 (4 VGPRs)
using f4v   = __attribute__((ext_vector_type(4))) float;
using u16x4 = __attribute__((ext_vector_type(4))) unsigned short;
typedef unsigned short ushort_t;

// ---- bf16 helpers (attn QK^T / Y1)
__device__ __forceinline__ unsigned short bfh(float x) {
    unsigned int u = __float_as_uint(x);
    return (unsigned short)((u + 0x7FFF + ((u >> 16) & 1)) >> 16);
}
__device__ __forceinline__ float bff(unsigned short h) {
    return __uint_as_float(((unsigned int)h) << 16);
}
__device__ __forceinline__ void split1(float x, unsigned short& h, unsigned short& l) {
    h = bfh(x); l = bfh(x - bff(h));
}
__device__ __forceinline__ void splitf4(float4 v, u16x4& h, u16x4& l) {
    unsigned short h0 = bfh(v.x), h1 = bfh(v.y), h2 = bfh(v.z), h3 = bfh(v.w);
    h = (u16x4){h0, h1, h2, h3};
    l = (u16x4){bfh(v.x - bff(h0)), bfh(v.y - bff(h1)),
                bfh(v.z - bff(h2)), bfh(v.w - bff(h3))};
}

// ---- f16 helpers
__device__ __forceinline__ unsigned short f16q(float x) {
    _Float16 h = (_Float16)x;
    return __builtin_bit_cast(unsigned short, h);
}
__device__ __forceinline__ float f16f(unsigned short u) {
    return (float)__builtin_bit_cast(_Float16, u);
}
__device__ __forceinline__ void splitf16(float x, unsigned short& h, unsigned short& l) {
    _Float16 hh = (_Float16)x;
    h = __builtin_bit_cast(unsigned short, hh);
    l = f16q(x - (float)hh);
}
__device__ __forceinline__ void splitf16_4(float4 v, u16x4& h, u16x4& l) {
    unsigned short h0, l0, h1, l1, h2, l2, h3, l3;
    splitf16(v.x, h0, l0); splitf16(v.y, h1, l1);
    splitf16(v.z, h2, l2); splitf16(v.w, h3, l3);
    h = (u16x4){h0, h1, h2, h3};
    l = (u16x4){l0, l1, l2, l3};
}
__device__ __forceinline__ u16x4 f16q4(float4 v) {
    return (u16x4){f16q(v.x), f16q(v.y), f16q(v.z), f16q(v.w)};
}

#define MFMA_  __builtin_amdgcn_mfma_f32_16x16x32_bf16
#define MFMAH_ __builtin_amdgcn_mfma_f32_16x16x32_f16

// async global->LDS, 16B per lane; LDS dest = wave-uniform base + lane*16
__device__ __forceinline__ void gld16(const void* g, void* l) {
    __builtin_amdgcn_global_load_lds(
        (const __attribute__((address_space(1))) unsigned int*)g,
        (__attribute__((address_space(3))) unsigned int*)l, 16, 0, 0);
}

// bijective XCD swizzle (m204)
__device__ __forceinline__ int xcd_swz(int b, int nwg) {
    int q = nwg >> 3, r = nwg & 7;
    int xcd = b & 7, loc = b >> 3;
    return (xcd < r ? xcd * (q + 1) : r * (q + 1) + (xcd - r) * q) + loc;
}

// ---------------------------------------------------------------------------
// split_all: x -> f16 pair ; [Wq;Wk;Wv] -> w1 ; [Wke;Wve] -> w2 ; Wout -> wo.
// ---------------------------------------------------------------------------
#define X_F4   1048576      // 4096*1024/4
#define W1_F4  393216       // 1536*256
#define W2_F4  327680       // 1280*256
#define WO_F4  262144       // 1024*256

__global__ __launch_bounds__(256) void split_all(
    const float* __restrict__ x,
    const float* __restrict__ Wq, const float* __restrict__ Wk,
    const float* __restrict__ Wv, const float* __restrict__ Wke,
    const float* __restrict__ Wve, const float* __restrict__ Wout,
    ushort_t* __restrict__ xh, ushort_t* __restrict__ xl,
    ushort_t* __restrict__ w1, ushort_t* __restrict__ w2,
    ushort_t* __restrict__ wo)
{
    int gid = blockIdx.x * 256 + threadIdx.x;
    if (gid < X_F4) {
        float4 vv = ((const float4*)x)[gid];
        u16x4 h, l; splitf16_4(vv, h, l);
        ((u16x4*)xh)[gid] = h; ((u16x4*)xl)[gid] = l;
    } else if (gid < X_F4 + W1_F4) {
        int i = gid - X_F4;
        int row = i >> 8, c4 = i & 255;
        const float* s = (row < 256) ? Wq + (size_t)row * 1024
                       : (row < 512) ? Wk + (size_t)(row - 256) * 1024
                                     : Wv + (size_t)(row - 512) * 1024;
        ((u16x4*)w1)[i] = f16q4(*(const float4*)(s + c4 * 4));
    } else if (gid < X_F4 + W1_F4 + W2_F4) {
        int i = gid - X_F4 - W1_F4;
        int row = i >> 8, c4 = i & 255;
        const float* s = (row < 256) ? Wke + (size_t)row * 1024
                                     : Wve + (size_t)(row - 256) * 1024;
        ((u16x4*)w2)[i] = f16q4(*(const float4*)(s + c4 * 4));
    } else {
        int i = gid - X_F4 - W1_F4 - W2_F4;
        ((u16x4*)wo)[i] = f16q4(((const float4*)Wout)[i]);
    }
}

// ---------------------------------------------------------------------------
// f16 2-pass GEMM body with double-buffered global_load_lds staging (m97/T3):
// LDS: 2 buffers x {Ahi[128][32] | Alo[128][32] | B[128][32]} f16 = 48 KB.
// STAGE(next) issued before ds_read+MFMA(cur); one __syncthreads per K-step
// (its pre-barrier vmcnt drain completes the prefetch).
// Row remap: arow = (gr>>SHIFT)*rowjump + (gr & ((1<<SHIFT)-1)).
// ---------------------------------------------------------------------------
template <int SHIFT>
__device__ __forceinline__ void bg128(
    const ushort_t* __restrict__ Ah, const ushort_t* __restrict__ Al,
    const ushort_t* __restrict__ Wh,
    int bx, int by, int rowjump,
    ushort_t* SM, f4v (&acc)[4][4])
{
    int t = threadIdx.x;
    int w = t >> 6, lane = t & 63;
    int row0 = by * 128, col0 = bx * 128;
    int wrow = (w >> 1) * 64, wcol = (w & 1) * 64;
    int fr = lane & 15, g = lane >> 4;

    // per-lane staging coords: wave w stages rows [w*32, w*32+32) of each tile,
    // 2 calls of 64 chunks; chunk c -> row w*32 + (c>>2), col-group c&3.
    int c0 = lane, c1 = 64 + lane;
    int r0 = w * 32 + (c0 >> 2), k80 = (c0 & 3) * 8;
    int r1 = w * 32 + (c1 >> 2), k81 = (c1 & 3) * 8;
    int gr0 = row0 + r0, gr1 = row0 + r1;
    size_t a0 = (size_t)(gr0 >> SHIFT) * rowjump + (gr0 & ((1 << SHIFT) - 1));
    size_t a1 = (size_t)(gr1 >> SHIFT) * rowjump + (gr1 & ((1 << SHIFT) - 1));
    const ushort_t* pA0h = Ah + a0 * 1024 + k80;
    const ushort_t* pA1h = Ah + a1 * 1024 + k81;
    const ushort_t* pA0l = Al + a0 * 1024 + k80;
    const ushort_t* pA1l = Al + a1 * 1024 + k81;
    const ushort_t* pW0  = Wh + (size_t)(col0 + r0) * 1024 + k80;
    const ushort_t* pW1  = Wh + (size_t)(col0 + r1) * 1024 + k81;
    int woff = w * 1024;   // wave slice in shorts

    #pragma unroll
    for (int mt = 0; mt < 4; ++mt)
        #pragma unroll
        for (int nt = 0; nt < 4; ++nt) acc[mt][nt] = (f4v){0.f, 0.f, 0.f, 0.f};

    auto STAGE = [&](int buf, int k0) {
        ushort_t* Bp = SM + buf * 12288;
        gld16(pA0h + k0, Bp + woff);
        gld16(pA1h + k0, Bp + woff + 512);
        gld16(pA0l + k0, Bp + 4096 + woff);
        gld16(pA1l + k0, Bp + 4096 + woff + 512);
        gld16(pW0  + k0, Bp + 8192 + woff);
        gld16(pW1  + k0, Bp + 8192 + woff + 512);
    };

    STAGE(0, 0);
    __syncthreads();
    int cur = 0;
    for (int k0 = 0; k0 < 1024; k0 += 32) {
        if (k0 + 32 < 1024) STAGE(cur ^ 1, k0 + 32);
        ushort_t* Bp = SM + cur * 12288;
        h8v a_h[4], a_l[4], b_[4];
        #pragma unroll
        for (int mt = 0; mt < 4; ++mt) {
            a_h[mt] = *(const h8v*)&Bp[(wrow + mt * 16 + fr) * 32 + g * 8];
            a_l[mt] = *(const h8v*)&Bp[4096 + (wrow + mt * 16 + fr) * 32 + g * 8];
        }
        #pragma unroll
        for (int nt = 0; nt < 4; ++nt)
            b_[nt] = *(const h8v*)&Bp[8192 + (wcol + nt * 16 + fr) * 32 + g * 8];
        #pragma unroll
        for (int mt = 0; mt < 4; ++mt)
            #pragma unroll
            for (int nt = 0; nt < 4; ++nt) {
                acc[mt][nt] = MFMAH_(a_h[mt], b_[nt], acc[mt][nt], 0, 0, 0);
                acc[mt][nt] = MFMAH_(a_l[mt], b_[nt], acc[mt][nt], 0, 0, 0);
            }
        __syncthreads();
        cur ^= 1;
    }
}

// ---------------------------------------------------------------------------
// proj2: main (384 blocks: 32 by x 12 bx) + enc (80 blocks: 8 by x 10 bx).
// ---------------------------------------------------------------------------
__global__ __launch_bounds__(256) void proj2(
    const ushort_t* __restrict__ xh, const ushort_t* __restrict__ xl,
    const ushort_t* __restrict__ w1, const ushort_t* __restrict__ w2,
    float* __restrict__ tmpq, float* __restrict__ tmpk, float* __restrict__ v,
    float* __restrict__ tmpke, float* __restrict__ ve)
{
    __shared__ ushort_t SM[24576];
    f4v acc[4][4];
    int blk = xcd_swz(blockIdx.x, 464);
    int t = threadIdx.x, w = t >> 6, lane = t & 63;
    int wrow = (w >> 1) * 64, wcol = (w & 1) * 64;
    int fr = lane & 15, g = lane >> 4;

    if (blk < 384) {
        int bx = blk % 12, by = blk / 12;
        bg128<12>(xh, xl, w1, bx, by, 0, SM, acc);
        int row0 = by * 128, col0 = bx * 128;
        #pragma unroll
        for (int mt = 0; mt < 4; ++mt)
            #pragma unroll
            for (int nt = 0; nt < 4; ++nt)
                #pragma unroll
                for (int r4 = 0; r4 < 4; ++r4) {
                    int r  = row0 + wrow + mt * 16 + g * 4 + r4;
                    int cc = col0 + wcol + nt * 16 + fr;
                    float val = acc[mt][nt][r4];
                    if (cc < 256)      tmpq[(size_t)r * 256 + cc] = val;
                    else if (cc < 512) tmpk[(size_t)r * 256 + (cc - 256)] = val;
                    else {
                        int c2 = cc - 512, hh = c2 >> 6, jj = c2 & 63;
                        int bb = r >> 11, n = r & 2047;
                        v[(((size_t)(bb * 16 + hh)) * 2048 + n) * 64 + jj] = val;
                    }
                }
    } else {
        int r2 = blk - 384;
        int bx = r2 % 10, by = r2 / 10;
        bg128<9>(xh, xl, w2, bx, by, 2048, SM, acc);
        int row0 = by * 128, col0 = bx * 128;
        #pragma unroll
        for (int mt = 0; mt < 4; ++mt)
            #pragma unroll
            for (int nt = 0; nt < 4; ++nt)
                #pragma unroll
                for (int r4 = 0; r4 < 4; ++r4) {
                    int r  = row0 + wrow + mt * 16 + g * 4 + r4;
                    int cc = col0 + wcol + nt * 16 + fr;
                    float val = acc[mt][nt][r4];
                    if (cc < 256) tmpke[(size_t)r * 256 + cc] = val;
                    else {
                        int c2 = cc - 256, hh = c2 >> 6, jj = c2 & 63;
                        int bb = r >> 9, n = r & 511;
                        ve[(((size_t)(bb * 16 + hh)) * 512 + n) * 64 + jj] = val;
                    }
                }
    }
}

// out_gemm: attn(f16 pair) @ Wout(f16)^T -> f32 d_out.  256 blocks.
__global__ __launch_bounds__(256) void out_gemm(
    const ushort_t* __restrict__ Ah, const ushort_t* __restrict__ Al,
    const ushort_t* __restrict__ Wh, float* __restrict__ out)
{
    __shared__ ushort_t SM[24576];
    f4v acc[4][4];
    int blk = xcd_swz(blockIdx.x, 256);
    int bx = blk & 7, by = blk >> 3;
    bg128<12>(Ah, Al, Wh, bx, by, 0, SM, acc);
    int t = threadIdx.x, w = t >> 6, lane = t & 63;
    int wrow = (w >> 1) * 64, wcol = (w & 1) * 64;
    int fr = lane & 15, g = lane >> 4;
    int row0 = by * 128, col0 = bx * 128;
    #pragma unroll
    for (int mt = 0; mt < 4; ++mt)
        #pragma unroll
        for (int nt = 0; nt < 4; ++nt)
            #pragma unroll
            for (int r4 = 0; r4 < 4; ++r4) {
                int r  = row0 + wrow + mt * 16 + g * 4 + r4;
                int cc = col0 + wcol + nt * 16 + fr;
                out[(size_t)r * 1024 + cc] = acc[mt][nt][r4];
            }
}

// ---------------------------------------------------------------------------
// MFMA state kernel, f16 2-pass (unchanged from round 8).
// ---------------------------------------------------------------------------
__device__ __forceinline__ void st_stage(
    const float* __restrict__ Kp, const float* __restrict__ V,
    size_t krow0, size_t vrow0, int h, int t,
    float* ksT, ushort_t* VTH, ushort_t* VTL)
{
    {
        int r = t >> 2, q4 = t & 3;
        float4 kv = *(const float4*)&Kp[(krow0 + r) * 256 + h * 16 + q4 * 4];
        ksT[(q4 * 4 + 0) * 68 + r] = kv.x;
        ksT[(q4 * 4 + 1) * 68 + r] = kv.y;
        ksT[(q4 * 4 + 2) * 68 + r] = kv.z;
        ksT[(q4 * 4 + 3) * 68 + r] = kv.w;
    }
    if (t < 64) ksT[16 * 68 + t] = 1.0f;
    {
        int r = t & 63, jg = t >> 6;
        #pragma unroll
        for (int cc = 0; cc < 4; ++cc) {
            float4 vv = *(const float4*)&V[(vrow0 + r) * HD_ + jg * 16 + cc * 4];
            float vals[4] = {vv.x, vv.y, vv.z, vv.w};
            #pragma unroll
            for (int e = 0; e < 4; ++e) {
                int j = jg * 16 + cc * 4 + e;
                unsigned short hh, ll; splitf16(vals[e], hh, ll);
                VTH[j * 72 + r] = hh;
                VTL[j * 72 + r] = ll;
            }
        }
    }
    if (t < 64) { VTH[64 * 72 + t] = 0x3C00; VTL[64 * 72 + t] = 0; }  // f16 1.0
}

__device__ __forceinline__ void st_ftile(
    const float* ksT, int ft, int fr, int g,
    const h8v (&AHf)[2][5], const h8v (&ALf)[2][5], f4v (&acc)[5])
{
    int f = ft * 16 + fr;
    int fi, fj; float scale;
    if (f == 0)       { fi = 16; fj = 16; scale = 1.0f; }
    else if (f < 17)  { fi = f - 1; fj = 16; scale = 0.5f; }
    else if (f < 273) { fi = (f - 17) >> 4; fj = (f - 17) & 15; scale = C2C_; }
    else              { fi = 16; fj = 16; scale = 0.0f; }
    #pragma unroll
    for (int ks2 = 0; ks2 < 2; ++ks2) {
        const float* pa = ksT + fi * 68 + ks2 * 32 + g * 8;
        const float* pb = ksT + fj * 68 + ks2 * 32 + g * 8;
        h8v bv;
        #pragma unroll
        for (int e = 0; e < 8; ++e) bv[e] = (_Float16)(pa[e] * pb[e] * scale);
        #pragma unroll
        for (int jt = 0; jt < 5; ++jt) {
            acc[jt] = MFMAH_(AHf[ks2][jt], bv, acc[jt], 0, 0, 0);
            acc[jt] = MFMAH_(ALf[ks2][jt], bv, acc[jt], 0, 0, 0);
        }
    }
}

__global__ __launch_bounds__(256) void state_all(
    const float* __restrict__ Kpe, const float* __restrict__ Ve, ushort_t* __restrict__ Se,
    const float* __restrict__ Kpc, const float* __restrict__ Vc, ushort_t* __restrict__ Sc)
{
    __shared__ float ksT[17 * 68];
    __shared__ ushort_t VTH[80 * 72], VTL[80 * 72];
    int blk = blockIdx.x, t = threadIdx.x;
    int w = t >> 6, lane = t & 63, fr = lane & 15, g = lane >> 4;

    for (int i = t; i < 15 * 72; i += 256) { VTH[65 * 72 + i] = 0; VTL[65 * 72 + i] = 0; }

    if (blk >= 160) {
        int b2 = blk - 160;
        int c = b2 & 31, bh = b2 >> 5;
        int b = bh >> 4, h = bh & 15;
        ushort_t* Sg = Sc + ((size_t)bh * NC_ + c) * 2 * SSZ_;
        st_stage(Kpc, Vc, (size_t)b * 2048 + c * 64, (size_t)bh * 2048 + c * 64,
                 h, t, ksT, VTH, VTL);
        __syncthreads();
        h8v AHf[2][5], ALf[2][5];
        #pragma unroll
        for (int ks2 = 0; ks2 < 2; ++ks2)
            #pragma unroll
            for (int jt = 0; jt < 5; ++jt) {
                AHf[ks2][jt] = *(const h8v*)&VTH[(jt * 16 + fr) * 72 + ks2 * 32 + g * 8];
                ALf[ks2][jt] = *(const h8v*)&VTL[(jt * 16 + fr) * 72 + ks2 * 32 + g * 8];
            }
        for (int ft = w; ft < 18; ft += 4) {
            f4v acc[5];
            #pragma unroll
            for (int jt = 0; jt < 5; ++jt) acc[jt] = (f4v){0.f, 0.f, 0.f, 0.f};
            st_ftile(ksT, ft, fr, g, AHf, ALf, acc);
            #pragma unroll
            for (int jt = 0; jt < 5; ++jt)
                #pragma unroll
                for (int r4 = 0; r4 < 4; ++r4) {
                    int j = jt * 16 + g * 4 + r4;
                    if (j < 65) {
                        unsigned short hh, ll; splitf16(acc[jt][r4], hh, ll);
                        Sg[(size_t)j * FP_ + ft * 16 + fr] = hh;
                        Sg[SSZ_ + (size_t)j * FP_ + ft * 16 + fr] = ll;
                    }
                }
        }
    } else {
        int bh = blk / 5, fg = blk % 5;
        int b = bh >> 4, h = bh & 15;
        int ft = fg * 4 + w;
        ushort_t* Sg = Se + (size_t)bh * 2 * SSZ_;
        f4v acc[5];
        #pragma unroll
        for (int jt = 0; jt < 5; ++jt) acc[jt] = (f4v){0.f, 0.f, 0.f, 0.f};
        for (int m0 = 0; m0 < 512; m0 += 64) {
            if (m0) __syncthreads();
            st_stage(Kpe, Ve, (size_t)b * 512 + m0, (size_t)bh * 512 + m0,
                     h, t, ksT, VTH, VTL);
            __syncthreads();
            if (ft < 18) {
                h8v AHf[2][5], ALf[2][5];
                #pragma unroll
                for (int ks2 = 0; ks2 < 2; ++ks2)
                    #pragma unroll
                    for (int jt = 0; jt < 5; ++jt) {
                        AHf[ks2][jt] = *(const h8v*)&VTH[(jt * 16 + fr) * 72 + ks2 * 32 + g * 8];
                        ALf[ks2][jt] = *(const h8v*)&VTL[(jt * 16 + fr) * 72 + ks2 * 32 + g * 8];
                    }
                st_ftile(ksT, ft, fr, g, AHf, ALf, acc);
            }
        }
        if (ft < 18) {
            #pragma unroll
            for (int jt = 0; jt < 5; ++jt)
                #pragma unroll
                for (int r4 = 0; r4 < 4; ++r4) {
                    int j = jt * 16 + g * 4 + r4;
                    if (j < 65) {
                        unsigned short hh, ll; splitf16(acc[jt][r4], hh, ll);
                        Sg[(size_t)j * FP_ + ft * 16 + fr] = hh;
                        Sg[SSZ_ + (size_t)j * FP_ + ft * 16 + fr] = ll;
                    }
                }
        }
    }
}

// ---------------------------------------------------------------------------
// Exclusive prefix over f16-pair states, in place (element-wise, race-free).
// ---------------------------------------------------------------------------
__global__ __launch_bounds__(256) void prefix_scan(
    ushort_t* __restrict__ Sloc, const ushort_t* __restrict__ Senc)
{
    const int Q = SSZ_ / 4;    // 4680 quad-groups
    int gid = blockIdx.x * 256 + threadIdx.x;
    if (gid >= 32 * Q) return;
    int bh = gid / Q, e = gid - bh * Q;
    const ushort_t* Eb = Senc + (size_t)bh * 2 * SSZ_;
    u16x4 h4 = *(const u16x4*)(Eb + e * 4);
    u16x4 l4 = *(const u16x4*)(Eb + SSZ_ + e * 4);
    float run[4];
    #pragma unroll
    for (int u = 0; u < 4; ++u) run[u] = f16f(h4[u]) + f16f(l4[u]);
    ushort_t* Sb = Sloc + (size_t)bh * NC_ * 2 * SSZ_;
    #pragma unroll 1
    for (int cb = 0; cb < 8; ++cb) {
        u16x4 th[4], tl[4];
        #pragma unroll
        for (int u2 = 0; u2 < 4; ++u2) {
            const ushort_t* P = Sb + (size_t)(cb * 4 + u2) * 2 * SSZ_;
            th[u2] = *(const u16x4*)(P + e * 4);
            tl[u2] = *(const u16x4*)(P + SSZ_ + e * 4);
        }
        #pragma unroll
        for (int u2 = 0; u2 < 4; ++u2) {
            ushort_t* P = Sb + (size_t)(cb * 4 + u2) * 2 * SSZ_;
            u16x4 oh, ol;
            #pragma unroll
            for (int u = 0; u < 4; ++u) {
                unsigned short hh, ll; splitf16(run[u], hh, ll);
                oh[u] = hh; ol[u] = ll;
                run[u] += f16f(th[u2][u]) + f16f(tl[u2][u]);
            }
            *(u16x4*)(P + e * 4) = oh;
            *(u16x4*)(P + SSZ_ + e * 4) = ol;
        }
    }
}

// ---------------------------------------------------------------------------
// MFMA attn_chunk (unchanged from round 8).
// ---------------------------------------------------------------------------
template <int FW>
__device__ __forceinline__ void y2_slice(
    int f0, const ushort_t* __restrict__ Sth, const ushort_t* __restrict__ Stl,
    const float* qs,
    ushort_t* QF1, ushort_t* STH, ushort_t* STL,
    f4v (&acc)[5], int w, int fr, int g, int t)
{
    for (int i = t; i < 64 * FW; i += 256) {
        int row = i / FW, cc = i % FW;
        int f = f0 + cc;
        float qv;
        if (f == 0)       qv = 1.0f;
        else if (f < 17)  qv = qs[row * 20 + (f - 1)] * 0.5f;
        else if (f < 273) qv = qs[row * 20 + ((f - 17) >> 4)] * qs[row * 20 + ((f - 17) & 15)] * C2C_;
        else              qv = 0.0f;
        QF1[row * 72 + cc] = f16q(qv);
    }
    const int NS = FW / 8;
    for (int i = t; i < 65 * NS; i += 256) {
        int j = i / NS, seg = i % NS;
        *(s8v*)&STH[j * 72 + seg * 8] = *(const s8v*)(Sth + (size_t)j * FP_ + f0 + seg * 8);
        *(s8v*)&STL[j * 72 + seg * 8] = *(const s8v*)(Stl + (size_t)j * FP_ + f0 + seg * 8);
    }
    __syncthreads();
    #pragma unroll
    for (int ks2 = 0; ks2 < FW / 32; ++ks2) {
        h8v a = *(const h8v*)&QF1[(16 * w + fr) * 72 + ks2 * 32 + g * 8];
        #pragma unroll
        for (int jt = 0; jt < 5; ++jt) {
            h8v bh_ = *(const h8v*)&STH[(jt * 16 + fr) * 72 + ks2 * 32 + g * 8];
            h8v bl_ = *(const h8v*)&STL[(jt * 16 + fr) * 72 + ks2 * 32 + g * 8];
            acc[jt] = MFMAH_(a, bh_, acc[jt], 0, 0, 0);
            acc[jt] = MFMAH_(a, bl_, acc[jt], 0, 0, 0);
        }
    }
    __syncthreads();
}

__global__ __launch_bounds__(256) void attn_chunk(
    const float* __restrict__ qp, const float* __restrict__ kp,
    const float* __restrict__ v, const ushort_t* __restrict__ Spre,
    ushort_t* __restrict__ atnh, ushort_t* __restrict__ atnl)
{
    __shared__ ushort_t U[20736];
    __shared__ float qs[64 * 20];
    __shared__ float den_s[64];
    ushort_t* AH  = U;            // [64][72]  (bf16)
    ushort_t* AL  = U + 4608;
    ushort_t* QH  = U + 9216;     // [64][40]  (bf16)
    ushort_t* QL  = U + 11776;
    ushort_t* KH  = U + 14336;
    ushort_t* KL  = U + 16896;
    ushort_t* VTH = U + 9216;     // [80][72]  (bf16)
    ushort_t* VTL = U + 14976;
    ushort_t* QF1 = U;            // [64][72]  (f16)
    ushort_t* STH = U + 9216;     // [80][72]  (f16)
    ushort_t* STL = U + 14976;

    int bid = blockIdx.x;
    int bh = bid >> 5, c = bid & 31;
    int b = bh >> 4, h = bh & 15;
    int t = threadIdx.x;
    int w = t >> 6, lane = t & 63, fr = lane & 15, g = lane >> 4;
    int rowbase = b * N_ + c * CHK_;

    {
        int r = t >> 2, q4 = t & 3;
        float4 qv = *(const float4*)&qp[(size_t)(rowbase + r) * 256 + h * 16 + q4 * 4];
        float4 kv = *(const float4*)&kp[(size_t)(rowbase + r) * 256 + h * 16 + q4 * 4];
        u16x4 hh, ll;
        splitf4(qv, hh, ll);
        *(u16x4*)&QH[r * 40 + q4 * 4] = hh;
        *(u16x4*)&QL[r * 40 + q4 * 4] = ll;
        splitf4(kv, hh, ll);
        *(u16x4*)&KH[r * 40 + q4 * 4] = hh;
        *(u16x4*)&KL[r * 40 + q4 * 4] = ll;
        u16x4 z4 = (u16x4){0, 0, 0, 0};
        *(u16x4*)&QH[r * 40 + 16 + q4 * 4] = z4;
        *(u16x4*)&QL[r * 40 + 16 + q4 * 4] = z4;
        *(u16x4*)&KH[r * 40 + 16 + q4 * 4] = z4;
        *(u16x4*)&KL[r * 40 + 16 + q4 * 4] = z4;
        qs[r * 20 + q4 * 4 + 0] = qv.x;
        qs[r * 20 + q4 * 4 + 1] = qv.y;
        qs[r * 20 + q4 * 4 + 2] = qv.z;
        qs[r * 20 + q4 * 4 + 3] = qv.w;
    }
    __syncthreads();

    {
        s8v qh = *(const s8v*)&QH[(16 * w + fr) * 40 + g * 8];
        s8v ql = *(const s8v*)&QL[(16 * w + fr) * 40 + g * 8];
        f4v sacc[4];
        #pragma unroll
        for (int jt = 0; jt < 4; ++jt) sacc[jt] = (f4v){0.f, 0.f, 0.f, 0.f};
        #pragma unroll
        for (int jt = 0; jt < 4; ++jt) {
            s8v kh = *(const s8v*)&KH[(jt * 16 + fr) * 40 + g * 8];
            s8v kl = *(const s8v*)&KL[(jt * 16 + fr) * 40 + g * 8];
            sacc[jt] = MFMA_(qh, kh, sacc[jt], 0, 0, 0);
            sacc[jt] = MFMA_(qh, kl, sacc[jt], 0, 0, 0);
            sacc[jt] = MFMA_(ql, kh, sacc[jt], 0, 0, 0);
        }
        #pragma unroll
        for (int jt = 0; jt < 4; ++jt)
            #pragma unroll
            for (int r4 = 0; r4 < 4; ++r4) {
                int row = 16 * w + g * 4 + r4, col = jt * 16 + fr;
                float s = sacc[jt][r4];
                float a = (row >= col) ? (fmaf(s, 0.25f, 1.0f) + s * s * 0.03125f) : 0.f;
                unsigned short hh, ll; split1(a, hh, ll);
                AH[row * 72 + col] = hh;
                AL[row * 72 + col] = ll;
            }
    }
    __syncthreads();

    for (int i = t; i < 80 * 64; i += 256) {
        int j = i >> 6, m = i & 63;
        float val;
        if (j < 64)       val = v[((size_t)bh * N_ + c * CHK_ + m) * HD_ + j];
        else if (j == 64) val = 1.0f;
        else              val = 0.0f;
        unsigned short hh, ll; split1(val, hh, ll);
        VTH[j * 72 + m] = hh;
        VTL[j * 72 + m] = ll;
    }
    __syncthreads();

    f4v acc[5];
    #pragma unroll
    for (int jt = 0; jt < 5; ++jt) acc[jt] = (f4v){0.f, 0.f, 0.f, 0.f};
    #pragma unroll
    for (int ks2 = 0; ks2 < 2; ++ks2) {
        s8v ah = *(const s8v*)&AH[(16 * w + fr) * 72 + ks2 * 32 + g * 8];
        s8v al = *(const s8v*)&AL[(16 * w + fr) * 72 + ks2 * 32 + g * 8];
        #pragma unroll
        for (int jt = 0; jt < 5; ++jt) {
            s8v bh_ = *(const s8v*)&VTH[(jt * 16 + fr) * 72 + ks2 * 32 + g * 8];
            s8v bl_ = *(const s8v*)&VTL[(jt * 16 + fr) * 72 + ks2 * 32 + g * 8];
            acc[jt] = MFMA_(ah, bh_, acc[jt], 0, 0, 0);
            acc[jt] = MFMA_(ah, bl_, acc[jt], 0, 0, 0);
            acc[jt] = MFMA_(al, bh_, acc[jt], 0, 0, 0);
        }
    }
    __syncthreads();

    const ushort_t* Sth = Spre + ((size_t)bh * NC_ + c) * 2 * SSZ_;
    const ushort_t* Stl = Sth + SSZ_;
    for (int p = 0; p < 4; ++p)
        y2_slice<64>(p * 64, Sth, Stl, qs, QF1, STH, STL, acc, w, fr, g, t);
    y2_slice<32>(256, Sth, Stl, qs, QF1, STH, STL, acc, w, fr, g, t);

    if (fr == 0) {
        #pragma unroll
        for (int r4 = 0; r4 < 4; ++r4)
            den_s[16 * w + g * 4 + r4] = acc[4][r4];
    }
    __syncthreads();
    #pragma unroll
    for (int r4 = 0; r4 < 4; ++r4) {
        float z = 1.0f / (den_s[16 * w + g * 4 + r4] + EPS_);
        int row = rowbase + 16 * w + g * 4 + r4;
        #pragma unroll
        for (int jt = 0; jt < 4; ++jt) {
            float val = acc[jt][r4] * z;
            unsigned short hh, ll; splitf16(val, hh, ll);
            size_t idx = (size_t)row * 1024 + h * 64 + jt * 16 + fr;
            atnh[idx] = hh;
            atnl[idx] = ll;
        }
    }
}

// ---------------------------------------------------------------------------
extern "C" void kernel_launch(void* const* d_in, const int* in_sizes, int n_in,
                              void* d_out, int out_size, void* d_ws, size_t ws_size,
                              hipStream_t stream)
{
    const float* x    = (const float*)d_in[0];
    const float* Wq   = (const float*)d_in[1];
    const float* Wk   = (const float*)d_in[2];
    const float* Wv   = (const float*)d_in[3];
    const float* Wke  = (const float*)d_in[4];
    const float* Wve  = (const float*)d_in[5];
    const float* Wout = (const float*)d_in[6];
    float* out = (float*)d_out;
    float* ws  = (float*)d_ws;

    // f32 region
    float* tmpq  = ws;                                 // 1,048,576
    float* tmpk  = tmpq  + (size_t)1048576;            // 1,048,576
    float* tmpke = tmpk  + (size_t)1048576;            //   262,144
    float* v     = tmpke + (size_t)262144;             // 4,194,304
    float* ve    = v     + (size_t)4194304;            // 1,048,576
    float* Sloc  = ve    + (size_t)1048576;            // 19,169,280 (f16-pair states)
    float* Senc  = Sloc  + (size_t)19169280;           //   599,040  (f16-pair states)
    // f16 region
    ushort_t* xh = (ushort_t*)(Senc + 599040);         // 4,194,304 shorts
    ushort_t* xl = xh + (size_t)4194304;               // 4,194,304 shorts
    ushort_t* wo = xl + (size_t)4194304;               // 1,048,576 shorts (own region)
    // overlays:
    ushort_t* w1 = (ushort_t*)Sloc;                    // dead before state_all
    ushort_t* w2 = w1 + (size_t)1572864;
    ushort_t* atnh = xh;                               // xh/xl dead after proj2
    ushort_t* atnl = xl;
    ushort_t* Sloc_us = (ushort_t*)Sloc;
    ushort_t* Senc_us = (ushort_t*)Senc;

    dim3 blk(256);

    split_all<<<7936, blk, 0, stream>>>(x, Wq, Wk, Wv, Wke, Wve, Wout,
                                        xh, xl, w1, w2, wo);
    proj2<<<464, blk, 0, stream>>>(xh, xl, w1, w2, tmpq, tmpk, v, tmpke, ve);
    state_all<<<160 + 32 * NC_, blk, 0, stream>>>(tmpke, ve, Senc_us, tmpk, v, Sloc_us);
    prefix_scan<<<585, blk, 0, stream>>>(Sloc_us, Senc_us);
    attn_chunk<<<32 * NC_, blk, 0, stream>>>(tmpq, tmpk, v, Sloc_us, atnh, atnl);
    out_gemm<<<256, blk, 0, stream>>>(atnh, atnl, wo, out);
}

// Round 10
// 142.399 us; speedup vs baseline: 6.4399x; 1.2649x over previous
//
#include <hip/hip_runtime.h>

// Problem constants
#define B_    2
#define N_    2048
#define H_    16
#define HD_   64
#define ENC_  512
#define FP_   288
#define CHK_  64
#define NC_   32
#define SSZ_  18720                  // state elems: [65 j][288 f]; SINGLE f16 plane
#define C2C_  0.17677669529663687f   // 1/(4*sqrt(2))
#define EPS_  1e-12f

using s8v   = __attribute__((ext_vector_type(8))) short;     // 8x16-bit carrier
using h8v   = __attribute__((ext_vector_type(8))) _Float16;  // 8 f16 (4 VGPRs)
using f4v   = __attribute__((ext_vector_type(4))) float;
using u16x4 = __attribute__((ext_vector_type(4))) unsigned short;
typedef unsigned short ushort_t;

// ---- bf16 helpers (attn QK^T only)
__device__ __forceinline__ unsigned short bfh(float x) {
    unsigned int u = __float_as_uint(x);
    return (unsigned short)((u + 0x7FFF + ((u >> 16) & 1)) >> 16);
}
__device__ __forceinline__ float bff(unsigned short h) {
    return __uint_as_float(((unsigned int)h) << 16);
}
__device__ __forceinline__ void splitf4(float4 v, u16x4& h, u16x4& l) {
    unsigned short h0 = bfh(v.x), h1 = bfh(v.y), h2 = bfh(v.z), h3 = bfh(v.w);
    h = (u16x4){h0, h1, h2, h3};
    l = (u16x4){bfh(v.x - bff(h0)), bfh(v.y - bff(h1)),
                bfh(v.z - bff(h2)), bfh(v.w - bff(h3))};
}

// ---- f16 helpers
__device__ __forceinline__ unsigned short f16q(float x) {
    _Float16 h = (_Float16)x;
    return __builtin_bit_cast(unsigned short, h);
}
__device__ __forceinline__ float f16f(unsigned short u) {
    return (float)__builtin_bit_cast(_Float16, u);
}
__device__ __forceinline__ void splitf16(float x, unsigned short& h, unsigned short& l) {
    _Float16 hh = (_Float16)x;
    h = __builtin_bit_cast(unsigned short, hh);
    l = f16q(x - (float)hh);
}
__device__ __forceinline__ void splitf16_4(float4 v, u16x4& h, u16x4& l) {
    unsigned short h0, l0, h1, l1, h2, l2, h3, l3;
    splitf16(v.x, h0, l0); splitf16(v.y, h1, l1);
    splitf16(v.z, h2, l2); splitf16(v.w, h3, l3);
    h = (u16x4){h0, h1, h2, h3};
    l = (u16x4){l0, l1, l2, l3};
}
__device__ __forceinline__ u16x4 f16q4(float4 v) {
    return (u16x4){f16q(v.x), f16q(v.y), f16q(v.z), f16q(v.w)};
}

#define MFMA_  __builtin_amdgcn_mfma_f32_16x16x32_bf16
#define MFMAH_ __builtin_amdgcn_mfma_f32_16x16x32_f16

// async global->LDS, 16B per lane
__device__ __forceinline__ void gld16(const void* g, void* l) {
    __builtin_amdgcn_global_load_lds(
        (const __attribute__((address_space(1))) unsigned int*)g,
        (__attribute__((address_space(3))) unsigned int*)l, 16, 0, 0);
}

// bijective XCD swizzle (m204)
__device__ __forceinline__ int xcd_swz(int b, int nwg) {
    int q = nwg >> 3, r = nwg & 7;
    int xcd = b & 7, loc = b >> 3;
    return (xcd < r ? xcd * (q + 1) : r * (q + 1) + (xcd - r) * q) + loc;
}

// ---------------------------------------------------------------------------
// split_all: x -> f16 pair ; [Wq;Wk;Wv] -> w1 ; [Wke;Wve] -> w2 ; Wout -> wo.
// ---------------------------------------------------------------------------
#define X_F4   1048576
#define W1_F4  393216
#define W2_F4  327680
#define WO_F4  262144

__global__ __launch_bounds__(256) void split_all(
    const float* __restrict__ x,
    const float* __restrict__ Wq, const float* __restrict__ Wk,
    const float* __restrict__ Wv, const float* __restrict__ Wke,
    const float* __restrict__ Wve, const float* __restrict__ Wout,
    ushort_t* __restrict__ xh, ushort_t* __restrict__ xl,
    ushort_t* __restrict__ w1, ushort_t* __restrict__ w2,
    ushort_t* __restrict__ wo)
{
    int gid = blockIdx.x * 256 + threadIdx.x;
    if (gid < X_F4) {
        float4 vv = ((const float4*)x)[gid];
        u16x4 h, l; splitf16_4(vv, h, l);
        ((u16x4*)xh)[gid] = h; ((u16x4*)xl)[gid] = l;
    } else if (gid < X_F4 + W1_F4) {
        int i = gid - X_F4;
        int row = i >> 8, c4 = i & 255;
        const float* s = (row < 256) ? Wq + (size_t)row * 1024
                       : (row < 512) ? Wk + (size_t)(row - 256) * 1024
                                     : Wv + (size_t)(row - 512) * 1024;
        ((u16x4*)w1)[i] = f16q4(*(const float4*)(s + c4 * 4));
    } else if (gid < X_F4 + W1_F4 + W2_F4) {
        int i = gid - X_F4 - W1_F4;
        int row = i >> 8, c4 = i & 255;
        const float* s = (row < 256) ? Wke + (size_t)row * 1024
                                     : Wve + (size_t)(row - 256) * 1024;
        ((u16x4*)w2)[i] = f16q4(*(const float4*)(s + c4 * 4));
    } else {
        int i = gid - X_F4 - W1_F4 - W2_F4;
        ((u16x4*)wo)[i] = f16q4(((const float4*)Wout)[i]);
    }
}

// ---------------------------------------------------------------------------
// f16 2-pass GEMM body with double-buffered global_load_lds staging.
// ---------------------------------------------------------------------------
template <int SHIFT>
__device__ __forceinline__ void bg128(
    const ushort_t* __restrict__ Ah, const ushort_t* __restrict__ Al,
    const ushort_t* __restrict__ Wh,
    int bx, int by, int rowjump,
    ushort_t* SM, f4v (&acc)[4][4])
{
    int t = threadIdx.x;
    int w = t >> 6, lane = t & 63;
    int row0 = by * 128, col0 = bx * 128;
    int wrow = (w >> 1) * 64, wcol = (w & 1) * 64;
    int fr = lane & 15, g = lane >> 4;

    int c0 = lane, c1 = 64 + lane;
    int r0 = w * 32 + (c0 >> 2), k80 = (c0 & 3) * 8;
    int r1 = w * 32 + (c1 >> 2), k81 = (c1 & 3) * 8;
    int gr0 = row0 + r0, gr1 = row0 + r1;
    size_t a0 = (size_t)(gr0 >> SHIFT) * rowjump + (gr0 & ((1 << SHIFT) - 1));
    size_t a1 = (size_t)(gr1 >> SHIFT) * rowjump + (gr1 & ((1 << SHIFT) - 1));
    const ushort_t* pA0h = Ah + a0 * 1024 + k80;
    const ushort_t* pA1h = Ah + a1 * 1024 + k81;
    const ushort_t* pA0l = Al + a0 * 1024 + k80;
    const ushort_t* pA1l = Al + a1 * 1024 + k81;
    const ushort_t* pW0  = Wh + (size_t)(col0 + r0) * 1024 + k80;
    const ushort_t* pW1  = Wh + (size_t)(col0 + r1) * 1024 + k81;
    int woff = w * 1024;

    #pragma unroll
    for (int mt = 0; mt < 4; ++mt)
        #pragma unroll
        for (int nt = 0; nt < 4; ++nt) acc[mt][nt] = (f4v){0.f, 0.f, 0.f, 0.f};

    auto STAGE = [&](int buf, int k0) {
        ushort_t* Bp = SM + buf * 12288;
        gld16(pA0h + k0, Bp + woff);
        gld16(pA1h + k0, Bp + woff + 512);
        gld16(pA0l + k0, Bp + 4096 + woff);
        gld16(pA1l + k0, Bp + 4096 + woff + 512);
        gld16(pW0  + k0, Bp + 8192 + woff);
        gld16(pW1  + k0, Bp + 8192 + woff + 512);
    };

    STAGE(0, 0);
    __syncthreads();
    int cur = 0;
    for (int k0 = 0; k0 < 1024; k0 += 32) {
        if (k0 + 32 < 1024) STAGE(cur ^ 1, k0 + 32);
        ushort_t* Bp = SM + cur * 12288;
        h8v a_h[4], a_l[4], b_[4];
        #pragma unroll
        for (int mt = 0; mt < 4; ++mt) {
            a_h[mt] = *(const h8v*)&Bp[(wrow + mt * 16 + fr) * 32 + g * 8];
            a_l[mt] = *(const h8v*)&Bp[4096 + (wrow + mt * 16 + fr) * 32 + g * 8];
        }
        #pragma unroll
        for (int nt = 0; nt < 4; ++nt)
            b_[nt] = *(const h8v*)&Bp[8192 + (wcol + nt * 16 + fr) * 32 + g * 8];
        #pragma unroll
        for (int mt = 0; mt < 4; ++mt)
            #pragma unroll
            for (int nt = 0; nt < 4; ++nt) {
                acc[mt][nt] = MFMAH_(a_h[mt], b_[nt], acc[mt][nt], 0, 0, 0);
                acc[mt][nt] = MFMAH_(a_l[mt], b_[nt], acc[mt][nt], 0, 0, 0);
            }
        __syncthreads();
        cur ^= 1;
    }
}

// ---------------------------------------------------------------------------
// proj2: main (384 blocks) + enc (80 blocks).
// ---------------------------------------------------------------------------
__global__ __launch_bounds__(256) void proj2(
    const ushort_t* __restrict__ xh, const ushort_t* __restrict__ xl,
    const ushort_t* __restrict__ w1, const ushort_t* __restrict__ w2,
    float* __restrict__ tmpq, float* __restrict__ tmpk, float* __restrict__ v,
    float* __restrict__ tmpke, float* __restrict__ ve)
{
    __shared__ ushort_t SM[24576];
    f4v acc[4][4];
    int blk = xcd_swz(blockIdx.x, 464);
    int t = threadIdx.x, w = t >> 6, lane = t & 63;
    int wrow = (w >> 1) * 64, wcol = (w & 1) * 64;
    int fr = lane & 15, g = lane >> 4;

    if (blk < 384) {
        int bx = blk % 12, by = blk / 12;
        bg128<12>(xh, xl, w1, bx, by, 0, SM, acc);
        int row0 = by * 128, col0 = bx * 128;
        #pragma unroll
        for (int mt = 0; mt < 4; ++mt)
            #pragma unroll
            for (int nt = 0; nt < 4; ++nt)
                #pragma unroll
                for (int r4 = 0; r4 < 4; ++r4) {
                    int r  = row0 + wrow + mt * 16 + g * 4 + r4;
                    int cc = col0 + wcol + nt * 16 + fr;
                    float val = acc[mt][nt][r4];
                    if (cc < 256)      tmpq[(size_t)r * 256 + cc] = val;
                    else if (cc < 512) tmpk[(size_t)r * 256 + (cc - 256)] = val;
                    else {
                        int c2 = cc - 512, hh = c2 >> 6, jj = c2 & 63;
                        int bb = r >> 11, n = r & 2047;
                        v[(((size_t)(bb * 16 + hh)) * 2048 + n) * 64 + jj] = val;
                    }
                }
    } else {
        int r2 = blk - 384;
        int bx = r2 % 10, by = r2 / 10;
        bg128<9>(xh, xl, w2, bx, by, 2048, SM, acc);
        int row0 = by * 128, col0 = bx * 128;
        #pragma unroll
        for (int mt = 0; mt < 4; ++mt)
            #pragma unroll
            for (int nt = 0; nt < 4; ++nt)
                #pragma unroll
                for (int r4 = 0; r4 < 4; ++r4) {
                    int r  = row0 + wrow + mt * 16 + g * 4 + r4;
                    int cc = col0 + wcol + nt * 16 + fr;
                    float val = acc[mt][nt][r4];
                    if (cc < 256) tmpke[(size_t)r * 256 + cc] = val;
                    else {
                        int c2 = cc - 256, hh = c2 >> 6, jj = c2 & 63;
                        int bb = r >> 9, n = r & 511;
                        ve[(((size_t)(bb * 16 + hh)) * 512 + n) * 64 + jj] = val;
                    }
                }
    }
}

// out_gemm: attn(f16 pair) @ Wout(f16)^T -> f32 d_out.
__global__ __launch_bounds__(256) void out_gemm(
    const ushort_t* __restrict__ Ah, const ushort_t* __restrict__ Al,
    const ushort_t* __restrict__ Wh, float* __restrict__ out)
{
    __shared__ ushort_t SM[24576];
    f4v acc[4][4];
    int blk = xcd_swz(blockIdx.x, 256);
    int bx = blk & 7, by = blk >> 3;
    bg128<12>(Ah, Al, Wh, bx, by, 0, SM, acc);
    int t = threadIdx.x, w = t >> 6, lane = t & 63;
    int wrow = (w >> 1) * 64, wcol = (w & 1) * 64;
    int fr = lane & 15, g = lane >> 4;
    int row0 = by * 128, col0 = bx * 128;
    #pragma unroll
    for (int mt = 0; mt < 4; ++mt)
        #pragma unroll
        for (int nt = 0; nt < 4; ++nt)
            #pragma unroll
            for (int r4 = 0; r4 < 4; ++r4) {
                int r  = row0 + wrow + mt * 16 + g * 4 + r4;
                int cc = col0 + wcol + nt * 16 + fr;
                out[(size_t)r * 1024 + cc] = acc[mt][nt][r4];
            }
}

// ---------------------------------------------------------------------------
// MFMA state kernel (V f16-pair x feat single f16, 2-pass); SINGLE f16 store.
// ---------------------------------------------------------------------------
__device__ __forceinline__ void st_stage(
    const float* __restrict__ Kp, const float* __restrict__ V,
    size_t krow0, size_t vrow0, int h, int t,
    float* ksT, ushort_t* VTH, ushort_t* VTL)
{
    {
        int r = t >> 2, q4 = t & 3;
        float4 kv = *(const float4*)&Kp[(krow0 + r) * 256 + h * 16 + q4 * 4];
        ksT[(q4 * 4 + 0) * 68 + r] = kv.x;
        ksT[(q4 * 4 + 1) * 68 + r] = kv.y;
        ksT[(q4 * 4 + 2) * 68 + r] = kv.z;
        ksT[(q4 * 4 + 3) * 68 + r] = kv.w;
    }
    if (t < 64) ksT[16 * 68 + t] = 1.0f;
    {
        int r = t & 63, jg = t >> 6;
        #pragma unroll
        for (int cc = 0; cc < 4; ++cc) {
            float4 vv = *(const float4*)&V[(vrow0 + r) * HD_ + jg * 16 + cc * 4];
            float vals[4] = {vv.x, vv.y, vv.z, vv.w};
            #pragma unroll
            for (int e = 0; e < 4; ++e) {
                int j = jg * 16 + cc * 4 + e;
                unsigned short hh, ll; splitf16(vals[e], hh, ll);
                VTH[j * 72 + r] = hh;
                VTL[j * 72 + r] = ll;
            }
        }
    }
    if (t < 64) { VTH[64 * 72 + t] = 0x3C00; VTL[64 * 72 + t] = 0; }
}

__device__ __forceinline__ void st_ftile(
    const float* ksT, int ft, int fr, int g,
    const h8v (&AHf)[2][5], const h8v (&ALf)[2][5], f4v (&acc)[5])
{
    int f = ft * 16 + fr;
    int fi, fj; float scale;
    if (f == 0)       { fi = 16; fj = 16; scale = 1.0f; }
    else if (f < 17)  { fi = f - 1; fj = 16; scale = 0.5f; }
    else if (f < 273) { fi = (f - 17) >> 4; fj = (f - 17) & 15; scale = C2C_; }
    else              { fi = 16; fj = 16; scale = 0.0f; }
    #pragma unroll
    for (int ks2 = 0; ks2 < 2; ++ks2) {
        const float* pa = ksT + fi * 68 + ks2 * 32 + g * 8;
        const float* pb = ksT + fj * 68 + ks2 * 32 + g * 8;
        h8v bv;
        #pragma unroll
        for (int e = 0; e < 8; ++e) bv[e] = (_Float16)(pa[e] * pb[e] * scale);
        #pragma unroll
        for (int jt = 0; jt < 5; ++jt) {
            acc[jt] = MFMAH_(AHf[ks2][jt], bv, acc[jt], 0, 0, 0);
            acc[jt] = MFMAH_(ALf[ks2][jt], bv, acc[jt], 0, 0, 0);
        }
    }
}

__global__ __launch_bounds__(256) void state_all(
    const float* __restrict__ Kpe, const float* __restrict__ Ve, ushort_t* __restrict__ Se,
    const float* __restrict__ Kpc, const float* __restrict__ Vc, ushort_t* __restrict__ Sc)
{
    __shared__ float ksT[17 * 68];
    __shared__ ushort_t VTH[80 * 72], VTL[80 * 72];
    int blk = blockIdx.x, t = threadIdx.x;
    int w = t >> 6, lane = t & 63, fr = lane & 15, g = lane >> 4;

    for (int i = t; i < 15 * 72; i += 256) { VTH[65 * 72 + i] = 0; VTL[65 * 72 + i] = 0; }

    if (blk >= 160) {
        int b2 = blk - 160;
        int c = b2 & 31, bh = b2 >> 5;
        int b = bh >> 4, h = bh & 15;
        ushort_t* Sg = Sc + ((size_t)bh * NC_ + c) * SSZ_;
        st_stage(Kpc, Vc, (size_t)b * 2048 + c * 64, (size_t)bh * 2048 + c * 64,
                 h, t, ksT, VTH, VTL);
        __syncthreads();
        h8v AHf[2][5], ALf[2][5];
        #pragma unroll
        for (int ks2 = 0; ks2 < 2; ++ks2)
            #pragma unroll
            for (int jt = 0; jt < 5; ++jt) {
                AHf[ks2][jt] = *(const h8v*)&VTH[(jt * 16 + fr) * 72 + ks2 * 32 + g * 8];
                ALf[ks2][jt] = *(const h8v*)&VTL[(jt * 16 + fr) * 72 + ks2 * 32 + g * 8];
            }
        for (int ft = w; ft < 18; ft += 4) {
            f4v acc[5];
            #pragma unroll
            for (int jt = 0; jt < 5; ++jt) acc[jt] = (f4v){0.f, 0.f, 0.f, 0.f};
            st_ftile(ksT, ft, fr, g, AHf, ALf, acc);
            #pragma unroll
            for (int jt = 0; jt < 5; ++jt)
                #pragma unroll
                for (int r4 = 0; r4 < 4; ++r4) {
                    int j = jt * 16 + g * 4 + r4;
                    if (j < 65) Sg[(size_t)j * FP_ + ft * 16 + fr] = f16q(acc[jt][r4]);
                }
        }
    } else {
        int bh = blk / 5, fg = blk % 5;
        int b = bh >> 4, h = bh & 15;
        int ft = fg * 4 + w;
        ushort_t* Sg = Se + (size_t)bh * SSZ_;
        f4v acc[5];
        #pragma unroll
        for (int jt = 0; jt < 5; ++jt) acc[jt] = (f4v){0.f, 0.f, 0.f, 0.f};
        for (int m0 = 0; m0 < 512; m0 += 64) {
            if (m0) __syncthreads();
            st_stage(Kpe, Ve, (size_t)b * 512 + m0, (size_t)bh * 512 + m0,
                     h, t, ksT, VTH, VTL);
            __syncthreads();
            if (ft < 18) {
                h8v AHf[2][5], ALf[2][5];
                #pragma unroll
                for (int ks2 = 0; ks2 < 2; ++ks2)
                    #pragma unroll
                    for (int jt = 0; jt < 5; ++jt) {
                        AHf[ks2][jt] = *(const h8v*)&VTH[(jt * 16 + fr) * 72 + ks2 * 32 + g * 8];
                        ALf[ks2][jt] = *(const h8v*)&VTL[(jt * 16 + fr) * 72 + ks2 * 32 + g * 8];
                    }
                st_ftile(ksT, ft, fr, g, AHf, ALf, acc);
            }
        }
        if (ft < 18) {
            #pragma unroll
            for (int jt = 0; jt < 5; ++jt)
                #pragma unroll
                for (int r4 = 0; r4 < 4; ++r4) {
                    int j = jt * 16 + g * 4 + r4;
                    if (j < 65) Sg[(size_t)j * FP_ + ft * 16 + fr] = f16q(acc[jt][r4]);
                }
        }
    }
}

// ---------------------------------------------------------------------------
// Exclusive prefix over single-f16 states, in place (f32 accumulate in regs).
// ---------------------------------------------------------------------------
__global__ __launch_bounds__(256) void prefix_scan(
    ushort_t* __restrict__ Sloc, const ushort_t* __restrict__ Senc)
{
    const int Q = SSZ_ / 8;    // 2340 oct-groups (16B)
    int gid = blockIdx.x * 256 + threadIdx.x;
    if (gid >= 32 * Q) return;
    int bh = gid / Q, e = gid - bh * Q;
    s8v ev = *(const s8v*)(Senc + (size_t)bh * SSZ_ + e * 8);
    float run[8];
    #pragma unroll
    for (int u = 0; u < 8; ++u) run[u] = f16f((ushort_t)ev[u]);
    ushort_t* Sb = Sloc + (size_t)bh * NC_ * SSZ_ + e * 8;
    #pragma unroll 1
    for (int cb = 0; cb < 8; ++cb) {
        s8v t0 = *(const s8v*)(Sb + (size_t)(cb * 4 + 0) * SSZ_);
        s8v t1 = *(const s8v*)(Sb + (size_t)(cb * 4 + 1) * SSZ_);
        s8v t2 = *(const s8v*)(Sb + (size_t)(cb * 4 + 2) * SSZ_);
        s8v t3 = *(const s8v*)(Sb + (size_t)(cb * 4 + 3) * SSZ_);
        s8v o0, o1, o2, o3;
        #pragma unroll
        for (int u = 0; u < 8; ++u) { o0[u] = (short)f16q(run[u]); run[u] += f16f((ushort_t)t0[u]); }
        #pragma unroll
        for (int u = 0; u < 8; ++u) { o1[u] = (short)f16q(run[u]); run[u] += f16f((ushort_t)t1[u]); }
        #pragma unroll
        for (int u = 0; u < 8; ++u) { o2[u] = (short)f16q(run[u]); run[u] += f16f((ushort_t)t2[u]); }
        #pragma unroll
        for (int u = 0; u < 8; ++u) { o3[u] = (short)f16q(run[u]); run[u] += f16f((ushort_t)t3[u]); }
        *(s8v*)(Sb + (size_t)(cb * 4 + 0) * SSZ_) = o0;
        *(s8v*)(Sb + (size_t)(cb * 4 + 1) * SSZ_) = o1;
        *(s8v*)(Sb + (size_t)(cb * 4 + 2) * SSZ_) = o2;
        *(s8v*)(Sb + (size_t)(cb * 4 + 3) * SSZ_) = o3;
    }
}

// ---------------------------------------------------------------------------
// attn_chunk: QK^T bf16 3-pass; Y1 = A(f16 pair) @ V(f16 single);
// Y2 = QF(f16) @ S(f16 single) with register-prefetched state slices (T14).
// ---------------------------------------------------------------------------
template<int FW>
__device__ __forceinline__ void y2_issue(
    const ushort_t* __restrict__ Sth, int f0, int t, s8v& r0, s8v& r1, s8v& r2)
{
    constexpr int NS = FW / 8;
    constexpr int TOT = 65 * NS;
    int s1 = t + 256, s2 = t + 512;
    r0 = *(const s8v*)(Sth + (size_t)(t / NS) * FP_ + f0 + (t % NS) * 8);
    if (s1 < TOT) r1 = *(const s8v*)(Sth + (size_t)(s1 / NS) * FP_ + f0 + (s1 % NS) * 8);
    if (FW == 64 && s2 < TOT) r2 = *(const s8v*)(Sth + (size_t)(s2 / NS) * FP_ + f0 + (s2 % NS) * 8);
}

template<int FW>
__device__ __forceinline__ void y2_write(
    ushort_t* STH, int t, const s8v& r0, const s8v& r1, const s8v& r2)
{
    constexpr int NS = FW / 8;
    constexpr int TOT = 65 * NS;
    int s1 = t + 256, s2 = t + 512;
    *(s8v*)&STH[(t / NS) * 72 + (t % NS) * 8] = r0;
    if (s1 < TOT) *(s8v*)&STH[(s1 / NS) * 72 + (s1 % NS) * 8] = r1;
    if (FW == 64 && s2 < TOT) *(s8v*)&STH[(s2 / NS) * 72 + (s2 % NS) * 8] = r2;
}

template<int FW>
__device__ __forceinline__ void qf_gen(int f0, const float* qs, ushort_t* QF1, int t)
{
    for (int i = t; i < 64 * FW; i += 256) {
        int row = i / FW, cc = i % FW;
        int f = f0 + cc;
        float qv;
        if (f == 0)       qv = 1.0f;
        else if (f < 17)  qv = qs[row * 20 + (f - 1)] * 0.5f;
        else if (f < 273) qv = qs[row * 20 + ((f - 17) >> 4)] * qs[row * 20 + ((f - 17) & 15)] * C2C_;
        else              qv = 0.0f;
        QF1[row * 72 + cc] = f16q(qv);
    }
}

template<int FW>
__device__ __forceinline__ void y2_mfma(
    const ushort_t* QF1, const ushort_t* STH,
    f4v (&acc)[5], int w, int fr, int g)
{
    #pragma unroll
    for (int ks2 = 0; ks2 < FW / 32; ++ks2) {
        h8v a = *(const h8v*)&QF1[(16 * w + fr) * 72 + ks2 * 32 + g * 8];
        #pragma unroll
        for (int jt = 0; jt < 5; ++jt) {
            h8v b = *(const h8v*)&STH[(jt * 16 + fr) * 72 + ks2 * 32 + g * 8];
            acc[jt] = MFMAH_(a, b, acc[jt], 0, 0, 0);
        }
    }
}

__global__ __launch_bounds__(256) void attn_chunk(
    const float* __restrict__ qp, const float* __restrict__ kp,
    const float* __restrict__ v, const ushort_t* __restrict__ Spre,
    ushort_t* __restrict__ atnh, ushort_t* __restrict__ atnl)
{
    __shared__ ushort_t U[19456];
    __shared__ float qs[64 * 20];
    __shared__ float den_s[64];
    ushort_t* AH  = U;            // [64][72]  f16 pair (A)
    ushort_t* AL  = U + 4608;
    ushort_t* QH  = U + 9216;     // [64][40]  bf16
    ushort_t* QL  = U + 11776;
    ushort_t* KH  = U + 14336;
    ushort_t* KL  = U + 16896;    // ends 19456
    ushort_t* VTH = U + 9216;     // [80][72]  f16 single (after phase A)
    ushort_t* QF1 = U;            // [64][72]  f16 (Y2)
    ushort_t* STH = U + 9216;     // [80][72]  f16 (Y2; rows 65-79 stay 0)

    int bid = blockIdx.x;
    int bh = bid >> 5, c = bid & 31;
    int b = bh >> 4, h = bh & 15;
    int t = threadIdx.x;
    int w = t >> 6, lane = t & 63, fr = lane & 15, g = lane >> 4;
    int rowbase = b * N_ + c * CHK_;
    const ushort_t* Sth = Spre + ((size_t)bh * NC_ + c) * SSZ_;

    // ---- issue q/k loads
    int rqk = t >> 2, q4 = t & 3;
    float4 qv = *(const float4*)&qp[(size_t)(rowbase + rqk) * 256 + h * 16 + q4 * 4];
    float4 kv = *(const float4*)&kp[(size_t)(rowbase + rqk) * 256 + h * 16 + q4 * 4];
    // ---- prefetch: state slice 0 + V tile (fly under QK^T)
    s8v rA0 = {}, rA1 = {}, rA2 = {};
    y2_issue<64>(Sth, 0, t, rA0, rA1, rA2);
    int mv = t & 63, jg0 = t >> 6;
    const float* vr = &v[((size_t)bh * N_ + c * CHK_ + mv) * HD_ + jg0 * 16];
    float4 rv0 = *(const float4*)(vr + 0);
    float4 rv1 = *(const float4*)(vr + 4);
    float4 rv2 = *(const float4*)(vr + 8);
    float4 rv3 = *(const float4*)(vr + 12);

    // ---- stage q/k (bf16 pair) + qs f32
    {
        u16x4 hh, ll;
        splitf4(qv, hh, ll);
        *(u16x4*)&QH[rqk * 40 + q4 * 4] = hh;
        *(u16x4*)&QL[rqk * 40 + q4 * 4] = ll;
        splitf4(kv, hh, ll);
        *(u16x4*)&KH[rqk * 40 + q4 * 4] = hh;
        *(u16x4*)&KL[rqk * 40 + q4 * 4] = ll;
        u16x4 z4 = (u16x4){0, 0, 0, 0};
        *(u16x4*)&QH[rqk * 40 + 16 + q4 * 4] = z4;
        *(u16x4*)&QL[rqk * 40 + 16 + q4 * 4] = z4;
        *(u16x4*)&KH[rqk * 40 + 16 + q4 * 4] = z4;
        *(u16x4*)&KL[rqk * 40 + 16 + q4 * 4] = z4;
        qs[rqk * 20 + q4 * 4 + 0] = qv.x;
        qs[rqk * 20 + q4 * 4 + 1] = qv.y;
        qs[rqk * 20 + q4 * 4 + 2] = qv.z;
        qs[rqk * 20 + q4 * 4 + 3] = qv.w;
    }
    __syncthreads();

    // ---- phase A: QK^T (bf16 3-pass), poly+tril, split to f16 pair AH/AL
    {
        s8v qh = *(const s8v*)&QH[(16 * w + fr) * 40 + g * 8];
        s8v ql = *(const s8v*)&QL[(16 * w + fr) * 40 + g * 8];
        f4v sacc[4];
        #pragma unroll
        for (int jt = 0; jt < 4; ++jt) sacc[jt] = (f4v){0.f, 0.f, 0.f, 0.f};
        #pragma unroll
        for (int jt = 0; jt < 4; ++jt) {
            s8v kh = *(const s8v*)&KH[(jt * 16 + fr) * 40 + g * 8];
            s8v kl = *(const s8v*)&KL[(jt * 16 + fr) * 40 + g * 8];
            sacc[jt] = MFMA_(qh, kh, sacc[jt], 0, 0, 0);
            sacc[jt] = MFMA_(qh, kl, sacc[jt], 0, 0, 0);
            sacc[jt] = MFMA_(ql, kh, sacc[jt], 0, 0, 0);
        }
        __syncthreads();   // QH..KL dead after this barrier (sacc in regs)
        #pragma unroll
        for (int jt = 0; jt < 4; ++jt)
            #pragma unroll
            for (int r4 = 0; r4 < 4; ++r4) {
                int row = 16 * w + g * 4 + r4, col = jt * 16 + fr;
                float s = sacc[jt][r4];
                float a = (row >= col) ? (fmaf(s, 0.25f, 1.0f) + s * s * 0.03125f) : 0.f;
                unsigned short hh, ll; splitf16(a, hh, ll);
                AH[row * 72 + col] = hh;
                AL[row * 72 + col] = ll;
            }
    }
    // ---- write V tile (single f16) from prefetched regs + ones/zero rows
    {
        float4 rr0 = rv0, rr1 = rv1, rr2 = rv2, rr3 = rv3;
        int j0 = jg0 * 16;
        VTH[(j0 +  0) * 72 + mv] = f16q(rr0.x); VTH[(j0 +  1) * 72 + mv] = f16q(rr0.y);
        VTH[(j0 +  2) * 72 + mv] = f16q(rr0.z); VTH[(j0 +  3) * 72 + mv] = f16q(rr0.w);
        VTH[(j0 +  4) * 72 + mv] = f16q(rr1.x); VTH[(j0 +  5) * 72 + mv] = f16q(rr1.y);
        VTH[(j0 +  6) * 72 + mv] = f16q(rr1.z); VTH[(j0 +  7) * 72 + mv] = f16q(rr1.w);
        VTH[(j0 +  8) * 72 + mv] = f16q(rr2.x); VTH[(j0 +  9) * 72 + mv] = f16q(rr2.y);
        VTH[(j0 + 10) * 72 + mv] = f16q(rr2.z); VTH[(j0 + 11) * 72 + mv] = f16q(rr2.w);
        VTH[(j0 + 12) * 72 + mv] = f16q(rr3.x); VTH[(j0 + 13) * 72 + mv] = f16q(rr3.y);
        VTH[(j0 + 14) * 72 + mv] = f16q(rr3.z); VTH[(j0 + 15) * 72 + mv] = f16q(rr3.w);
    }
    if (t < 64) VTH[64 * 72 + t] = 0x3C00;          // f16 1.0 (denominator row)
    for (int i = t; i < 15 * 72; i += 256) VTH[65 * 72 + i] = 0;
    __syncthreads();

    // ---- Y1: acc += A(pair) @ VT(single)
    f4v acc[5];
    #pragma unroll
    for (int jt = 0; jt < 5; ++jt) acc[jt] = (f4v){0.f, 0.f, 0.f, 0.f};
    #pragma unroll
    for (int ks2 = 0; ks2 < 2; ++ks2) {
        h8v ah = *(const h8v*)&AH[(16 * w + fr) * 72 + ks2 * 32 + g * 8];
        h8v al = *(const h8v*)&AL[(16 * w + fr) * 72 + ks2 * 32 + g * 8];
        #pragma unroll
        for (int jt = 0; jt < 5; ++jt) {
            h8v b = *(const h8v*)&VTH[(jt * 16 + fr) * 72 + ks2 * 32 + g * 8];
            acc[jt] = MFMAH_(ah, b, acc[jt], 0, 0, 0);
            acc[jt] = MFMAH_(al, b, acc[jt], 0, 0, 0);
        }
    }
    __syncthreads();

    // ---- Y2: 5 state slices, register-prefetched (slice 0 already in rA*)
    #pragma unroll
    for (int p = 0; p < 4; ++p) {
        y2_write<64>(STH, t, rA0, rA1, rA2);
        if (p < 3) y2_issue<64>(Sth, (p + 1) * 64, t, rA0, rA1, rA2);
        else       y2_issue<32>(Sth, 256,          t, rA0, rA1, rA2);
        qf_gen<64>(p * 64, qs, QF1, t);
        __syncthreads();
        y2_mfma<64>(QF1, STH, acc, w, fr, g);
        __syncthreads();
    }
    y2_write<32>(STH, t, rA0, rA1, rA2);
    qf_gen<32>(256, qs, QF1, t);
    __syncthreads();
    y2_mfma<32>(QF1, STH, acc, w, fr, g);

    // ---- epilogue: divide by denominator, store f16 pair
    if (fr == 0) {
        #pragma unroll
        for (int r4 = 0; r4 < 4; ++r4)
            den_s[16 * w + g * 4 + r4] = acc[4][r4];
    }
    __syncthreads();
    #pragma unroll
    for (int r4 = 0; r4 < 4; ++r4) {
        float z = 1.0f / (den_s[16 * w + g * 4 + r4] + EPS_);
        int row = rowbase + 16 * w + g * 4 + r4;
        #pragma unroll
        for (int jt = 0; jt < 4; ++jt) {
            float val = acc[jt][r4] * z;
            unsigned short hh, ll; splitf16(val, hh, ll);
            size_t idx = (size_t)row * 1024 + h * 64 + jt * 16 + fr;
            atnh[idx] = hh;
            atnl[idx] = ll;
        }
    }
}

// ---------------------------------------------------------------------------
extern "C" void kernel_launch(void* const* d_in, const int* in_sizes, int n_in,
                              void* d_out, int out_size, void* d_ws, size_t ws_size,
                              hipStream_t stream)
{
    const float* x    = (const float*)d_in[0];
    const float* Wq   = (const float*)d_in[1];
    const float* Wk   = (const float*)d_in[2];
    const float* Wv   = (const float*)d_in[3];
    const float* Wke  = (const float*)d_in[4];
    const float* Wve  = (const float*)d_in[5];
    const float* Wout = (const float*)d_in[6];
    float* out = (float*)d_out;
    float* ws  = (float*)d_ws;

    // f32 region
    float* tmpq  = ws;                                 // 1,048,576
    float* tmpk  = tmpq  + (size_t)1048576;            // 1,048,576
    float* tmpke = tmpk  + (size_t)1048576;            //   262,144
    float* v     = tmpke + (size_t)262144;             // 4,194,304
    float* ve    = v     + (size_t)4194304;            // 1,048,576
    // f16 region
    ushort_t* Sloc = (ushort_t*)(ve + 1048576);        // 19,169,280 shorts (single-plane states)
    ushort_t* Senc = Sloc + (size_t)19169280;          //   599,040 shorts
    ushort_t* xh   = Senc + (size_t)599040;            // 4,194,304 shorts
    ushort_t* xl   = xh   + (size_t)4194304;           // 4,194,304 shorts
    ushort_t* wo   = xl   + (size_t)4194304;           // 1,048,576 shorts
    // overlays:
    ushort_t* w1 = Sloc;                               // dead before state_all
    ushort_t* w2 = w1 + (size_t)1572864;
    ushort_t* atnh = xh;                               // xh/xl dead after proj2
    ushort_t* atnl = xl;

    dim3 blk(256);

    split_all<<<7936, blk, 0, stream>>>(x, Wq, Wk, Wv, Wke, Wve, Wout,
                                        xh, xl, w1, w2, wo);
    proj2<<<464, blk, 0, stream>>>(xh, xl, w1, w2, tmpq, tmpk, v, tmpke, ve);
    state_all<<<160 + 32 * NC_, blk, 0, stream>>>(tmpke, ve, Senc, tmpk, v, Sloc);
    prefix_scan<<<293, blk, 0, stream>>>(Sloc, Senc);
    attn_chunk<<<32 * NC_, blk, 0, stream>>>(tmpq, tmpk, v, Sloc, atnh, atnl);
    out_gemm<<<256, blk, 0, stream>>>(atnh, atnl, wo, out);
}

// Round 11
// 120.837 us; speedup vs baseline: 7.5891x; 1.1784x over previous
//
#include <hip/hip_runtime.h>

// Problem constants
#define B_    2
#define N_    2048
#define H_    16
#define HD_   64
#define ENC_  512
#define FP_   288
#define CHK_  64
#define NC_   32
#define SSZ_  18720                  // state elems: [65 j][288 f]; SINGLE f16 plane
#define C2C_  0.17677669529663687f   // 1/(4*sqrt(2))
#define EPS_  1e-12f

using s8v   = __attribute__((ext_vector_type(8))) short;     // 8x16-bit carrier
using h8v   = __attribute__((ext_vector_type(8))) _Float16;  // 8 f16 (4 VGPRs)
using f4v   = __attribute__((ext_vector_type(4))) float;
using u16x4 = __attribute__((ext_vector_type(4))) unsigned short;
typedef unsigned short ushort_t;

// ---- bf16 helpers (attn QK^T only)
__device__ __forceinline__ unsigned short bfh(float x) {
    unsigned int u = __float_as_uint(x);
    return (unsigned short)((u + 0x7FFF + ((u >> 16) & 1)) >> 16);
}
__device__ __forceinline__ float bff(unsigned short h) {
    return __uint_as_float(((unsigned int)h) << 16);
}
__device__ __forceinline__ void splitf4(float4 v, u16x4& h, u16x4& l) {
    unsigned short h0 = bfh(v.x), h1 = bfh(v.y), h2 = bfh(v.z), h3 = bfh(v.w);
    h = (u16x4){h0, h1, h2, h3};
    l = (u16x4){bfh(v.x - bff(h0)), bfh(v.y - bff(h1)),
                bfh(v.z - bff(h2)), bfh(v.w - bff(h3))};
}

// ---- f16 helpers
__device__ __forceinline__ unsigned short f16q(float x) {
    _Float16 h = (_Float16)x;
    return __builtin_bit_cast(unsigned short, h);
}
__device__ __forceinline__ float f16f(unsigned short u) {
    return (float)__builtin_bit_cast(_Float16, u);
}
__device__ __forceinline__ void splitf16(float x, unsigned short& h, unsigned short& l) {
    _Float16 hh = (_Float16)x;
    h = __builtin_bit_cast(unsigned short, hh);
    l = f16q(x - (float)hh);
}
__device__ __forceinline__ void splitf16_4(float4 v, u16x4& h, u16x4& l) {
    unsigned short h0, l0, h1, l1, h2, l2, h3, l3;
    splitf16(v.x, h0, l0); splitf16(v.y, h1, l1);
    splitf16(v.z, h2, l2); splitf16(v.w, h3, l3);
    h = (u16x4){h0, h1, h2, h3};
    l = (u16x4){l0, l1, l2, l3};
}
__device__ __forceinline__ u16x4 f16q4(float4 v) {
    return (u16x4){f16q(v.x), f16q(v.y), f16q(v.z), f16q(v.w)};
}

#define MFMA_  __builtin_amdgcn_mfma_f32_16x16x32_bf16
#define MFMAH_ __builtin_amdgcn_mfma_f32_16x16x32_f16

// async global->LDS, 16B per lane
__device__ __forceinline__ void gld16(const void* g, void* l) {
    __builtin_amdgcn_global_load_lds(
        (const __attribute__((address_space(1))) unsigned int*)g,
        (__attribute__((address_space(3))) unsigned int*)l, 16, 0, 0);
}

// bijective XCD swizzle (m204)
__device__ __forceinline__ int xcd_swz(int b, int nwg) {
    int q = nwg >> 3, r = nwg & 7;
    int xcd = b & 7, loc = b >> 3;
    return (xcd < r ? xcd * (q + 1) : r * (q + 1) + (xcd - r) * q) + loc;
}

// ---------------------------------------------------------------------------
// split_all: x -> f16 pair ; [Wq;Wk;Wv] -> w1 ; [Wke;Wve] -> w2 ; Wout -> wo.
// ---------------------------------------------------------------------------
#define X_F4   1048576
#define W1_F4  393216
#define W2_F4  327680
#define WO_F4  262144

__global__ __launch_bounds__(256) void split_all(
    const float* __restrict__ x,
    const float* __restrict__ Wq, const float* __restrict__ Wk,
    const float* __restrict__ Wv, const float* __restrict__ Wke,
    const float* __restrict__ Wve, const float* __restrict__ Wout,
    ushort_t* __restrict__ xh, ushort_t* __restrict__ xl,
    ushort_t* __restrict__ w1, ushort_t* __restrict__ w2,
    ushort_t* __restrict__ wo)
{
    int gid = blockIdx.x * 256 + threadIdx.x;
    if (gid < X_F4) {
        float4 vv = ((const float4*)x)[gid];
        u16x4 h, l; splitf16_4(vv, h, l);
        ((u16x4*)xh)[gid] = h; ((u16x4*)xl)[gid] = l;
    } else if (gid < X_F4 + W1_F4) {
        int i = gid - X_F4;
        int row = i >> 8, c4 = i & 255;
        const float* s = (row < 256) ? Wq + (size_t)row * 1024
                       : (row < 512) ? Wk + (size_t)(row - 256) * 1024
                                     : Wv + (size_t)(row - 512) * 1024;
        ((u16x4*)w1)[i] = f16q4(*(const float4*)(s + c4 * 4));
    } else if (gid < X_F4 + W1_F4 + W2_F4) {
        int i = gid - X_F4 - W1_F4;
        int row = i >> 8, c4 = i & 255;
        const float* s = (row < 256) ? Wke + (size_t)row * 1024
                                     : Wve + (size_t)(row - 256) * 1024;
        ((u16x4*)w2)[i] = f16q4(*(const float4*)(s + c4 * 4));
    } else {
        int i = gid - X_F4 - W1_F4 - W2_F4;
        ((u16x4*)wo)[i] = f16q4(((const float4*)Wout)[i]);
    }
}

// ---------------------------------------------------------------------------
// f16 GEMM body, PASSES = 2 (A = hi/lo pair) or 1 (A = single plane).
// Double-buffered global_load_lds staging; BM=BN=128, BK=32, 4 waves.
// ---------------------------------------------------------------------------
template <int SHIFT, int PASSES>
__device__ __forceinline__ void bg128(
    const ushort_t* __restrict__ Ah, const ushort_t* __restrict__ Al,
    const ushort_t* __restrict__ Wh,
    int bx, int by, int rowjump,
    ushort_t* SM, f4v (&acc)[4][4])
{
    int t = threadIdx.x;
    int w = t >> 6, lane = t & 63;
    int row0 = by * 128, col0 = bx * 128;
    int wrow = (w >> 1) * 64, wcol = (w & 1) * 64;
    int fr = lane & 15, g = lane >> 4;

    int c0 = lane, c1 = 64 + lane;
    int r0 = w * 32 + (c0 >> 2), k80 = (c0 & 3) * 8;
    int r1 = w * 32 + (c1 >> 2), k81 = (c1 & 3) * 8;
    int gr0 = row0 + r0, gr1 = row0 + r1;
    size_t a0 = (size_t)(gr0 >> SHIFT) * rowjump + (gr0 & ((1 << SHIFT) - 1));
    size_t a1 = (size_t)(gr1 >> SHIFT) * rowjump + (gr1 & ((1 << SHIFT) - 1));
    const ushort_t* pA0h = Ah + a0 * 1024 + k80;
    const ushort_t* pA1h = Ah + a1 * 1024 + k81;
    const ushort_t* pA0l = Al + a0 * 1024 + k80;
    const ushort_t* pA1l = Al + a1 * 1024 + k81;
    const ushort_t* pW0  = Wh + (size_t)(col0 + r0) * 1024 + k80;
    const ushort_t* pW1  = Wh + (size_t)(col0 + r1) * 1024 + k81;
    int woff = w * 1024;

    #pragma unroll
    for (int mt = 0; mt < 4; ++mt)
        #pragma unroll
        for (int nt = 0; nt < 4; ++nt) acc[mt][nt] = (f4v){0.f, 0.f, 0.f, 0.f};

    auto STAGE = [&](int buf, int k0) {
        ushort_t* Bp = SM + buf * 12288;
        gld16(pA0h + k0, Bp + woff);
        gld16(pA1h + k0, Bp + woff + 512);
        if (PASSES == 2) {
            gld16(pA0l + k0, Bp + 4096 + woff);
            gld16(pA1l + k0, Bp + 4096 + woff + 512);
        }
        gld16(pW0  + k0, Bp + 8192 + woff);
        gld16(pW1  + k0, Bp + 8192 + woff + 512);
    };

    STAGE(0, 0);
    __syncthreads();
    int cur = 0;
    for (int k0 = 0; k0 < 1024; k0 += 32) {
        if (k0 + 32 < 1024) STAGE(cur ^ 1, k0 + 32);
        ushort_t* Bp = SM + cur * 12288;
        h8v a_h[4], a_l[4], b_[4];
        #pragma unroll
        for (int mt = 0; mt < 4; ++mt) {
            a_h[mt] = *(const h8v*)&Bp[(wrow + mt * 16 + fr) * 32 + g * 8];
            if (PASSES == 2)
                a_l[mt] = *(const h8v*)&Bp[4096 + (wrow + mt * 16 + fr) * 32 + g * 8];
        }
        #pragma unroll
        for (int nt = 0; nt < 4; ++nt)
            b_[nt] = *(const h8v*)&Bp[8192 + (wcol + nt * 16 + fr) * 32 + g * 8];
        #pragma unroll
        for (int mt = 0; mt < 4; ++mt)
            #pragma unroll
            for (int nt = 0; nt < 4; ++nt) {
                acc[mt][nt] = MFMAH_(a_h[mt], b_[nt], acc[mt][nt], 0, 0, 0);
                if (PASSES == 2)
                    acc[mt][nt] = MFMAH_(a_l[mt], b_[nt], acc[mt][nt], 0, 0, 0);
            }
        __syncthreads();
        cur ^= 1;
    }
}

// ---------------------------------------------------------------------------
// proj2: main (384 blocks) + enc (80 blocks).  q/k column-blocks use 2-pass
// (quadratic features downstream); V column-blocks use 1-pass (linear path).
// ---------------------------------------------------------------------------
__global__ __launch_bounds__(256) void proj2(
    const ushort_t* __restrict__ xh, const ushort_t* __restrict__ xl,
    const ushort_t* __restrict__ w1, const ushort_t* __restrict__ w2,
    float* __restrict__ tmpq, float* __restrict__ tmpk, float* __restrict__ v,
    float* __restrict__ tmpke, float* __restrict__ ve)
{
    __shared__ ushort_t SM[24576];
    f4v acc[4][4];
    int blk = xcd_swz(blockIdx.x, 464);
    int t = threadIdx.x, w = t >> 6, lane = t & 63;
    int wrow = (w >> 1) * 64, wcol = (w & 1) * 64;
    int fr = lane & 15, g = lane >> 4;

    if (blk < 384) {
        int bx = blk % 12, by = blk / 12;
        if (bx < 4) bg128<12, 2>(xh, xl, w1, bx, by, 0, SM, acc);
        else        bg128<12, 1>(xh, xl, w1, bx, by, 0, SM, acc);
        int row0 = by * 128, col0 = bx * 128;
        #pragma unroll
        for (int mt = 0; mt < 4; ++mt)
            #pragma unroll
            for (int nt = 0; nt < 4; ++nt)
                #pragma unroll
                for (int r4 = 0; r4 < 4; ++r4) {
                    int r  = row0 + wrow + mt * 16 + g * 4 + r4;
                    int cc = col0 + wcol + nt * 16 + fr;
                    float val = acc[mt][nt][r4];
                    if (cc < 256)      tmpq[(size_t)r * 256 + cc] = val;
                    else if (cc < 512) tmpk[(size_t)r * 256 + (cc - 256)] = val;
                    else {
                        int c2 = cc - 512, hh = c2 >> 6, jj = c2 & 63;
                        int bb = r >> 11, n = r & 2047;
                        v[(((size_t)(bb * 16 + hh)) * 2048 + n) * 64 + jj] = val;
                    }
                }
    } else {
        int r2 = blk - 384;
        int bx = r2 % 10, by = r2 / 10;
        if (bx < 2) bg128<9, 2>(xh, xl, w2, bx, by, 2048, SM, acc);
        else        bg128<9, 1>(xh, xl, w2, bx, by, 2048, SM, acc);
        int row0 = by * 128, col0 = bx * 128;
        #pragma unroll
        for (int mt = 0; mt < 4; ++mt)
            #pragma unroll
            for (int nt = 0; nt < 4; ++nt)
                #pragma unroll
                for (int r4 = 0; r4 < 4; ++r4) {
                    int r  = row0 + wrow + mt * 16 + g * 4 + r4;
                    int cc = col0 + wcol + nt * 16 + fr;
                    float val = acc[mt][nt][r4];
                    if (cc < 256) tmpke[(size_t)r * 256 + cc] = val;
                    else {
                        int c2 = cc - 256, hh = c2 >> 6, jj = c2 & 63;
                        int bb = r >> 9, n = r & 511;
                        ve[(((size_t)(bb * 16 + hh)) * 512 + n) * 64 + jj] = val;
                    }
                }
    }
}

// out_gemm: attn(single f16) @ Wout(f16)^T -> f32 d_out, 1-pass.
__global__ __launch_bounds__(256) void out_gemm(
    const ushort_t* __restrict__ Atn, const ushort_t* __restrict__ Wh,
    float* __restrict__ out)
{
    __shared__ ushort_t SM[24576];
    f4v acc[4][4];
    int blk = xcd_swz(blockIdx.x, 256);
    int bx = blk & 7, by = blk >> 3;
    bg128<12, 1>(Atn, Atn, Wh, bx, by, 0, SM, acc);
    int t = threadIdx.x, w = t >> 6, lane = t & 63;
    int wrow = (w >> 1) * 64, wcol = (w & 1) * 64;
    int fr = lane & 15, g = lane >> 4;
    int row0 = by * 128, col0 = bx * 128;
    #pragma unroll
    for (int mt = 0; mt < 4; ++mt)
        #pragma unroll
        for (int nt = 0; nt < 4; ++nt)
            #pragma unroll
            for (int r4 = 0; r4 < 4; ++r4) {
                int r  = row0 + wrow + mt * 16 + g * 4 + r4;
                int cc = col0 + wcol + nt * 16 + fr;
                out[(size_t)r * 1024 + cc] = acc[mt][nt][r4];
            }
}

// ---------------------------------------------------------------------------
// MFMA state kernel, 1-pass: A = Vext single f16, B = on-the-fly features.
// ---------------------------------------------------------------------------
__device__ __forceinline__ void st_stage(
    const float* __restrict__ Kp, const float* __restrict__ V,
    size_t krow0, size_t vrow0, int h, int t,
    float* ksT, ushort_t* VTH)
{
    {
        int r = t >> 2, q4 = t & 3;
        float4 kv = *(const float4*)&Kp[(krow0 + r) * 256 + h * 16 + q4 * 4];
        ksT[(q4 * 4 + 0) * 68 + r] = kv.x;
        ksT[(q4 * 4 + 1) * 68 + r] = kv.y;
        ksT[(q4 * 4 + 2) * 68 + r] = kv.z;
        ksT[(q4 * 4 + 3) * 68 + r] = kv.w;
    }
    if (t < 64) ksT[16 * 68 + t] = 1.0f;
    {
        int r = t & 63, jg = t >> 6;
        #pragma unroll
        for (int cc = 0; cc < 4; ++cc) {
            float4 vv = *(const float4*)&V[(vrow0 + r) * HD_ + jg * 16 + cc * 4];
            float vals[4] = {vv.x, vv.y, vv.z, vv.w};
            #pragma unroll
            for (int e = 0; e < 4; ++e) {
                int j = jg * 16 + cc * 4 + e;
                VTH[j * 72 + r] = f16q(vals[e]);
            }
        }
    }
    if (t < 64) VTH[64 * 72 + t] = 0x3C00;  // f16 1.0
}

__device__ __forceinline__ void st_ftile(
    const float* ksT, int ft, int fr, int g,
    const h8v (&AHf)[2][5], f4v (&acc)[5])
{
    int f = ft * 16 + fr;
    int fi, fj; float scale;
    if (f == 0)       { fi = 16; fj = 16; scale = 1.0f; }
    else if (f < 17)  { fi = f - 1; fj = 16; scale = 0.5f; }
    else if (f < 273) { fi = (f - 17) >> 4; fj = (f - 17) & 15; scale = C2C_; }
    else              { fi = 16; fj = 16; scale = 0.0f; }
    #pragma unroll
    for (int ks2 = 0; ks2 < 2; ++ks2) {
        const float* pa = ksT + fi * 68 + ks2 * 32 + g * 8;
        const float* pb = ksT + fj * 68 + ks2 * 32 + g * 8;
        h8v bv;
        #pragma unroll
        for (int e = 0; e < 8; ++e) bv[e] = (_Float16)(pa[e] * pb[e] * scale);
        #pragma unroll
        for (int jt = 0; jt < 5; ++jt)
            acc[jt] = MFMAH_(AHf[ks2][jt], bv, acc[jt], 0, 0, 0);
    }
}

__global__ __launch_bounds__(256) void state_all(
    const float* __restrict__ Kpe, const float* __restrict__ Ve, ushort_t* __restrict__ Se,
    const float* __restrict__ Kpc, const float* __restrict__ Vc, ushort_t* __restrict__ Sc)
{
    __shared__ float ksT[17 * 68];
    __shared__ ushort_t VTH[80 * 72];
    int blk = blockIdx.x, t = threadIdx.x;
    int w = t >> 6, lane = t & 63, fr = lane & 15, g = lane >> 4;

    for (int i = t; i < 15 * 72; i += 256) VTH[65 * 72 + i] = 0;

    if (blk >= 160) {
        int b2 = blk - 160;
        int c = b2 & 31, bh = b2 >> 5;
        int b = bh >> 4, h = bh & 15;
        ushort_t* Sg = Sc + ((size_t)bh * NC_ + c) * SSZ_;
        st_stage(Kpc, Vc, (size_t)b * 2048 + c * 64, (size_t)bh * 2048 + c * 64,
                 h, t, ksT, VTH);
        __syncthreads();
        h8v AHf[2][5];
        #pragma unroll
        for (int ks2 = 0; ks2 < 2; ++ks2)
            #pragma unroll
            for (int jt = 0; jt < 5; ++jt)
                AHf[ks2][jt] = *(const h8v*)&VTH[(jt * 16 + fr) * 72 + ks2 * 32 + g * 8];
        for (int ft = w; ft < 18; ft += 4) {
            f4v acc[5];
            #pragma unroll
            for (int jt = 0; jt < 5; ++jt) acc[jt] = (f4v){0.f, 0.f, 0.f, 0.f};
            st_ftile(ksT, ft, fr, g, AHf, acc);
            #pragma unroll
            for (int jt = 0; jt < 5; ++jt)
                #pragma unroll
                for (int r4 = 0; r4 < 4; ++r4) {
                    int j = jt * 16 + g * 4 + r4;
                    if (j < 65) Sg[(size_t)j * FP_ + ft * 16 + fr] = f16q(acc[jt][r4]);
                }
        }
    } else {
        int bh = blk / 5, fg = blk % 5;
        int b = bh >> 4, h = bh & 15;
        int ft = fg * 4 + w;
        ushort_t* Sg = Se + (size_t)bh * SSZ_;
        f4v acc[5];
        #pragma unroll
        for (int jt = 0; jt < 5; ++jt) acc[jt] = (f4v){0.f, 0.f, 0.f, 0.f};
        for (int m0 = 0; m0 < 512; m0 += 64) {
            if (m0) __syncthreads();
            st_stage(Kpe, Ve, (size_t)b * 512 + m0, (size_t)bh * 512 + m0,
                     h, t, ksT, VTH);
            __syncthreads();
            if (ft < 18) {
                h8v AHf[2][5];
                #pragma unroll
                for (int ks2 = 0; ks2 < 2; ++ks2)
                    #pragma unroll
                    for (int jt = 0; jt < 5; ++jt)
                        AHf[ks2][jt] = *(const h8v*)&VTH[(jt * 16 + fr) * 72 + ks2 * 32 + g * 8];
                st_ftile(ksT, ft, fr, g, AHf, acc);
            }
        }
        if (ft < 18) {
            #pragma unroll
            for (int jt = 0; jt < 5; ++jt)
                #pragma unroll
                for (int r4 = 0; r4 < 4; ++r4) {
                    int j = jt * 16 + g * 4 + r4;
                    if (j < 65) Sg[(size_t)j * FP_ + ft * 16 + fr] = f16q(acc[jt][r4]);
                }
        }
    }
}

// ---------------------------------------------------------------------------
// Exclusive prefix over single-f16 states, in place (f32 accumulate in regs).
// ---------------------------------------------------------------------------
__global__ __launch_bounds__(256) void prefix_scan(
    ushort_t* __restrict__ Sloc, const ushort_t* __restrict__ Senc)
{
    const int Q = SSZ_ / 8;    // 2340 oct-groups (16B)
    int gid = blockIdx.x * 256 + threadIdx.x;
    if (gid >= 32 * Q) return;
    int bh = gid / Q, e = gid - bh * Q;
    s8v ev = *(const s8v*)(Senc + (size_t)bh * SSZ_ + e * 8);
    float run[8];
    #pragma unroll
    for (int u = 0; u < 8; ++u) run[u] = f16f((ushort_t)ev[u]);
    ushort_t* Sb = Sloc + (size_t)bh * NC_ * SSZ_ + e * 8;
    #pragma unroll 1
    for (int cb = 0; cb < 8; ++cb) {
        s8v t0 = *(const s8v*)(Sb + (size_t)(cb * 4 + 0) * SSZ_);
        s8v t1 = *(const s8v*)(Sb + (size_t)(cb * 4 + 1) * SSZ_);
        s8v t2 = *(const s8v*)(Sb + (size_t)(cb * 4 + 2) * SSZ_);
        s8v t3 = *(const s8v*)(Sb + (size_t)(cb * 4 + 3) * SSZ_);
        s8v o0, o1, o2, o3;
        #pragma unroll
        for (int u = 0; u < 8; ++u) { o0[u] = (short)f16q(run[u]); run[u] += f16f((ushort_t)t0[u]); }
        #pragma unroll
        for (int u = 0; u < 8; ++u) { o1[u] = (short)f16q(run[u]); run[u] += f16f((ushort_t)t1[u]); }
        #pragma unroll
        for (int u = 0; u < 8; ++u) { o2[u] = (short)f16q(run[u]); run[u] += f16f((ushort_t)t2[u]); }
        #pragma unroll
        for (int u = 0; u < 8; ++u) { o3[u] = (short)f16q(run[u]); run[u] += f16f((ushort_t)t3[u]); }
        *(s8v*)(Sb + (size_t)(cb * 4 + 0) * SSZ_) = o0;
        *(s8v*)(Sb + (size_t)(cb * 4 + 1) * SSZ_) = o1;
        *(s8v*)(Sb + (size_t)(cb * 4 + 2) * SSZ_) = o2;
        *(s8v*)(Sb + (size_t)(cb * 4 + 3) * SSZ_) = o3;
    }
}

// ---------------------------------------------------------------------------
// attn_chunk: QK^T bf16 3-pass; Y1 = A(f16 pair) @ V(f16 single);
// Y2 = QF(f16) @ S(f16 single) with register-prefetched state slices.
// Epilogue writes SINGLE f16.
// ---------------------------------------------------------------------------
template<int FW>
__device__ __forceinline__ void y2_issue(
    const ushort_t* __restrict__ Sth, int f0, int t, s8v& r0, s8v& r1, s8v& r2)
{
    constexpr int NS = FW / 8;
    constexpr int TOT = 65 * NS;
    int s1 = t + 256, s2 = t + 512;
    r0 = *(const s8v*)(Sth + (size_t)(t / NS) * FP_ + f0 + (t % NS) * 8);
    if (s1 < TOT) r1 = *(const s8v*)(Sth + (size_t)(s1 / NS) * FP_ + f0 + (s1 % NS) * 8);
    if (FW == 64 && s2 < TOT) r2 = *(const s8v*)(Sth + (size_t)(s2 / NS) * FP_ + f0 + (s2 % NS) * 8);
}

template<int FW>
__device__ __forceinline__ void y2_write(
    ushort_t* STH, int t, const s8v& r0, const s8v& r1, const s8v& r2)
{
    constexpr int NS = FW / 8;
    constexpr int TOT = 65 * NS;
    int s1 = t + 256, s2 = t + 512;
    *(s8v*)&STH[(t / NS) * 72 + (t % NS) * 8] = r0;
    if (s1 < TOT) *(s8v*)&STH[(s1 / NS) * 72 + (s1 % NS) * 8] = r1;
    if (FW == 64 && s2 < TOT) *(s8v*)&STH[(s2 / NS) * 72 + (s2 % NS) * 8] = r2;
}

template<int FW>
__device__ __forceinline__ void qf_gen(int f0, const float* qs, ushort_t* QF1, int t)
{
    for (int i = t; i < 64 * FW; i += 256) {
        int row = i / FW, cc = i % FW;
        int f = f0 + cc;
        float qv;
        if (f == 0)       qv = 1.0f;
        else if (f < 17)  qv = qs[row * 20 + (f - 1)] * 0.5f;
        else if (f < 273) qv = qs[row * 20 + ((f - 17) >> 4)] * qs[row * 20 + ((f - 17) & 15)] * C2C_;
        else              qv = 0.0f;
        QF1[row * 72 + cc] = f16q(qv);
    }
}

template<int FW>
__device__ __forceinline__ void y2_mfma(
    const ushort_t* QF1, const ushort_t* STH,
    f4v (&acc)[5], int w, int fr, int g)
{
    #pragma unroll
    for (int ks2 = 0; ks2 < FW / 32; ++ks2) {
        h8v a = *(const h8v*)&QF1[(16 * w + fr) * 72 + ks2 * 32 + g * 8];
        #pragma unroll
        for (int jt = 0; jt < 5; ++jt) {
            h8v b = *(const h8v*)&STH[(jt * 16 + fr) * 72 + ks2 * 32 + g * 8];
            acc[jt] = MFMAH_(a, b, acc[jt], 0, 0, 0);
        }
    }
}

__global__ __launch_bounds__(256) void attn_chunk(
    const float* __restrict__ qp, const float* __restrict__ kp,
    const float* __restrict__ v, const ushort_t* __restrict__ Spre,
    ushort_t* __restrict__ atn)
{
    __shared__ ushort_t U[19456];
    __shared__ float qs[64 * 20];
    __shared__ float den_s[64];
    ushort_t* AH  = U;            // [64][72]  f16 pair (A)
    ushort_t* AL  = U + 4608;
    ushort_t* QH  = U + 9216;     // [64][40]  bf16
    ushort_t* QL  = U + 11776;
    ushort_t* KH  = U + 14336;
    ushort_t* KL  = U + 16896;    // ends 19456
    ushort_t* VTH = U + 9216;     // [80][72]  f16 single (after phase A)
    ushort_t* QF1 = U;            // [64][72]  f16 (Y2)
    ushort_t* STH = U + 9216;     // [80][72]  f16 (Y2; rows 65-79 stay 0)

    int bid = blockIdx.x;
    int bh = bid >> 5, c = bid & 31;
    int b = bh >> 4, h = bh & 15;
    int t = threadIdx.x;
    int w = t >> 6, lane = t & 63, fr = lane & 15, g = lane >> 4;
    int rowbase = b * N_ + c * CHK_;
    const ushort_t* Sth = Spre + ((size_t)bh * NC_ + c) * SSZ_;

    // ---- issue q/k loads
    int rqk = t >> 2, q4 = t & 3;
    float4 qv = *(const float4*)&qp[(size_t)(rowbase + rqk) * 256 + h * 16 + q4 * 4];
    float4 kv = *(const float4*)&kp[(size_t)(rowbase + rqk) * 256 + h * 16 + q4 * 4];
    // ---- prefetch: state slice 0 + V tile (fly under QK^T)
    s8v rA0 = {}, rA1 = {}, rA2 = {};
    y2_issue<64>(Sth, 0, t, rA0, rA1, rA2);
    int mv = t & 63, jg0 = t >> 6;
    const float* vr = &v[((size_t)bh * N_ + c * CHK_ + mv) * HD_ + jg0 * 16];
    float4 rv0 = *(const float4*)(vr + 0);
    float4 rv1 = *(const float4*)(vr + 4);
    float4 rv2 = *(const float4*)(vr + 8);
    float4 rv3 = *(const float4*)(vr + 12);

    // ---- stage q/k (bf16 pair) + qs f32
    {
        u16x4 hh, ll;
        splitf4(qv, hh, ll);
        *(u16x4*)&QH[rqk * 40 + q4 * 4] = hh;
        *(u16x4*)&QL[rqk * 40 + q4 * 4] = ll;
        splitf4(kv, hh, ll);
        *(u16x4*)&KH[rqk * 40 + q4 * 4] = hh;
        *(u16x4*)&KL[rqk * 40 + q4 * 4] = ll;
        u16x4 z4 = (u16x4){0, 0, 0, 0};
        *(u16x4*)&QH[rqk * 40 + 16 + q4 * 4] = z4;
        *(u16x4*)&QL[rqk * 40 + 16 + q4 * 4] = z4;
        *(u16x4*)&KH[rqk * 40 + 16 + q4 * 4] = z4;
        *(u16x4*)&KL[rqk * 40 + 16 + q4 * 4] = z4;
        qs[rqk * 20 + q4 * 4 + 0] = qv.x;
        qs[rqk * 20 + q4 * 4 + 1] = qv.y;
        qs[rqk * 20 + q4 * 4 + 2] = qv.z;
        qs[rqk * 20 + q4 * 4 + 3] = qv.w;
    }
    __syncthreads();

    // ---- phase A: QK^T (bf16 3-pass), poly+tril, split to f16 pair AH/AL
    {
        s8v qh = *(const s8v*)&QH[(16 * w + fr) * 40 + g * 8];
        s8v ql = *(const s8v*)&QL[(16 * w + fr) * 40 + g * 8];
        f4v sacc[4];
        #pragma unroll
        for (int jt = 0; jt < 4; ++jt) sacc[jt] = (f4v){0.f, 0.f, 0.f, 0.f};
        #pragma unroll
        for (int jt = 0; jt < 4; ++jt) {
            s8v kh = *(const s8v*)&KH[(jt * 16 + fr) * 40 + g * 8];
            s8v kl = *(const s8v*)&KL[(jt * 16 + fr) * 40 + g * 8];
            sacc[jt] = MFMA_(qh, kh, sacc[jt], 0, 0, 0);
            sacc[jt] = MFMA_(qh, kl, sacc[jt], 0, 0, 0);
            sacc[jt] = MFMA_(ql, kh, sacc[jt], 0, 0, 0);
        }
        __syncthreads();   // QH..KL dead after this barrier (sacc in regs)
        #pragma unroll
        for (int jt = 0; jt < 4; ++jt)
            #pragma unroll
            for (int r4 = 0; r4 < 4; ++r4) {
                int row = 16 * w + g * 4 + r4, col = jt * 16 + fr;
                float s = sacc[jt][r4];
                float a = (row >= col) ? (fmaf(s, 0.25f, 1.0f) + s * s * 0.03125f) : 0.f;
                unsigned short hh, ll; splitf16(a, hh, ll);
                AH[row * 72 + col] = hh;
                AL[row * 72 + col] = ll;
            }
    }
    // ---- write V tile (single f16) from prefetched regs + ones/zero rows
    {
        int j0 = jg0 * 16;
        VTH[(j0 +  0) * 72 + mv] = f16q(rv0.x); VTH[(j0 +  1) * 72 + mv] = f16q(rv0.y);
        VTH[(j0 +  2) * 72 + mv] = f16q(rv0.z); VTH[(j0 +  3) * 72 + mv] = f16q(rv0.w);
        VTH[(j0 +  4) * 72 + mv] = f16q(rv1.x); VTH[(j0 +  5) * 72 + mv] = f16q(rv1.y);
        VTH[(j0 +  6) * 72 + mv] = f16q(rv1.z); VTH[(j0 +  7) * 72 + mv] = f16q(rv1.w);
        VTH[(j0 +  8) * 72 + mv] = f16q(rv2.x); VTH[(j0 +  9) * 72 + mv] = f16q(rv2.y);
        VTH[(j0 + 10) * 72 + mv] = f16q(rv2.z); VTH[(j0 + 11) * 72 + mv] = f16q(rv2.w);
        VTH[(j0 + 12) * 72 + mv] = f16q(rv3.x); VTH[(j0 + 13) * 72 + mv] = f16q(rv3.y);
        VTH[(j0 + 14) * 72 + mv] = f16q(rv3.z); VTH[(j0 + 15) * 72 + mv] = f16q(rv3.w);
    }
    if (t < 64) VTH[64 * 72 + t] = 0x3C00;          // f16 1.0 (denominator row)
    for (int i = t; i < 15 * 72; i += 256) VTH[65 * 72 + i] = 0;
    __syncthreads();

    // ---- Y1: acc += A(pair) @ VT(single)
    f4v acc[5];
    #pragma unroll
    for (int jt = 0; jt < 5; ++jt) acc[jt] = (f4v){0.f, 0.f, 0.f, 0.f};
    #pragma unroll
    for (int ks2 = 0; ks2 < 2; ++ks2) {
        h8v ah = *(const h8v*)&AH[(16 * w + fr) * 72 + ks2 * 32 + g * 8];
        h8v al = *(const h8v*)&AL[(16 * w + fr) * 72 + ks2 * 32 + g * 8];
        #pragma unroll
        for (int jt = 0; jt < 5; ++jt) {
            h8v b = *(const h8v*)&VTH[(jt * 16 + fr) * 72 + ks2 * 32 + g * 8];
            acc[jt] = MFMAH_(ah, b, acc[jt], 0, 0, 0);
            acc[jt] = MFMAH_(al, b, acc[jt], 0, 0, 0);
        }
    }
    __syncthreads();

    // ---- Y2: 5 state slices, register-prefetched (slice 0 already in rA*)
    #pragma unroll
    for (int p = 0; p < 4; ++p) {
        y2_write<64>(STH, t, rA0, rA1, rA2);
        if (p < 3) y2_issue<64>(Sth, (p + 1) * 64, t, rA0, rA1, rA2);
        else       y2_issue<32>(Sth, 256,          t, rA0, rA1, rA2);
        qf_gen<64>(p * 64, qs, QF1, t);
        __syncthreads();
        y2_mfma<64>(QF1, STH, acc, w, fr, g);
        __syncthreads();
    }
    y2_write<32>(STH, t, rA0, rA1, rA2);
    qf_gen<32>(256, qs, QF1, t);
    __syncthreads();
    y2_mfma<32>(QF1, STH, acc, w, fr, g);

    // ---- epilogue: divide by denominator, store single f16
    if (fr == 0) {
        #pragma unroll
        for (int r4 = 0; r4 < 4; ++r4)
            den_s[16 * w + g * 4 + r4] = acc[4][r4];
    }
    __syncthreads();
    #pragma unroll
    for (int r4 = 0; r4 < 4; ++r4) {
        float z = 1.0f / (den_s[16 * w + g * 4 + r4] + EPS_);
        int row = rowbase + 16 * w + g * 4 + r4;
        #pragma unroll
        for (int jt = 0; jt < 4; ++jt) {
            float val = acc[jt][r4] * z;
            atn[(size_t)row * 1024 + h * 64 + jt * 16 + fr] = f16q(val);
        }
    }
}

// ---------------------------------------------------------------------------
extern "C" void kernel_launch(void* const* d_in, const int* in_sizes, int n_in,
                              void* d_out, int out_size, void* d_ws, size_t ws_size,
                              hipStream_t stream)
{
    const float* x    = (const float*)d_in[0];
    const float* Wq   = (const float*)d_in[1];
    const float* Wk   = (const float*)d_in[2];
    const float* Wv   = (const float*)d_in[3];
    const float* Wke  = (const float*)d_in[4];
    const float* Wve  = (const float*)d_in[5];
    const float* Wout = (const float*)d_in[6];
    float* out = (float*)d_out;
    float* ws  = (float*)d_ws;

    // f32 region
    float* tmpq  = ws;                                 // 1,048,576
    float* tmpk  = tmpq  + (size_t)1048576;            // 1,048,576
    float* tmpke = tmpk  + (size_t)1048576;            //   262,144
    float* v     = tmpke + (size_t)262144;             // 4,194,304
    float* ve    = v     + (size_t)4194304;            // 1,048,576
    // f16 region
    ushort_t* Sloc = (ushort_t*)(ve + 1048576);        // 19,169,280 shorts (single-plane states)
    ushort_t* Senc = Sloc + (size_t)19169280;          //   599,040 shorts
    ushort_t* xh   = Senc + (size_t)599040;            // 4,194,304 shorts
    ushort_t* xl   = xh   + (size_t)4194304;           // 4,194,304 shorts
    ushort_t* wo   = xl   + (size_t)4194304;           // 1,048,576 shorts
    // overlays:
    ushort_t* w1 = Sloc;                               // dead before state_all
    ushort_t* w2 = w1 + (size_t)1572864;
    ushort_t* atn = xh;                                // xh dead after proj2

    dim3 blk(256);

    split_all<<<7936, blk, 0, stream>>>(x, Wq, Wk, Wv, Wke, Wve, Wout,
                                        xh, xl, w1, w2, wo);
    proj2<<<464, blk, 0, stream>>>(xh, xl, w1, w2, tmpq, tmpk, v, tmpke, ve);
    state_all<<<160 + 32 * NC_, blk, 0, stream>>>(tmpke, ve, Senc, tmpk, v, Sloc);
    prefix_scan<<<293, blk, 0, stream>>>(Sloc, Senc);
    attn_chunk<<<32 * NC_, blk, 0, stream>>>(tmpq, tmpk, v, Sloc, atn);
    out_gemm<<<256, blk, 0, stream>>>(atn, wo, out);
}

// Round 12
// 109.925 us; speedup vs baseline: 8.3424x; 1.0993x over previous
//
#include <hip/hip_runtime.h>

// Problem constants
#define B_    2
#define N_    2048
#define H_    16
#define HD_   64
#define ENC_  512
#define FP_   288
#define CHK_  64
#define NC_   32
#define SSZ_  18720                  // state elems: [65 j][288 f]; SINGLE f16 plane
#define C2C_  0.17677669529663687f   // 1/(4*sqrt(2))
#define EPS_  1e-12f

using s8v   = __attribute__((ext_vector_type(8))) short;     // 8x16-bit carrier
using s4v   = __attribute__((ext_vector_type(4))) short;     // 4x16-bit carrier
using h8v   = __attribute__((ext_vector_type(8))) _Float16;  // 8 f16 (4 VGPRs)
using f4v   = __attribute__((ext_vector_type(4))) float;
using u16x4 = __attribute__((ext_vector_type(4))) unsigned short;
typedef unsigned short ushort_t;

// ---- f16 helpers
__device__ __forceinline__ unsigned short f16q(float x) {
    _Float16 h = (_Float16)x;
    return __builtin_bit_cast(unsigned short, h);
}
__device__ __forceinline__ float f16f(unsigned short u) {
    return (float)__builtin_bit_cast(_Float16, u);
}
__device__ __forceinline__ u16x4 f16q4(float4 v) {
    return (u16x4){f16q(v.x), f16q(v.y), f16q(v.z), f16q(v.w)};
}

#define MFMAH_ __builtin_amdgcn_mfma_f32_16x16x32_f16

// async global->LDS, 16B per lane
__device__ __forceinline__ void gld16(const void* g, void* l) {
    __builtin_amdgcn_global_load_lds(
        (const __attribute__((address_space(1))) unsigned int*)g,
        (__attribute__((address_space(3))) unsigned int*)l, 16, 0, 0);
}

// bijective XCD swizzle (m204)
__device__ __forceinline__ int xcd_swz(int b, int nwg) {
    int q = nwg >> 3, r = nwg & 7;
    int xcd = b & 7, loc = b >> 3;
    return (xcd < r ? xcd * (q + 1) : r * (q + 1) + (xcd - r) * q) + loc;
}

// ---------------------------------------------------------------------------
// split_all: x -> xh ; [Wq;Wk;Wv] -> w1 ; [Wke;Wve] -> w2 ; Wout -> wo.
// All single f16.
// ---------------------------------------------------------------------------
#define X_F4   1048576
#define W1_F4  393216
#define W2_F4  327680
#define WO_F4  262144

__global__ __launch_bounds__(256) void split_all(
    const float* __restrict__ x,
    const float* __restrict__ Wq, const float* __restrict__ Wk,
    const float* __restrict__ Wv, const float* __restrict__ Wke,
    const float* __restrict__ Wve, const float* __restrict__ Wout,
    ushort_t* __restrict__ xh,
    ushort_t* __restrict__ w1, ushort_t* __restrict__ w2,
    ushort_t* __restrict__ wo)
{
    int gid = blockIdx.x * 256 + threadIdx.x;
    if (gid < X_F4) {
        ((u16x4*)xh)[gid] = f16q4(((const float4*)x)[gid]);
    } else if (gid < X_F4 + W1_F4) {
        int i = gid - X_F4;
        int row = i >> 8, c4 = i & 255;
        const float* s = (row < 256) ? Wq + (size_t)row * 1024
                       : (row < 512) ? Wk + (size_t)(row - 256) * 1024
                                     : Wv + (size_t)(row - 512) * 1024;
        ((u16x4*)w1)[i] = f16q4(*(const float4*)(s + c4 * 4));
    } else if (gid < X_F4 + W1_F4 + W2_F4) {
        int i = gid - X_F4 - W1_F4;
        int row = i >> 8, c4 = i & 255;
        const float* s = (row < 256) ? Wke + (size_t)row * 1024
                                     : Wve + (size_t)(row - 256) * 1024;
        ((u16x4*)w2)[i] = f16q4(*(const float4*)(s + c4 * 4));
    } else {
        int i = gid - X_F4 - W1_F4 - W2_F4;
        ((u16x4*)wo)[i] = f16q4(((const float4*)Wout)[i]);
    }
}

// ---------------------------------------------------------------------------
// f16 1-pass GEMM body; double-buffered global_load_lds staging.
// LDS: 2 buffers x {A[128][32] | B[128][32]} f16 = 32 KB.
// ---------------------------------------------------------------------------
template <int SHIFT>
__device__ __forceinline__ void bg128(
    const ushort_t* __restrict__ Ah, const ushort_t* __restrict__ Wh,
    int bx, int by, int rowjump,
    ushort_t* SM, f4v (&acc)[4][4])
{
    int t = threadIdx.x;
    int w = t >> 6, lane = t & 63;
    int row0 = by * 128, col0 = bx * 128;
    int wrow = (w >> 1) * 64, wcol = (w & 1) * 64;
    int fr = lane & 15, g = lane >> 4;

    int c0 = lane, c1 = 64 + lane;
    int r0 = w * 32 + (c0 >> 2), k80 = (c0 & 3) * 8;
    int r1 = w * 32 + (c1 >> 2), k81 = (c1 & 3) * 8;
    int gr0 = row0 + r0, gr1 = row0 + r1;
    size_t a0 = (size_t)(gr0 >> SHIFT) * rowjump + (gr0 & ((1 << SHIFT) - 1));
    size_t a1 = (size_t)(gr1 >> SHIFT) * rowjump + (gr1 & ((1 << SHIFT) - 1));
    const ushort_t* pA0 = Ah + a0 * 1024 + k80;
    const ushort_t* pA1 = Ah + a1 * 1024 + k81;
    const ushort_t* pW0 = Wh + (size_t)(col0 + r0) * 1024 + k80;
    const ushort_t* pW1 = Wh + (size_t)(col0 + r1) * 1024 + k81;
    int woff = w * 1024;

    #pragma unroll
    for (int mt = 0; mt < 4; ++mt)
        #pragma unroll
        for (int nt = 0; nt < 4; ++nt) acc[mt][nt] = (f4v){0.f, 0.f, 0.f, 0.f};

    auto STAGE = [&](int buf, int k0) {
        ushort_t* Bp = SM + buf * 8192;
        gld16(pA0 + k0, Bp + woff);
        gld16(pA1 + k0, Bp + woff + 512);
        gld16(pW0 + k0, Bp + 4096 + woff);
        gld16(pW1 + k0, Bp + 4096 + woff + 512);
    };

    STAGE(0, 0);
    __syncthreads();
    int cur = 0;
    for (int k0 = 0; k0 < 1024; k0 += 32) {
        if (k0 + 32 < 1024) STAGE(cur ^ 1, k0 + 32);
        ushort_t* Bp = SM + cur * 8192;
        h8v a_h[4], b_[4];
        #pragma unroll
        for (int mt = 0; mt < 4; ++mt)
            a_h[mt] = *(const h8v*)&Bp[(wrow + mt * 16 + fr) * 32 + g * 8];
        #pragma unroll
        for (int nt = 0; nt < 4; ++nt)
            b_[nt] = *(const h8v*)&Bp[4096 + (wcol + nt * 16 + fr) * 32 + g * 8];
        #pragma unroll
        for (int mt = 0; mt < 4; ++mt)
            #pragma unroll
            for (int nt = 0; nt < 4; ++nt)
                acc[mt][nt] = MFMAH_(a_h[mt], b_[nt], acc[mt][nt], 0, 0, 0);
        __syncthreads();
        cur ^= 1;
    }
}

// ---------------------------------------------------------------------------
// proj2: main (384 blocks) + enc (80 blocks), all 1-pass.
// ---------------------------------------------------------------------------
__global__ __launch_bounds__(256) void proj2(
    const ushort_t* __restrict__ xh,
    const ushort_t* __restrict__ w1, const ushort_t* __restrict__ w2,
    float* __restrict__ tmpq, float* __restrict__ tmpk, float* __restrict__ v,
    float* __restrict__ tmpke, float* __restrict__ ve)
{
    __shared__ ushort_t SM[16384];
    f4v acc[4][4];
    int blk = xcd_swz(blockIdx.x, 464);
    int t = threadIdx.x, w = t >> 6, lane = t & 63;
    int wrow = (w >> 1) * 64, wcol = (w & 1) * 64;
    int fr = lane & 15, g = lane >> 4;

    if (blk < 384) {
        int bx = blk % 12, by = blk / 12;
        bg128<12>(xh, w1, bx, by, 0, SM, acc);
        int row0 = by * 128, col0 = bx * 128;
        #pragma unroll
        for (int mt = 0; mt < 4; ++mt)
            #pragma unroll
            for (int nt = 0; nt < 4; ++nt)
                #pragma unroll
                for (int r4 = 0; r4 < 4; ++r4) {
                    int r  = row0 + wrow + mt * 16 + g * 4 + r4;
                    int cc = col0 + wcol + nt * 16 + fr;
                    float val = acc[mt][nt][r4];
                    if (cc < 256)      tmpq[(size_t)r * 256 + cc] = val;
                    else if (cc < 512) tmpk[(size_t)r * 256 + (cc - 256)] = val;
                    else {
                        int c2 = cc - 512, hh = c2 >> 6, jj = c2 & 63;
                        int bb = r >> 11, n = r & 2047;
                        v[(((size_t)(bb * 16 + hh)) * 2048 + n) * 64 + jj] = val;
                    }
                }
    } else {
        int r2 = blk - 384;
        int bx = r2 % 10, by = r2 / 10;
        bg128<9>(xh, w2, bx, by, 2048, SM, acc);
        int row0 = by * 128, col0 = bx * 128;
        #pragma unroll
        for (int mt = 0; mt < 4; ++mt)
            #pragma unroll
            for (int nt = 0; nt < 4; ++nt)
                #pragma unroll
                for (int r4 = 0; r4 < 4; ++r4) {
                    int r  = row0 + wrow + mt * 16 + g * 4 + r4;
                    int cc = col0 + wcol + nt * 16 + fr;
                    float val = acc[mt][nt][r4];
                    if (cc < 256) tmpke[(size_t)r * 256 + cc] = val;
                    else {
                        int c2 = cc - 256, hh = c2 >> 6, jj = c2 & 63;
                        int bb = r >> 9, n = r & 511;
                        ve[(((size_t)(bb * 16 + hh)) * 512 + n) * 64 + jj] = val;
                    }
                }
    }
}

// out_gemm: attn(single f16) @ Wout(f16)^T -> f32 d_out, 1-pass.
__global__ __launch_bounds__(256) void out_gemm(
    const ushort_t* __restrict__ Atn, const ushort_t* __restrict__ Wh,
    float* __restrict__ out)
{
    __shared__ ushort_t SM[16384];
    f4v acc[4][4];
    int blk = xcd_swz(blockIdx.x, 256);
    int bx = blk & 7, by = blk >> 3;
    bg128<12>(Atn, Wh, bx, by, 0, SM, acc);
    int t = threadIdx.x, w = t >> 6, lane = t & 63;
    int wrow = (w >> 1) * 64, wcol = (w & 1) * 64;
    int fr = lane & 15, g = lane >> 4;
    int row0 = by * 128, col0 = bx * 128;
    #pragma unroll
    for (int mt = 0; mt < 4; ++mt)
        #pragma unroll
        for (int nt = 0; nt < 4; ++nt)
            #pragma unroll
            for (int r4 = 0; r4 < 4; ++r4) {
                int r  = row0 + wrow + mt * 16 + g * 4 + r4;
                int cc = col0 + wcol + nt * 16 + fr;
                out[(size_t)r * 1024 + cc] = acc[mt][nt][r4];
            }
}

// ---------------------------------------------------------------------------
// MFMA state kernel, 1-pass: A = Vext single f16, B = on-the-fly features.
// ---------------------------------------------------------------------------
__device__ __forceinline__ void st_stage(
    const float* __restrict__ Kp, const float* __restrict__ V,
    size_t krow0, size_t vrow0, int h, int t,
    float* ksT, ushort_t* VTH)
{
    {
        int r = t >> 2, q4 = t & 3;
        float4 kv = *(const float4*)&Kp[(krow0 + r) * 256 + h * 16 + q4 * 4];
        ksT[(q4 * 4 + 0) * 68 + r] = kv.x;
        ksT[(q4 * 4 + 1) * 68 + r] = kv.y;
        ksT[(q4 * 4 + 2) * 68 + r] = kv.z;
        ksT[(q4 * 4 + 3) * 68 + r] = kv.w;
    }
    if (t < 64) ksT[16 * 68 + t] = 1.0f;
    {
        int r = t & 63, jg = t >> 6;
        #pragma unroll
        for (int cc = 0; cc < 4; ++cc) {
            float4 vv = *(const float4*)&V[(vrow0 + r) * HD_ + jg * 16 + cc * 4];
            float vals[4] = {vv.x, vv.y, vv.z, vv.w};
            #pragma unroll
            for (int e = 0; e < 4; ++e) {
                int j = jg * 16 + cc * 4 + e;
                VTH[j * 72 + r] = f16q(vals[e]);
            }
        }
    }
    if (t < 64) VTH[64 * 72 + t] = 0x3C00;  // f16 1.0
}

__device__ __forceinline__ void st_ftile(
    const float* ksT, int ft, int fr, int g,
    const h8v (&AHf)[2][5], f4v (&acc)[5])
{
    int f = ft * 16 + fr;
    int fi, fj; float scale;
    if (f == 0)       { fi = 16; fj = 16; scale = 1.0f; }
    else if (f < 17)  { fi = f - 1; fj = 16; scale = 0.5f; }
    else if (f < 273) { fi = (f - 17) >> 4; fj = (f - 17) & 15; scale = C2C_; }
    else              { fi = 16; fj = 16; scale = 0.0f; }
    #pragma unroll
    for (int ks2 = 0; ks2 < 2; ++ks2) {
        const float* pa = ksT + fi * 68 + ks2 * 32 + g * 8;
        const float* pb = ksT + fj * 68 + ks2 * 32 + g * 8;
        h8v bv;
        #pragma unroll
        for (int e = 0; e < 8; ++e) bv[e] = (_Float16)(pa[e] * pb[e] * scale);
        #pragma unroll
        for (int jt = 0; jt < 5; ++jt)
            acc[jt] = MFMAH_(AHf[ks2][jt], bv, acc[jt], 0, 0, 0);
    }
}

__global__ __launch_bounds__(256) void state_all(
    const float* __restrict__ Kpe, const float* __restrict__ Ve, ushort_t* __restrict__ Se,
    const float* __restrict__ Kpc, const float* __restrict__ Vc, ushort_t* __restrict__ Sc)
{
    __shared__ float ksT[17 * 68];
    __shared__ ushort_t VTH[80 * 72];
    int blk = blockIdx.x, t = threadIdx.x;
    int w = t >> 6, lane = t & 63, fr = lane & 15, g = lane >> 4;

    for (int i = t; i < 15 * 72; i += 256) VTH[65 * 72 + i] = 0;

    if (blk >= 160) {
        int b2 = blk - 160;
        int c = b2 & 31, bh = b2 >> 5;
        int b = bh >> 4, h = bh & 15;
        ushort_t* Sg = Sc + ((size_t)bh * NC_ + c) * SSZ_;
        st_stage(Kpc, Vc, (size_t)b * 2048 + c * 64, (size_t)bh * 2048 + c * 64,
                 h, t, ksT, VTH);
        __syncthreads();
        h8v AHf[2][5];
        #pragma unroll
        for (int ks2 = 0; ks2 < 2; ++ks2)
            #pragma unroll
            for (int jt = 0; jt < 5; ++jt)
                AHf[ks2][jt] = *(const h8v*)&VTH[(jt * 16 + fr) * 72 + ks2 * 32 + g * 8];
        for (int ft = w; ft < 18; ft += 4) {
            f4v acc[5];
            #pragma unroll
            for (int jt = 0; jt < 5; ++jt) acc[jt] = (f4v){0.f, 0.f, 0.f, 0.f};
            st_ftile(ksT, ft, fr, g, AHf, acc);
            #pragma unroll
            for (int jt = 0; jt < 5; ++jt)
                #pragma unroll
                for (int r4 = 0; r4 < 4; ++r4) {
                    int j = jt * 16 + g * 4 + r4;
                    if (j < 65) Sg[(size_t)j * FP_ + ft * 16 + fr] = f16q(acc[jt][r4]);
                }
        }
    } else {
        int bh = blk / 5, fg = blk % 5;
        int b = bh >> 4, h = bh & 15;
        int ft = fg * 4 + w;
        ushort_t* Sg = Se + (size_t)bh * SSZ_;
        f4v acc[5];
        #pragma unroll
        for (int jt = 0; jt < 5; ++jt) acc[jt] = (f4v){0.f, 0.f, 0.f, 0.f};
        for (int m0 = 0; m0 < 512; m0 += 64) {
            if (m0) __syncthreads();
            st_stage(Kpe, Ve, (size_t)b * 512 + m0, (size_t)bh * 512 + m0,
                     h, t, ksT, VTH);
            __syncthreads();
            if (ft < 18) {
                h8v AHf[2][5];
                #pragma unroll
                for (int ks2 = 0; ks2 < 2; ++ks2)
                    #pragma unroll
                    for (int jt = 0; jt < 5; ++jt)
                        AHf[ks2][jt] = *(const h8v*)&VTH[(jt * 16 + fr) * 72 + ks2 * 32 + g * 8];
                st_ftile(ksT, ft, fr, g, AHf, acc);
            }
        }
        if (ft < 18) {
            #pragma unroll
            for (int jt = 0; jt < 5; ++jt)
                #pragma unroll
                for (int r4 = 0; r4 < 4; ++r4) {
                    int j = jt * 16 + g * 4 + r4;
                    if (j < 65) Sg[(size_t)j * FP_ + ft * 16 + fr] = f16q(acc[jt][r4]);
                }
        }
    }
}

// ---------------------------------------------------------------------------
// Exclusive prefix over single-f16 states, in place (f32 accumulate).
// 8B granularity for 2x wave-parallelism (latency hiding).
// ---------------------------------------------------------------------------
__global__ __launch_bounds__(256) void prefix_scan(
    ushort_t* __restrict__ Sloc, const ushort_t* __restrict__ Senc)
{
    const int Q = SSZ_ / 4;    // 4680 quad(4-short) groups
    int gid = blockIdx.x * 256 + threadIdx.x;
    if (gid >= 32 * Q) return;
    int bh = gid / Q, e = gid - bh * Q;
    s4v ev = *(const s4v*)(Senc + (size_t)bh * SSZ_ + e * 4);
    float run[4];
    #pragma unroll
    for (int u = 0; u < 4; ++u) run[u] = f16f((ushort_t)ev[u]);
    ushort_t* Sb = Sloc + (size_t)bh * NC_ * SSZ_ + e * 4;
    #pragma unroll 1
    for (int cb = 0; cb < 8; ++cb) {
        s4v t0 = *(const s4v*)(Sb + (size_t)(cb * 4 + 0) * SSZ_);
        s4v t1 = *(const s4v*)(Sb + (size_t)(cb * 4 + 1) * SSZ_);
        s4v t2 = *(const s4v*)(Sb + (size_t)(cb * 4 + 2) * SSZ_);
        s4v t3 = *(const s4v*)(Sb + (size_t)(cb * 4 + 3) * SSZ_);
        s4v o0, o1, o2, o3;
        #pragma unroll
        for (int u = 0; u < 4; ++u) { o0[u] = (short)f16q(run[u]); run[u] += f16f((ushort_t)t0[u]); }
        #pragma unroll
        for (int u = 0; u < 4; ++u) { o1[u] = (short)f16q(run[u]); run[u] += f16f((ushort_t)t1[u]); }
        #pragma unroll
        for (int u = 0; u < 4; ++u) { o2[u] = (short)f16q(run[u]); run[u] += f16f((ushort_t)t2[u]); }
        #pragma unroll
        for (int u = 0; u < 4; ++u) { o3[u] = (short)f16q(run[u]); run[u] += f16f((ushort_t)t3[u]); }
        *(s4v*)(Sb + (size_t)(cb * 4 + 0) * SSZ_) = o0;
        *(s4v*)(Sb + (size_t)(cb * 4 + 1) * SSZ_) = o1;
        *(s4v*)(Sb + (size_t)(cb * 4 + 2) * SSZ_) = o2;
        *(s4v*)(Sb + (size_t)(cb * 4 + 3) * SSZ_) = o3;
    }
}

// ---------------------------------------------------------------------------
// attn_chunk: QK^T single-f16 1-pass; Y1 = A(f16) @ V(f16) 1-pass;
// Y2 = QF(f16) @ S(f16) with register-prefetched state slices.
// ---------------------------------------------------------------------------
template<int FW>
__device__ __forceinline__ void y2_issue(
    const ushort_t* __restrict__ Sth, int f0, int t, s8v& r0, s8v& r1, s8v& r2)
{
    constexpr int NS = FW / 8;
    constexpr int TOT = 65 * NS;
    int s1 = t + 256, s2 = t + 512;
    r0 = *(const s8v*)(Sth + (size_t)(t / NS) * FP_ + f0 + (t % NS) * 8);
    if (s1 < TOT) r1 = *(const s8v*)(Sth + (size_t)(s1 / NS) * FP_ + f0 + (s1 % NS) * 8);
    if (FW == 64 && s2 < TOT) r2 = *(const s8v*)(Sth + (size_t)(s2 / NS) * FP_ + f0 + (s2 % NS) * 8);
}

template<int FW>
__device__ __forceinline__ void y2_write(
    ushort_t* STH, int t, const s8v& r0, const s8v& r1, const s8v& r2)
{
    constexpr int NS = FW / 8;
    constexpr int TOT = 65 * NS;
    int s1 = t + 256, s2 = t + 512;
    *(s8v*)&STH[(t / NS) * 72 + (t % NS) * 8] = r0;
    if (s1 < TOT) *(s8v*)&STH[(s1 / NS) * 72 + (s1 % NS) * 8] = r1;
    if (FW == 64 && s2 < TOT) *(s8v*)&STH[(s2 / NS) * 72 + (s2 % NS) * 8] = r2;
}

template<int FW>
__device__ __forceinline__ void qf_gen(int f0, const float* qs, ushort_t* QF1, int t)
{
    for (int i = t; i < 64 * FW; i += 256) {
        int row = i / FW, cc = i % FW;
        int f = f0 + cc;
        float qv;
        if (f == 0)       qv = 1.0f;
        else if (f < 17)  qv = qs[row * 20 + (f - 1)] * 0.5f;
        else if (f < 273) qv = qs[row * 20 + ((f - 17) >> 4)] * qs[row * 20 + ((f - 17) & 15)] * C2C_;
        else              qv = 0.0f;
        QF1[row * 72 + cc] = f16q(qv);
    }
}

template<int FW>
__device__ __forceinline__ void y2_mfma(
    const ushort_t* QF1, const ushort_t* STH,
    f4v (&acc)[5], int w, int fr, int g)
{
    #pragma unroll
    for (int ks2 = 0; ks2 < FW / 32; ++ks2) {
        h8v a = *(const h8v*)&QF1[(16 * w + fr) * 72 + ks2 * 32 + g * 8];
        #pragma unroll
        for (int jt = 0; jt < 5; ++jt) {
            h8v b = *(const h8v*)&STH[(jt * 16 + fr) * 72 + ks2 * 32 + g * 8];
            acc[jt] = MFMAH_(a, b, acc[jt], 0, 0, 0);
        }
    }
}

__global__ __launch_bounds__(256) void attn_chunk(
    const float* __restrict__ qp, const float* __restrict__ kp,
    const float* __restrict__ v, const ushort_t* __restrict__ Spre,
    ushort_t* __restrict__ atn)
{
    __shared__ ushort_t U[14976];
    __shared__ float qs[64 * 20];
    __shared__ float den_s[64];
    ushort_t* AH  = U;            // [64][72]  f16 single (A)
    ushort_t* QH  = U + 9216;     // [64][40]  f16 single
    ushort_t* KH  = U + 11776;    // [64][40]  -> ends 14336
    ushort_t* VTH = U + 9216;     // [80][72]  f16 single (after QK^T)
    ushort_t* QF1 = U;            // [64][72]  f16 (Y2; overlays AH after Y1)
    ushort_t* STH = U + 9216;     // [80][72]  f16 (Y2; rows 65-79 stay 0)

    int bid = blockIdx.x;
    int bh = bid >> 5, c = bid & 31;
    int b = bh >> 4, h = bh & 15;
    int t = threadIdx.x;
    int w = t >> 6, lane = t & 63, fr = lane & 15, g = lane >> 4;
    int rowbase = b * N_ + c * CHK_;
    const ushort_t* Sth = Spre + ((size_t)bh * NC_ + c) * SSZ_;

    // ---- issue q/k loads
    int rqk = t >> 2, q4 = t & 3;
    float4 qv = *(const float4*)&qp[(size_t)(rowbase + rqk) * 256 + h * 16 + q4 * 4];
    float4 kv = *(const float4*)&kp[(size_t)(rowbase + rqk) * 256 + h * 16 + q4 * 4];
    // ---- prefetch: state slice 0 + V tile (fly under QK^T)
    s8v rA0 = {}, rA1 = {}, rA2 = {};
    y2_issue<64>(Sth, 0, t, rA0, rA1, rA2);
    int mv = t & 63, jg0 = t >> 6;
    const float* vr = &v[((size_t)bh * N_ + c * CHK_ + mv) * HD_ + jg0 * 16];
    float4 rv0 = *(const float4*)(vr + 0);
    float4 rv1 = *(const float4*)(vr + 4);
    float4 rv2 = *(const float4*)(vr + 8);
    float4 rv3 = *(const float4*)(vr + 12);

    // ---- stage q/k (single f16) + qs f32
    {
        *(u16x4*)&QH[rqk * 40 + q4 * 4] = f16q4(qv);
        *(u16x4*)&KH[rqk * 40 + q4 * 4] = f16q4(kv);
        u16x4 z4 = (u16x4){0, 0, 0, 0};
        *(u16x4*)&QH[rqk * 40 + 16 + q4 * 4] = z4;
        *(u16x4*)&KH[rqk * 40 + 16 + q4 * 4] = z4;
        qs[rqk * 20 + q4 * 4 + 0] = qv.x;
        qs[rqk * 20 + q4 * 4 + 1] = qv.y;
        qs[rqk * 20 + q4 * 4 + 2] = qv.z;
        qs[rqk * 20 + q4 * 4 + 3] = qv.w;
    }
    __syncthreads();

    // ---- phase A: QK^T (f16 1-pass), poly+tril, store single f16 AH
    {
        h8v qh = *(const h8v*)&QH[(16 * w + fr) * 40 + g * 8];
        f4v sacc[4];
        #pragma unroll
        for (int jt = 0; jt < 4; ++jt) sacc[jt] = (f4v){0.f, 0.f, 0.f, 0.f};
        #pragma unroll
        for (int jt = 0; jt < 4; ++jt) {
            h8v kh = *(const h8v*)&KH[(jt * 16 + fr) * 40 + g * 8];
            sacc[jt] = MFMAH_(qh, kh, sacc[jt], 0, 0, 0);
        }
        __syncthreads();   // QH/KH dead after this barrier (sacc in regs)
        #pragma unroll
        for (int jt = 0; jt < 4; ++jt)
            #pragma unroll
            for (int r4 = 0; r4 < 4; ++r4) {
                int row = 16 * w + g * 4 + r4, col = jt * 16 + fr;
                float s = sacc[jt][r4];
                float a = (row >= col) ? (fmaf(s, 0.25f, 1.0f) + s * s * 0.03125f) : 0.f;
                AH[row * 72 + col] = f16q(a);
            }
    }
    // ---- write V tile (single f16) from prefetched regs + ones/zero rows
    {
        int j0 = jg0 * 16;
        VTH[(j0 +  0) * 72 + mv] = f16q(rv0.x); VTH[(j0 +  1) * 72 + mv] = f16q(rv0.y);
        VTH[(j0 +  2) * 72 + mv] = f16q(rv0.z); VTH[(j0 +  3) * 72 + mv] = f16q(rv0.w);
        VTH[(j0 +  4) * 72 + mv] = f16q(rv1.x); VTH[(j0 +  5) * 72 + mv] = f16q(rv1.y);
        VTH[(j0 +  6) * 72 + mv] = f16q(rv1.z); VTH[(j0 +  7) * 72 + mv] = f16q(rv1.w);
        VTH[(j0 +  8) * 72 + mv] = f16q(rv2.x); VTH[(j0 +  9) * 72 + mv] = f16q(rv2.y);
        VTH[(j0 + 10) * 72 + mv] = f16q(rv2.z); VTH[(j0 + 11) * 72 + mv] = f16q(rv2.w);
        VTH[(j0 + 12) * 72 + mv] = f16q(rv3.x); VTH[(j0 + 13) * 72 + mv] = f16q(rv3.y);
        VTH[(j0 + 14) * 72 + mv] = f16q(rv3.z); VTH[(j0 + 15) * 72 + mv] = f16q(rv3.w);
    }
    if (t < 64) VTH[64 * 72 + t] = 0x3C00;          // f16 1.0 (denominator row)
    for (int i = t; i < 15 * 72; i += 256) VTH[65 * 72 + i] = 0;
    __syncthreads();

    // ---- Y1: acc += A(single) @ VT(single)
    f4v acc[5];
    #pragma unroll
    for (int jt = 0; jt < 5; ++jt) acc[jt] = (f4v){0.f, 0.f, 0.f, 0.f};
    #pragma unroll
    for (int ks2 = 0; ks2 < 2; ++ks2) {
        h8v ah = *(const h8v*)&AH[(16 * w + fr) * 72 + ks2 * 32 + g * 8];
        #pragma unroll
        for (int jt = 0; jt < 5; ++jt) {
            h8v b = *(const h8v*)&VTH[(jt * 16 + fr) * 72 + ks2 * 32 + g * 8];
            acc[jt] = MFMAH_(ah, b, acc[jt], 0, 0, 0);
        }
    }
    __syncthreads();

    // ---- Y2: 5 state slices, register-prefetched (slice 0 already in rA*)
    #pragma unroll
    for (int p = 0; p < 4; ++p) {
        y2_write<64>(STH, t, rA0, rA1, rA2);
        if (p < 3) y2_issue<64>(Sth, (p + 1) * 64, t, rA0, rA1, rA2);
        else       y2_issue<32>(Sth, 256,          t, rA0, rA1, rA2);
        qf_gen<64>(p * 64, qs, QF1, t);
        __syncthreads();
        y2_mfma<64>(QF1, STH, acc, w, fr, g);
        __syncthreads();
    }
    y2_write<32>(STH, t, rA0, rA1, rA2);
    qf_gen<32>(256, qs, QF1, t);
    __syncthreads();
    y2_mfma<32>(QF1, STH, acc, w, fr, g);

    // ---- epilogue: divide by denominator, store single f16
    if (fr == 0) {
        #pragma unroll
        for (int r4 = 0; r4 < 4; ++r4)
            den_s[16 * w + g * 4 + r4] = acc[4][r4];
    }
    __syncthreads();
    #pragma unroll
    for (int r4 = 0; r4 < 4; ++r4) {
        float z = 1.0f / (den_s[16 * w + g * 4 + r4] + EPS_);
        int row = rowbase + 16 * w + g * 4 + r4;
        #pragma unroll
        for (int jt = 0; jt < 4; ++jt) {
            float val = acc[jt][r4] * z;
            atn[(size_t)row * 1024 + h * 64 + jt * 16 + fr] = f16q(val);
        }
    }
}

// ---------------------------------------------------------------------------
extern "C" void kernel_launch(void* const* d_in, const int* in_sizes, int n_in,
                              void* d_out, int out_size, void* d_ws, size_t ws_size,
                              hipStream_t stream)
{
    const float* x    = (const float*)d_in[0];
    const float* Wq   = (const float*)d_in[1];
    const float* Wk   = (const float*)d_in[2];
    const float* Wv   = (const float*)d_in[3];
    const float* Wke  = (const float*)d_in[4];
    const float* Wve  = (const float*)d_in[5];
    const float* Wout = (const float*)d_in[6];
    float* out = (float*)d_out;
    float* ws  = (float*)d_ws;

    // f32 region
    float* tmpq  = ws;                                 // 1,048,576
    float* tmpk  = tmpq  + (size_t)1048576;            // 1,048,576
    float* tmpke = tmpk  + (size_t)1048576;            //   262,144
    float* v     = tmpke + (size_t)262144;             // 4,194,304
    float* ve    = v     + (size_t)4194304;            // 1,048,576
    // f16 region
    ushort_t* Sloc = (ushort_t*)(ve + 1048576);        // 19,169,280 shorts
    ushort_t* Senc = Sloc + (size_t)19169280;          //   599,040 shorts
    ushort_t* xh   = Senc + (size_t)599040;            // 4,194,304 shorts
    ushort_t* wo   = xh   + (size_t)4194304;           // 1,048,576 shorts
    // overlays:
    ushort_t* w1 = Sloc;                               // dead before state_all
    ushort_t* w2 = w1 + (size_t)1572864;
    ushort_t* atn = xh;                                // xh dead after proj2

    dim3 blk(256);

    split_all<<<7936, blk, 0, stream>>>(x, Wq, Wk, Wv, Wke, Wve, Wout,
                                        xh, w1, w2, wo);
    proj2<<<464, blk, 0, stream>>>(xh, w1, w2, tmpq, tmpk, v, tmpke, ve);
    state_all<<<160 + 32 * NC_, blk, 0, stream>>>(tmpke, ve, Senc, tmpk, v, Sloc);
    prefix_scan<<<585, blk, 0, stream>>>(Sloc, Senc);
    attn_chunk<<<32 * NC_, blk, 0, stream>>>(tmpq, tmpk, v, Sloc, atn);
    out_gemm<<<256, blk, 0, stream>>>(atn, wo, out);
}

// Round 13
// 103.506 us; speedup vs baseline: 8.8598x; 1.0620x over previous
//
#include <hip/hip_runtime.h>

// Problem constants
#define B_    2
#define N_    2048
#define H_    16
#define HD_   64
#define ENC_  512
#define FP_   288
#define CHK_  64
#define NC_   32
#define SSZ_  18720                  // state elems: [65 j][288 f]; SINGLE f16 plane
#define C2C_  0.17677669529663687f   // 1/(4*sqrt(2))
#define EPS_  1e-12f

using s8v   = __attribute__((ext_vector_type(8))) short;     // 8x16-bit carrier
using s4v   = __attribute__((ext_vector_type(4))) short;     // 4x16-bit carrier
using h8v   = __attribute__((ext_vector_type(8))) _Float16;  // 8 f16 (4 VGPRs)
using f4v   = __attribute__((ext_vector_type(4))) float;
using u16x4 = __attribute__((ext_vector_type(4))) unsigned short;
typedef unsigned short ushort_t;

// ---- f16 helpers
__device__ __forceinline__ unsigned short f16q(float x) {
    _Float16 h = (_Float16)x;
    return __builtin_bit_cast(unsigned short, h);
}
__device__ __forceinline__ float f16f(unsigned short u) {
    return (float)__builtin_bit_cast(_Float16, u);
}
__device__ __forceinline__ u16x4 f16q4(float4 v) {
    return (u16x4){f16q(v.x), f16q(v.y), f16q(v.z), f16q(v.w)};
}

#define MFMAH_ __builtin_amdgcn_mfma_f32_16x16x32_f16

// async global->LDS, 16B per lane
__device__ __forceinline__ void gld16(const void* g, void* l) {
    __builtin_amdgcn_global_load_lds(
        (const __attribute__((address_space(1))) unsigned int*)g,
        (__attribute__((address_space(3))) unsigned int*)l, 16, 0, 0);
}

// bijective XCD swizzle (m204)
__device__ __forceinline__ int xcd_swz(int b, int nwg) {
    int q = nwg >> 3, r = nwg & 7;
    int xcd = b & 7, loc = b >> 3;
    return (xcd < r ? xcd * (q + 1) : r * (q + 1) + (xcd - r) * q) + loc;
}

// ---------------------------------------------------------------------------
// split_all: x -> xh ; [Wq;Wk;Wv] -> w1 ; [Wke;Wve] -> w2 ; Wout -> wo.
// ---------------------------------------------------------------------------
#define X_F4   1048576
#define W1_F4  393216
#define W2_F4  327680
#define WO_F4  262144

__global__ __launch_bounds__(256) void split_all(
    const float* __restrict__ x,
    const float* __restrict__ Wq, const float* __restrict__ Wk,
    const float* __restrict__ Wv, const float* __restrict__ Wke,
    const float* __restrict__ Wve, const float* __restrict__ Wout,
    ushort_t* __restrict__ xh,
    ushort_t* __restrict__ w1, ushort_t* __restrict__ w2,
    ushort_t* __restrict__ wo)
{
    int gid = blockIdx.x * 256 + threadIdx.x;
    if (gid < X_F4) {
        ((u16x4*)xh)[gid] = f16q4(((const float4*)x)[gid]);
    } else if (gid < X_F4 + W1_F4) {
        int i = gid - X_F4;
        int row = i >> 8, c4 = i & 255;
        const float* s = (row < 256) ? Wq + (size_t)row * 1024
                       : (row < 512) ? Wk + (size_t)(row - 256) * 1024
                                     : Wv + (size_t)(row - 512) * 1024;
        ((u16x4*)w1)[i] = f16q4(*(const float4*)(s + c4 * 4));
    } else if (gid < X_F4 + W1_F4 + W2_F4) {
        int i = gid - X_F4 - W1_F4;
        int row = i >> 8, c4 = i & 255;
        const float* s = (row < 256) ? Wke + (size_t)row * 1024
                                     : Wve + (size_t)(row - 256) * 1024;
        ((u16x4*)w2)[i] = f16q4(*(const float4*)(s + c4 * 4));
    } else {
        int i = gid - X_F4 - W1_F4 - W2_F4;
        ((u16x4*)wo)[i] = f16q4(((const float4*)Wout)[i]);
    }
}

// ---------------------------------------------------------------------------
// f16 1-pass GEMM body; double-buffered global_load_lds staging.
// ---------------------------------------------------------------------------
template <int SHIFT>
__device__ __forceinline__ void bg128(
    const ushort_t* __restrict__ Ah, const ushort_t* __restrict__ Wh,
    int bx, int by, int rowjump,
    ushort_t* SM, f4v (&acc)[4][4])
{
    int t = threadIdx.x;
    int w = t >> 6, lane = t & 63;
    int row0 = by * 128, col0 = bx * 128;
    int wrow = (w >> 1) * 64, wcol = (w & 1) * 64;
    int fr = lane & 15, g = lane >> 4;

    int c0 = lane, c1 = 64 + lane;
    int r0 = w * 32 + (c0 >> 2), k80 = (c0 & 3) * 8;
    int r1 = w * 32 + (c1 >> 2), k81 = (c1 & 3) * 8;
    int gr0 = row0 + r0, gr1 = row0 + r1;
    size_t a0 = (size_t)(gr0 >> SHIFT) * rowjump + (gr0 & ((1 << SHIFT) - 1));
    size_t a1 = (size_t)(gr1 >> SHIFT) * rowjump + (gr1 & ((1 << SHIFT) - 1));
    const ushort_t* pA0 = Ah + a0 * 1024 + k80;
    const ushort_t* pA1 = Ah + a1 * 1024 + k81;
    const ushort_t* pW0 = Wh + (size_t)(col0 + r0) * 1024 + k80;
    const ushort_t* pW1 = Wh + (size_t)(col0 + r1) * 1024 + k81;
    int woff = w * 1024;

    #pragma unroll
    for (int mt = 0; mt < 4; ++mt)
        #pragma unroll
        for (int nt = 0; nt < 4; ++nt) acc[mt][nt] = (f4v){0.f, 0.f, 0.f, 0.f};

    auto STAGE = [&](int buf, int k0) {
        ushort_t* Bp = SM + buf * 8192;
        gld16(pA0 + k0, Bp + woff);
        gld16(pA1 + k0, Bp + woff + 512);
        gld16(pW0 + k0, Bp + 4096 + woff);
        gld16(pW1 + k0, Bp + 4096 + woff + 512);
    };

    STAGE(0, 0);
    __syncthreads();
    int cur = 0;
    for (int k0 = 0; k0 < 1024; k0 += 32) {
        if (k0 + 32 < 1024) STAGE(cur ^ 1, k0 + 32);
        ushort_t* Bp = SM + cur * 8192;
        h8v a_h[4], b_[4];
        #pragma unroll
        for (int mt = 0; mt < 4; ++mt)
            a_h[mt] = *(const h8v*)&Bp[(wrow + mt * 16 + fr) * 32 + g * 8];
        #pragma unroll
        for (int nt = 0; nt < 4; ++nt)
            b_[nt] = *(const h8v*)&Bp[4096 + (wcol + nt * 16 + fr) * 32 + g * 8];
        #pragma unroll
        for (int mt = 0; mt < 4; ++mt)
            #pragma unroll
            for (int nt = 0; nt < 4; ++nt)
                acc[mt][nt] = MFMAH_(a_h[mt], b_[nt], acc[mt][nt], 0, 0, 0);
        __syncthreads();
        cur ^= 1;
    }
}

// ---------------------------------------------------------------------------
// proj2: main (384 blocks) + enc (80 blocks); all outputs SINGLE f16.
// ---------------------------------------------------------------------------
__global__ __launch_bounds__(256) void proj2(
    const ushort_t* __restrict__ xh,
    const ushort_t* __restrict__ w1, const ushort_t* __restrict__ w2,
    ushort_t* __restrict__ tmpq, ushort_t* __restrict__ tmpk, ushort_t* __restrict__ v,
    ushort_t* __restrict__ tmpke, ushort_t* __restrict__ ve)
{
    __shared__ ushort_t SM[16384];
    f4v acc[4][4];
    int blk = xcd_swz(blockIdx.x, 464);
    int t = threadIdx.x, w = t >> 6, lane = t & 63;
    int wrow = (w >> 1) * 64, wcol = (w & 1) * 64;
    int fr = lane & 15, g = lane >> 4;

    if (blk < 384) {
        int bx = blk % 12, by = blk / 12;
        bg128<12>(xh, w1, bx, by, 0, SM, acc);
        int row0 = by * 128, col0 = bx * 128;
        #pragma unroll
        for (int mt = 0; mt < 4; ++mt)
            #pragma unroll
            for (int nt = 0; nt < 4; ++nt)
                #pragma unroll
                for (int r4 = 0; r4 < 4; ++r4) {
                    int r  = row0 + wrow + mt * 16 + g * 4 + r4;
                    int cc = col0 + wcol + nt * 16 + fr;
                    ushort_t val = f16q(acc[mt][nt][r4]);
                    if (cc < 256)      tmpq[(size_t)r * 256 + cc] = val;
                    else if (cc < 512) tmpk[(size_t)r * 256 + (cc - 256)] = val;
                    else {
                        int c2 = cc - 512, hh = c2 >> 6, jj = c2 & 63;
                        int bb = r >> 11, n = r & 2047;
                        v[(((size_t)(bb * 16 + hh)) * 2048 + n) * 64 + jj] = val;
                    }
                }
    } else {
        int r2 = blk - 384;
        int bx = r2 % 10, by = r2 / 10;
        bg128<9>(xh, w2, bx, by, 2048, SM, acc);
        int row0 = by * 128, col0 = bx * 128;
        #pragma unroll
        for (int mt = 0; mt < 4; ++mt)
            #pragma unroll
            for (int nt = 0; nt < 4; ++nt)
                #pragma unroll
                for (int r4 = 0; r4 < 4; ++r4) {
                    int r  = row0 + wrow + mt * 16 + g * 4 + r4;
                    int cc = col0 + wcol + nt * 16 + fr;
                    ushort_t val = f16q(acc[mt][nt][r4]);
                    if (cc < 256) tmpke[(size_t)r * 256 + cc] = val;
                    else {
                        int c2 = cc - 256, hh = c2 >> 6, jj = c2 & 63;
                        int bb = r >> 9, n = r & 511;
                        ve[(((size_t)(bb * 16 + hh)) * 512 + n) * 64 + jj] = val;
                    }
                }
    }
}

// out_gemm: attn(single f16) @ Wout(f16)^T -> f32 d_out, 1-pass.
__global__ __launch_bounds__(256) void out_gemm(
    const ushort_t* __restrict__ Atn, const ushort_t* __restrict__ Wh,
    float* __restrict__ out)
{
    __shared__ ushort_t SM[16384];
    f4v acc[4][4];
    int blk = xcd_swz(blockIdx.x, 256);
    int bx = blk & 7, by = blk >> 3;
    bg128<12>(Atn, Wh, bx, by, 0, SM, acc);
    int t = threadIdx.x, w = t >> 6, lane = t & 63;
    int wrow = (w >> 1) * 64, wcol = (w & 1) * 64;
    int fr = lane & 15, g = lane >> 4;
    int row0 = by * 128, col0 = bx * 128;
    #pragma unroll
    for (int mt = 0; mt < 4; ++mt)
        #pragma unroll
        for (int nt = 0; nt < 4; ++nt)
            #pragma unroll
            for (int r4 = 0; r4 < 4; ++r4) {
                int r  = row0 + wrow + mt * 16 + g * 4 + r4;
                int cc = col0 + wcol + nt * 16 + fr;
                out[(size_t)r * 1024 + cc] = acc[mt][nt][r4];
            }
}

// ---------------------------------------------------------------------------
// MFMA state kernel, 1-pass, f16 inputs: A = Vext f16, B = on-the-fly features.
// ---------------------------------------------------------------------------
__device__ __forceinline__ void st_stage(
    const ushort_t* __restrict__ Kp, const ushort_t* __restrict__ V,
    size_t krow0, size_t vrow0, int h, int t,
    float* ksT, ushort_t* VTH)
{
    {
        int r = t >> 2, q4 = t & 3;
        s4v kv = *(const s4v*)&Kp[(krow0 + r) * 256 + h * 16 + q4 * 4];
        ksT[(q4 * 4 + 0) * 68 + r] = f16f((ushort_t)kv[0]);
        ksT[(q4 * 4 + 1) * 68 + r] = f16f((ushort_t)kv[1]);
        ksT[(q4 * 4 + 2) * 68 + r] = f16f((ushort_t)kv[2]);
        ksT[(q4 * 4 + 3) * 68 + r] = f16f((ushort_t)kv[3]);
    }
    if (t < 64) ksT[16 * 68 + t] = 1.0f;
    {
        int r = t & 63, jg = t >> 6;
        const ushort_t* vrow = &V[(vrow0 + r) * HD_ + jg * 16];
        s8v v0 = *(const s8v*)(vrow);
        s8v v1 = *(const s8v*)(vrow + 8);
        int j0 = jg * 16;
        #pragma unroll
        for (int e = 0; e < 8; ++e) VTH[(j0 + e) * 72 + r] = (ushort_t)v0[e];
        #pragma unroll
        for (int e = 0; e < 8; ++e) VTH[(j0 + 8 + e) * 72 + r] = (ushort_t)v1[e];
    }
    if (t < 64) VTH[64 * 72 + t] = 0x3C00;  // f16 1.0
}

__device__ __forceinline__ void st_ftile(
    const float* ksT, int ft, int fr, int g,
    const h8v (&AHf)[2][5], f4v (&acc)[5])
{
    int f = ft * 16 + fr;
    int fi, fj; float scale;
    if (f == 0)       { fi = 16; fj = 16; scale = 1.0f; }
    else if (f < 17)  { fi = f - 1; fj = 16; scale = 0.5f; }
    else if (f < 273) { fi = (f - 17) >> 4; fj = (f - 17) & 15; scale = C2C_; }
    else              { fi = 16; fj = 16; scale = 0.0f; }
    #pragma unroll
    for (int ks2 = 0; ks2 < 2; ++ks2) {
        const float* pa = ksT + fi * 68 + ks2 * 32 + g * 8;
        const float* pb = ksT + fj * 68 + ks2 * 32 + g * 8;
        h8v bv;
        #pragma unroll
        for (int e = 0; e < 8; ++e) bv[e] = (_Float16)(pa[e] * pb[e] * scale);
        #pragma unroll
        for (int jt = 0; jt < 5; ++jt)
            acc[jt] = MFMAH_(AHf[ks2][jt], bv, acc[jt], 0, 0, 0);
    }
}

__global__ __launch_bounds__(256) void state_all(
    const ushort_t* __restrict__ Kpe, const ushort_t* __restrict__ Ve, ushort_t* __restrict__ Se,
    const ushort_t* __restrict__ Kpc, const ushort_t* __restrict__ Vc, ushort_t* __restrict__ Sc)
{
    __shared__ float ksT[17 * 68];
    __shared__ ushort_t VTH[80 * 72];
    int blk = blockIdx.x, t = threadIdx.x;
    int w = t >> 6, lane = t & 63, fr = lane & 15, g = lane >> 4;

    for (int i = t; i < 15 * 72; i += 256) VTH[65 * 72 + i] = 0;

    if (blk >= 160) {
        int b2 = blk - 160;
        int c = b2 & 31, bh = b2 >> 5;
        int b = bh >> 4, h = bh & 15;
        ushort_t* Sg = Sc + ((size_t)bh * NC_ + c) * SSZ_;
        st_stage(Kpc, Vc, (size_t)b * 2048 + c * 64, (size_t)bh * 2048 + c * 64,
                 h, t, ksT, VTH);
        __syncthreads();
        h8v AHf[2][5];
        #pragma unroll
        for (int ks2 = 0; ks2 < 2; ++ks2)
            #pragma unroll
            for (int jt = 0; jt < 5; ++jt)
                AHf[ks2][jt] = *(const h8v*)&VTH[(jt * 16 + fr) * 72 + ks2 * 32 + g * 8];
        for (int ft = w; ft < 18; ft += 4) {
            f4v acc[5];
            #pragma unroll
            for (int jt = 0; jt < 5; ++jt) acc[jt] = (f4v){0.f, 0.f, 0.f, 0.f};
            st_ftile(ksT, ft, fr, g, AHf, acc);
            #pragma unroll
            for (int jt = 0; jt < 5; ++jt)
                #pragma unroll
                for (int r4 = 0; r4 < 4; ++r4) {
                    int j = jt * 16 + g * 4 + r4;
                    if (j < 65) Sg[(size_t)j * FP_ + ft * 16 + fr] = f16q(acc[jt][r4]);
                }
        }
    } else {
        int bh = blk / 5, fg = blk % 5;
        int b = bh >> 4, h = bh & 15;
        int ft = fg * 4 + w;
        ushort_t* Sg = Se + (size_t)bh * SSZ_;
        f4v acc[5];
        #pragma unroll
        for (int jt = 0; jt < 5; ++jt) acc[jt] = (f4v){0.f, 0.f, 0.f, 0.f};
        for (int m0 = 0; m0 < 512; m0 += 64) {
            if (m0) __syncthreads();
            st_stage(Kpe, Ve, (size_t)b * 512 + m0, (size_t)bh * 512 + m0,
                     h, t, ksT, VTH);
            __syncthreads();
            if (ft < 18) {
                h8v AHf[2][5];
                #pragma unroll
                for (int ks2 = 0; ks2 < 2; ++ks2)
                    #pragma unroll
                    for (int jt = 0; jt < 5; ++jt)
                        AHf[ks2][jt] = *(const h8v*)&VTH[(jt * 16 + fr) * 72 + ks2 * 32 + g * 8];
                st_ftile(ksT, ft, fr, g, AHf, acc);
            }
        }
        if (ft < 18) {
            #pragma unroll
            for (int jt = 0; jt < 5; ++jt)
                #pragma unroll
                for (int r4 = 0; r4 < 4; ++r4) {
                    int j = jt * 16 + g * 4 + r4;
                    if (j < 65) Sg[(size_t)j * FP_ + ft * 16 + fr] = f16q(acc[jt][r4]);
                }
        }
    }
}

// ---------------------------------------------------------------------------
// Exclusive prefix over single-f16 states, in place.  All 32 chunk loads
// issued up front (static unroll -> registers), then running-sum stores.
// ---------------------------------------------------------------------------
__global__ __launch_bounds__(256) void prefix_scan(
    ushort_t* __restrict__ Sloc, const ushort_t* __restrict__ Senc)
{
    const int Q = SSZ_ / 4;    // 4680 quad(4-short) groups
    int gid = blockIdx.x * 256 + threadIdx.x;
    if (gid >= 32 * Q) return;
    int bh = gid / Q, e = gid - bh * Q;
    s4v ev = *(const s4v*)(Senc + (size_t)bh * SSZ_ + e * 4);
    float run[4];
    #pragma unroll
    for (int u = 0; u < 4; ++u) run[u] = f16f((ushort_t)ev[u]);
    ushort_t* Sb = Sloc + (size_t)bh * NC_ * SSZ_ + e * 4;
    s4v tv[NC_];
    #pragma unroll
    for (int c2 = 0; c2 < NC_; ++c2)
        tv[c2] = *(const s4v*)(Sb + (size_t)c2 * SSZ_);
    #pragma unroll
    for (int c2 = 0; c2 < NC_; ++c2) {
        s4v o;
        #pragma unroll
        for (int u = 0; u < 4; ++u) {
            o[u] = (short)f16q(run[u]);
            run[u] += f16f((ushort_t)tv[c2][u]);
        }
        *(s4v*)(Sb + (size_t)c2 * SSZ_) = o;
    }
}

// ---------------------------------------------------------------------------
// attn_chunk: all-f16 inputs.  QK^T 1-pass; Y1 = A @ V; Y2 = QF @ S with
// register-prefetched state slices.
// ---------------------------------------------------------------------------
template<int FW>
__device__ __forceinline__ void y2_issue(
    const ushort_t* __restrict__ Sth, int f0, int t, s8v& r0, s8v& r1, s8v& r2)
{
    constexpr int NS = FW / 8;
    constexpr int TOT = 65 * NS;
    int s1 = t + 256, s2 = t + 512;
    r0 = *(const s8v*)(Sth + (size_t)(t / NS) * FP_ + f0 + (t % NS) * 8);
    if (s1 < TOT) r1 = *(const s8v*)(Sth + (size_t)(s1 / NS) * FP_ + f0 + (s1 % NS) * 8);
    if (FW == 64 && s2 < TOT) r2 = *(const s8v*)(Sth + (size_t)(s2 / NS) * FP_ + f0 + (s2 % NS) * 8);
}

template<int FW>
__device__ __forceinline__ void y2_write(
    ushort_t* STH, int t, const s8v& r0, const s8v& r1, const s8v& r2)
{
    constexpr int NS = FW / 8;
    constexpr int TOT = 65 * NS;
    int s1 = t + 256, s2 = t + 512;
    *(s8v*)&STH[(t / NS) * 72 + (t % NS) * 8] = r0;
    if (s1 < TOT) *(s8v*)&STH[(s1 / NS) * 72 + (s1 % NS) * 8] = r1;
    if (FW == 64 && s2 < TOT) *(s8v*)&STH[(s2 / NS) * 72 + (s2 % NS) * 8] = r2;
}

template<int FW>
__device__ __forceinline__ void qf_gen(int f0, const float* qs, ushort_t* QF1, int t)
{
    for (int i = t; i < 64 * FW; i += 256) {
        int row = i / FW, cc = i % FW;
        int f = f0 + cc;
        float qv;
        if (f == 0)       qv = 1.0f;
        else if (f < 17)  qv = qs[row * 20 + (f - 1)] * 0.5f;
        else if (f < 273) qv = qs[row * 20 + ((f - 17) >> 4)] * qs[row * 20 + ((f - 17) & 15)] * C2C_;
        else              qv = 0.0f;
        QF1[row * 72 + cc] = f16q(qv);
    }
}

template<int FW>
__device__ __forceinline__ void y2_mfma(
    const ushort_t* QF1, const ushort_t* STH,
    f4v (&acc)[5], int w, int fr, int g)
{
    #pragma unroll
    for (int ks2 = 0; ks2 < FW / 32; ++ks2) {
        h8v a = *(const h8v*)&QF1[(16 * w + fr) * 72 + ks2 * 32 + g * 8];
        #pragma unroll
        for (int jt = 0; jt < 5; ++jt) {
            h8v b = *(const h8v*)&STH[(jt * 16 + fr) * 72 + ks2 * 32 + g * 8];
            acc[jt] = MFMAH_(a, b, acc[jt], 0, 0, 0);
        }
    }
}

__global__ __launch_bounds__(256) void attn_chunk(
    const ushort_t* __restrict__ qp, const ushort_t* __restrict__ kp,
    const ushort_t* __restrict__ v, const ushort_t* __restrict__ Spre,
    ushort_t* __restrict__ atn)
{
    __shared__ ushort_t U[14976];
    __shared__ float qs[64 * 20];
    __shared__ float den_s[64];
    ushort_t* AH  = U;            // [64][72]  f16 (A)
    ushort_t* QH  = U + 9216;     // [64][40]
    ushort_t* KH  = U + 11776;    // [64][40]  -> ends 14336
    ushort_t* VTH = U + 9216;     // [80][72]  (after QK^T)
    ushort_t* QF1 = U;            // [64][72]  (Y2; overlays AH after Y1)
    ushort_t* STH = U + 9216;     // [80][72]  (Y2; rows 65-79 stay 0)

    int bid = blockIdx.x;
    int bh = bid >> 5, c = bid & 31;
    int b = bh >> 4, h = bh & 15;
    int t = threadIdx.x;
    int w = t >> 6, lane = t & 63, fr = lane & 15, g = lane >> 4;
    int rowbase = b * N_ + c * CHK_;
    const ushort_t* Sth = Spre + ((size_t)bh * NC_ + c) * SSZ_;

    // ---- issue q/k loads (f16)
    int rqk = t >> 2, q4 = t & 3;
    s4v qv = *(const s4v*)&qp[(size_t)(rowbase + rqk) * 256 + h * 16 + q4 * 4];
    s4v kv = *(const s4v*)&kp[(size_t)(rowbase + rqk) * 256 + h * 16 + q4 * 4];
    // ---- prefetch: state slice 0 + V tile (fly under QK^T)
    s8v rA0 = {}, rA1 = {}, rA2 = {};
    y2_issue<64>(Sth, 0, t, rA0, rA1, rA2);
    int mv = t & 63, jg0 = t >> 6;
    const ushort_t* vr = &v[((size_t)bh * N_ + c * CHK_ + mv) * HD_ + jg0 * 16];
    s8v rv0 = *(const s8v*)(vr);
    s8v rv1 = *(const s8v*)(vr + 8);

    // ---- stage q/k (f16 copies) + qs f32
    {
        *(s4v*)&QH[rqk * 40 + q4 * 4] = qv;
        *(s4v*)&KH[rqk * 40 + q4 * 4] = kv;
        s4v z4 = (s4v){0, 0, 0, 0};
        *(s4v*)&QH[rqk * 40 + 16 + q4 * 4] = z4;
        *(s4v*)&KH[rqk * 40 + 16 + q4 * 4] = z4;
        qs[rqk * 20 + q4 * 4 + 0] = f16f((ushort_t)qv[0]);
        qs[rqk * 20 + q4 * 4 + 1] = f16f((ushort_t)qv[1]);
        qs[rqk * 20 + q4 * 4 + 2] = f16f((ushort_t)qv[2]);
        qs[rqk * 20 + q4 * 4 + 3] = f16f((ushort_t)qv[3]);
    }
    __syncthreads();

    // ---- phase A: QK^T (f16 1-pass), poly+tril, store f16 AH
    {
        h8v qh = *(const h8v*)&QH[(16 * w + fr) * 40 + g * 8];
        f4v sacc[4];
        #pragma unroll
        for (int jt = 0; jt < 4; ++jt) sacc[jt] = (f4v){0.f, 0.f, 0.f, 0.f};
        #pragma unroll
        for (int jt = 0; jt < 4; ++jt) {
            h8v kh = *(const h8v*)&KH[(jt * 16 + fr) * 40 + g * 8];
            sacc[jt] = MFMAH_(qh, kh, sacc[jt], 0, 0, 0);
        }
        __syncthreads();   // QH/KH dead after this barrier (sacc in regs)
        #pragma unroll
        for (int jt = 0; jt < 4; ++jt)
            #pragma unroll
            for (int r4 = 0; r4 < 4; ++r4) {
                int row = 16 * w + g * 4 + r4, col = jt * 16 + fr;
                float s = sacc[jt][r4];
                float a = (row >= col) ? (fmaf(s, 0.25f, 1.0f) + s * s * 0.03125f) : 0.f;
                AH[row * 72 + col] = f16q(a);
            }
    }
    // ---- write V tile from prefetched regs + ones/zero rows
    {
        int j0 = jg0 * 16;
        #pragma unroll
        for (int e = 0; e < 8; ++e) VTH[(j0 + e) * 72 + mv] = (ushort_t)rv0[e];
        #pragma unroll
        for (int e = 0; e < 8; ++e) VTH[(j0 + 8 + e) * 72 + mv] = (ushort_t)rv1[e];
    }
    if (t < 64) VTH[64 * 72 + t] = 0x3C00;          // f16 1.0 (denominator row)
    for (int i = t; i < 15 * 72; i += 256) VTH[65 * 72 + i] = 0;
    __syncthreads();

    // ---- Y1: acc += A @ VT
    f4v acc[5];
    #pragma unroll
    for (int jt = 0; jt < 5; ++jt) acc[jt] = (f4v){0.f, 0.f, 0.f, 0.f};
    #pragma unroll
    for (int ks2 = 0; ks2 < 2; ++ks2) {
        h8v ah = *(const h8v*)&AH[(16 * w + fr) * 72 + ks2 * 32 + g * 8];
        #pragma unroll
        for (int jt = 0; jt < 5; ++jt) {
            h8v b = *(const h8v*)&VTH[(jt * 16 + fr) * 72 + ks2 * 32 + g * 8];
            acc[jt] = MFMAH_(ah, b, acc[jt], 0, 0, 0);
        }
    }
    __syncthreads();

    // ---- Y2: 5 state slices, register-prefetched (slice 0 already in rA*)
    #pragma unroll
    for (int p = 0; p < 4; ++p) {
        y2_write<64>(STH, t, rA0, rA1, rA2);
        if (p < 3) y2_issue<64>(Sth, (p + 1) * 64, t, rA0, rA1, rA2);
        else       y2_issue<32>(Sth, 256,          t, rA0, rA1, rA2);
        qf_gen<64>(p * 64, qs, QF1, t);
        __syncthreads();
        y2_mfma<64>(QF1, STH, acc, w, fr, g);
        __syncthreads();
    }
    y2_write<32>(STH, t, rA0, rA1, rA2);
    qf_gen<32>(256, qs, QF1, t);
    __syncthreads();
    y2_mfma<32>(QF1, STH, acc, w, fr, g);

    // ---- epilogue: divide by denominator, store single f16
    if (fr == 0) {
        #pragma unroll
        for (int r4 = 0; r4 < 4; ++r4)
            den_s[16 * w + g * 4 + r4] = acc[4][r4];
    }
    __syncthreads();
    #pragma unroll
    for (int r4 = 0; r4 < 4; ++r4) {
        float z = 1.0f / (den_s[16 * w + g * 4 + r4] + EPS_);
        int row = rowbase + 16 * w + g * 4 + r4;
        #pragma unroll
        for (int jt = 0; jt < 4; ++jt) {
            float val = acc[jt][r4] * z;
            atn[(size_t)row * 1024 + h * 64 + jt * 16 + fr] = f16q(val);
        }
    }
}

// ---------------------------------------------------------------------------
extern "C" void kernel_launch(void* const* d_in, const int* in_sizes, int n_in,
                              void* d_out, int out_size, void* d_ws, size_t ws_size,
                              hipStream_t stream)
{
    const float* x    = (const float*)d_in[0];
    const float* Wq   = (const float*)d_in[1];
    const float* Wk   = (const float*)d_in[2];
    const float* Wv   = (const float*)d_in[3];
    const float* Wke  = (const float*)d_in[4];
    const float* Wve  = (const float*)d_in[5];
    const float* Wout = (const float*)d_in[6];
    float* out = (float*)d_out;

    // all-f16 workspace (~65 MB)
    ushort_t* usws  = (ushort_t*)d_ws;
    ushort_t* tmpq  = usws;                            // 1,048,576
    ushort_t* tmpk  = tmpq  + (size_t)1048576;         // 1,048,576
    ushort_t* tmpke = tmpk  + (size_t)1048576;         //   262,144
    ushort_t* v     = tmpke + (size_t)262144;          // 4,194,304
    ushort_t* ve    = v     + (size_t)4194304;         // 1,048,576
    ushort_t* Sloc  = ve    + (size_t)1048576;         // 19,169,280
    ushort_t* Senc  = Sloc  + (size_t)19169280;        //   599,040
    ushort_t* xh    = Senc  + (size_t)599040;          // 4,194,304
    ushort_t* wo    = xh    + (size_t)4194304;         // 1,048,576
    // overlays:
    ushort_t* w1 = Sloc;                               // dead before state_all
    ushort_t* w2 = w1 + (size_t)1572864;
    ushort_t* atn = xh;                                // xh dead after proj2

    dim3 blk(256);

    split_all<<<7936, blk, 0, stream>>>(x, Wq, Wk, Wv, Wke, Wve, Wout,
                                        xh, w1, w2, wo);
    proj2<<<464, blk, 0, stream>>>(xh, w1, w2, tmpq, tmpk, v, tmpke, ve);
    state_all<<<160 + 32 * NC_, blk, 0, stream>>>(tmpke, ve, Senc, tmpk, v, Sloc);
    prefix_scan<<<585, blk, 0, stream>>>(Sloc, Senc);
    attn_chunk<<<32 * NC_, blk, 0, stream>>>(tmpq, tmpk, v, Sloc, atn);
    out_gemm<<<256, blk, 0, stream>>>(atn, wo, out);
}